// Round 1
// baseline (17769.769 us; speedup 1.0000x reference)
//
#include <hip/hip_runtime.h>

#define EPSV 1e-5f

__device__ __forceinline__ float gelu_exact(float x) {
    return 0.5f * x * (1.0f + erff(x * 0.7071067811865475f));
}

// ---------------- tiny setup kernels ----------------
__global__ void k_wsfail(float* out) { out[0] = 1.0e9f; }

__global__ void k_wt(const float* __restrict__ w, float* __restrict__ wt, int cout, int cin9) {
    int idx = blockIdx.x * 256 + threadIdx.x;
    if (idx < cout * cin9) {
        int co = idx / cin9, k = idx % cin9;
        wt[k * cout + co] = w[idx];
    }
}

__global__ void k_tables(float* __restrict__ postab, float* __restrict__ ropetab) {
    int idx = blockIdx.x * 256 + threadIdx.x;
    if (idx < 256 * 512) {
        int p = idx >> 9, j = idx & 511;
        // pos2d: x[p] = p/16, y[p] = p%16 ; [sin(x*om) | cos(x*om) | sin(y*om) | cos(y*om)]
        float coord = (j < 256) ? (float)(p >> 4) : (float)(p & 15);
        int jm = j & 127;
        float om = powf(10000.0f, -(float)jm / 128.0f);
        float arg = coord * om;
        postab[idx] = ((j >> 7) & 1) ? cosf(arg) : sinf(arg);
    }
    if (idx < 512) {
        // xpos tables indexed by HEAD h (reference quirk): n_pos = H = 8
        int h = idx >> 6, d = idx & 63;
        float freq = (float)h * powf(10000.0f, -(float)(d >> 1) / 32.0f);
        float sv = (2.0f * (float)(d & 31) + 25.6f) / 89.6f;   // (2i + 0.4*64)/(1.4*64), i = d mod 32
        float pw = ((float)h - 4.0f) / 512.0f;                 // (h - n_pos//2)/512
        float sc = powf(sv, pw);
        ropetab[idx * 4 + 0] = cosf(freq);
        ropetab[idx * 4 + 1] = sinf(freq);
        ropetab[idx * 4 + 2] = sc;
        ropetab[idx * 4 + 3] = 1.0f / sc;
    }
}

__global__ void k_cls(const float* __restrict__ cls, float* __restrict__ xa) {
    int idx = blockIdx.x * 256 + threadIdx.x;   // 32*512 threads
    int b = idx >> 9, d = idx & 511;
    xa[(size_t)(b * 257) * 512 + d] = cls[d];
}

// ---------------- direct conv (3x3, pad 1), 16x16 output tile, all COUT per thread ----------------
template <int CIN, int COUT>
__global__ __launch_bounds__(256) void k_conv(const float* __restrict__ in,
                                              const float* __restrict__ wt,   // [CIN*9][COUT]
                                              const float* __restrict__ bias,
                                              float* __restrict__ out) {
    __shared__ float s_in[CIN][18][18];
    int b = blockIdx.y;
    int tile = blockIdx.x;
    int y0 = (tile >> 3) << 4;
    int x0 = (tile & 7) << 4;
    int tid = threadIdx.x;
    const int TOT = CIN * 324;
    for (int idx = tid; idx < TOT; idx += 256) {
        int ci = idx / 324, r = idx % 324;
        int ly = r / 18, lx = r % 18;
        int gy = y0 + ly - 1, gx = x0 + lx - 1;
        float v = 0.0f;
        if (gy >= 0 && gy < 128 && gx >= 0 && gx < 128)
            v = in[((size_t)(b * CIN + ci) * 128 + gy) * 128 + gx];
        s_in[ci][ly][lx] = v;
    }
    __syncthreads();
    int py = tid >> 4, px = tid & 15;
    float acc[COUT];
#pragma unroll
    for (int co = 0; co < COUT; co++) acc[co] = bias[co];
    for (int ci = 0; ci < CIN; ci++) {
#pragma unroll
        for (int dy = 0; dy < 3; dy++) {
#pragma unroll
            for (int dx = 0; dx < 3; dx++) {
                float v = s_in[ci][py + dy][px + dx];
                const float* wr = &wt[(ci * 9 + dy * 3 + dx) * COUT];   // uniform -> s_load
#pragma unroll
                for (int co = 0; co < COUT; co++)
                    acc[co] = fmaf(wr[co], v, acc[co]);
            }
        }
    }
    int oy = y0 + py, ox = x0 + px;
#pragma unroll
    for (int co = 0; co < COUT; co++)
        out[((size_t)(b * COUT + co) * 128 + oy) * 128 + ox] = acc[co];
}

// ---------------- GroupNorm: stats (per contiguous group chunk) + apply(+GELU) ----------------
__global__ __launch_bounds__(256) void k_gnstats(const float* __restrict__ x,
                                                 float* __restrict__ stat, int n) {
    int bid = blockIdx.x, tid = threadIdx.x;
    const float* xp = x + (size_t)bid * n;
    double ds = 0.0, dq = 0.0;
    for (int i = tid; i < n; i += 256) {
        float v = xp[i];
        ds += v;
        dq += (double)v * v;
    }
    __shared__ double rs[256], rq[256];
    rs[tid] = ds; rq[tid] = dq;
    __syncthreads();
    for (int s = 128; s > 0; s >>= 1) {
        if (tid < s) { rs[tid] += rs[tid + s]; rq[tid] += rq[tid + s]; }
        __syncthreads();
    }
    if (tid == 0) {
        double m = rs[0] / n;
        double var = rq[0] / n - m * m;
        stat[2 * bid] = (float)m;
        stat[2 * bid + 1] = (float)(1.0 / sqrt(var + 1e-5));
    }
}

__global__ void k_gnapply(float* __restrict__ x, const float* __restrict__ stat,
                          const float* __restrict__ g, const float* __restrict__ bta,
                          int C, int total) {
    int idx = blockIdx.x * 256 + threadIdx.x;
    if (idx >= total) return;
    int c = (idx >> 14) & (C - 1);    // HW = 16384, C power of two
    int gidx = idx >> 17;             // cpg*HW = 8*16384
    float m = stat[2 * gidx], r = stat[2 * gidx + 1];
    float v = (x[idx] - m) * r * g[c] + bta[c];
    x[idx] = gelu_exact(v);
}

// ---------------- generic fp32 SGEMM: C[m,n] (+)= A[m,:]*B[:,n] + bias[n] ----------------
// EPI==1: C = acc + bias ; EPI==2: C += acc + bias (residual)
template <int EPI>
__global__ __launch_bounds__(256) void k_gemm(const float* __restrict__ A,
                                              const float* __restrict__ Bm,
                                              const float* __restrict__ bias,
                                              float* __restrict__ C,
                                              int M, int N, int K) {
    __shared__ float As[16][128];
    __shared__ float Bs[16][128];
    int bm = blockIdx.y * 128, bn = blockIdx.x * 128;
    int tid = threadIdx.x;
    int ty = tid >> 4, tx = tid & 15;
    float acc[8][8] = {};
    for (int k0 = 0; k0 < K; k0 += 16) {
#pragma unroll
        for (int i = 0; i < 2; i++) {
            int idx = tid + i * 256;
            int m = idx >> 2, kk = (idx & 3) << 2;
            int row = bm + m;
            float4 v = make_float4(0.f, 0.f, 0.f, 0.f);
            if (row < M) v = *(const float4*)&A[(size_t)row * K + k0 + kk];
            As[kk + 0][m] = v.x; As[kk + 1][m] = v.y; As[kk + 2][m] = v.z; As[kk + 3][m] = v.w;
        }
#pragma unroll
        for (int i = 0; i < 2; i++) {
            int idx = tid + i * 256;
            int kr = idx >> 5, n4 = (idx & 31) << 2;
            float4 v = *(const float4*)&Bm[(size_t)(k0 + kr) * N + bn + n4];
            *(float4*)&Bs[kr][n4] = v;
        }
        __syncthreads();
#pragma unroll
        for (int k = 0; k < 16; k++) {
            float a[8], bb[8];
#pragma unroll
            for (int i = 0; i < 8; i++) a[i] = As[k][ty * 8 + i];
#pragma unroll
            for (int j = 0; j < 8; j++) bb[j] = Bs[k][tx * 8 + j];
#pragma unroll
            for (int i = 0; i < 8; i++)
#pragma unroll
                for (int j = 0; j < 8; j++)
                    acc[i][j] = fmaf(a[i], bb[j], acc[i][j]);
        }
        __syncthreads();
    }
#pragma unroll
    for (int i = 0; i < 8; i++) {
        int row = bm + ty * 8 + i;
        if (row >= M) break;
#pragma unroll
        for (int j = 0; j < 8; j++) {
            int col = bn + tx * 8 + j;
            float v = acc[i][j] + bias[col];
            size_t o = (size_t)row * N + col;
            if (EPI == 2) C[o] += v;
            else C[o] = v;
        }
    }
}

// ---------------- patch embed as implicit-im2col GEMM: M=8192 (b*256+p), N=512, K=4096 ----------------
__global__ __launch_bounds__(256) void k_patchgemm(const float* __restrict__ f2,
                                                   const float* __restrict__ W,      // [512][4096]
                                                   const float* __restrict__ bias,
                                                   const float* __restrict__ postab, // [256][512]
                                                   float* __restrict__ xa) {
    __shared__ float As[16][128];
    __shared__ float Bs[16][128];
    int bm = blockIdx.y * 128, bn = blockIdx.x * 128;
    int tid = threadIdx.x;
    int ty = tid >> 4, tx = tid & 15;
    int bimg = bm >> 8;   // constant per tile (128 | 256)
    float acc[8][8] = {};
    for (int k0 = 0; k0 < 4096; k0 += 16) {
#pragma unroll
        for (int i = 0; i < 2; i++) {
            int idx = tid + i * 256;
            int m = idx >> 2, kk = (idx & 3) << 2;
            int row = bm + m;
            int p = row & 255;
            int k = k0 + kk;
            int ci = k >> 6, r = k & 63, ky = r >> 3, kx = r & 7;   // kx in {0,4}
            int gy = ((p >> 4) << 3) + ky, gx = ((p & 15) << 3) + kx;
            float4 v = *(const float4*)&f2[((size_t)(bimg * 64 + ci) * 128 + gy) * 128 + gx];
            As[kk + 0][m] = v.x; As[kk + 1][m] = v.y; As[kk + 2][m] = v.z; As[kk + 3][m] = v.w;
        }
#pragma unroll
        for (int i = 0; i < 2; i++) {
            int idx = tid + i * 256;
            int n = idx >> 2, kk = (idx & 3) << 2;
            float4 v = *(const float4*)&W[(size_t)(bn + n) * 4096 + k0 + kk];
            Bs[kk + 0][n] = v.x; Bs[kk + 1][n] = v.y; Bs[kk + 2][n] = v.z; Bs[kk + 3][n] = v.w;
        }
        __syncthreads();
#pragma unroll
        for (int k = 0; k < 16; k++) {
            float a[8], bb[8];
#pragma unroll
            for (int i = 0; i < 8; i++) a[i] = As[k][ty * 8 + i];
#pragma unroll
            for (int j = 0; j < 8; j++) bb[j] = Bs[k][tx * 8 + j];
#pragma unroll
            for (int i = 0; i < 8; i++)
#pragma unroll
                for (int j = 0; j < 8; j++)
                    acc[i][j] = fmaf(a[i], bb[j], acc[i][j]);
        }
        __syncthreads();
    }
#pragma unroll
    for (int i = 0; i < 8; i++) {
        int row = bm + ty * 8 + i;
        int p = row & 255;
#pragma unroll
        for (int j = 0; j < 8; j++) {
            int col = bn + tx * 8 + j;
            float v = acc[i][j] + bias[col] + postab[p * 512 + col];
            xa[((size_t)(bimg * 257) + 1 + p) * 512 + col] = v;
        }
    }
}

// ---------------- LayerNorm over D=512 (one block per row) ----------------
__global__ __launch_bounds__(256) void k_ln(const float* __restrict__ x,
                                            const float* __restrict__ g,
                                            const float* __restrict__ bta,
                                            float* __restrict__ o) {
    int row = blockIdx.x, tid = threadIdx.x;
    const float* xr = x + (size_t)row * 512;
    float v0 = xr[tid], v1 = xr[tid + 256];
    __shared__ float rs[256];
    rs[tid] = v0 + v1;
    __syncthreads();
    for (int s = 128; s > 0; s >>= 1) { if (tid < s) rs[tid] += rs[tid + s]; __syncthreads(); }
    float mean = rs[0] * (1.0f / 512.0f);
    __syncthreads();
    float d0 = v0 - mean, d1 = v1 - mean;
    rs[tid] = d0 * d0 + d1 * d1;
    __syncthreads();
    for (int s = 128; s > 0; s >>= 1) { if (tid < s) rs[tid] += rs[tid + s]; __syncthreads(); }
    float rstd = rsqrtf(rs[0] * (1.0f / 512.0f) + EPSV);
    float* orow = o + (size_t)row * 512;
    orow[tid] = d0 * rstd * g[tid] + bta[tid];
    orow[tid + 256] = d1 * rstd * g[tid + 256] + bta[tid + 256];
}

// final LN with output remap: row -> (cls | tokens) layout
__global__ __launch_bounds__(256) void k_ln_out(const float* __restrict__ x,
                                                const float* __restrict__ g,
                                                const float* __restrict__ bta,
                                                float* __restrict__ out) {
    int row = blockIdx.x, tid = threadIdx.x;
    const float* xr = x + (size_t)row * 512;
    float v0 = xr[tid], v1 = xr[tid + 256];
    __shared__ float rs[256];
    rs[tid] = v0 + v1;
    __syncthreads();
    for (int s = 128; s > 0; s >>= 1) { if (tid < s) rs[tid] += rs[tid + s]; __syncthreads(); }
    float mean = rs[0] * (1.0f / 512.0f);
    __syncthreads();
    float d0 = v0 - mean, d1 = v1 - mean;
    rs[tid] = d0 * d0 + d1 * d1;
    __syncthreads();
    for (int s = 128; s > 0; s >>= 1) { if (tid < s) rs[tid] += rs[tid + s]; __syncthreads(); }
    float rstd = rsqrtf(rs[0] * (1.0f / 512.0f) + EPSV);
    int b = row / 257, t = row % 257;
    float* dst = (t == 0) ? out + (size_t)b * 512
                          : out + 16384 + (size_t)(b * 256 + (t - 1)) * 512;
    dst[tid] = d0 * rstd * g[tid] + bta[tid];
    dst[tid + 256] = d1 * rstd * g[tid + 256] + bta[tid + 256];
}

// ---------------- xPos rotary on q,k inside qkv buffer ----------------
__global__ void k_rope(float* __restrict__ qkv, const float* __restrict__ rt) {
    int idx = blockIdx.x * 256 + threadIdx.x;   // 8224*256 exact
    int d2 = idx & 31, h = (idx >> 5) & 7, bt = idx >> 8;
    int d0 = d2 * 2;
    size_t base = (size_t)bt * 1536 + h * 64 + d0;
    const float* r0 = &rt[(h * 64 + d0) * 4];
    float ct = r0[0], st = r0[1], s0 = r0[2], rs0 = r0[3];
    float s1 = r0[6], rs1 = r0[7];   // entry for d0+1 (same cos/sin)
    float q0 = qkv[base], q1 = qkv[base + 1];
    qkv[base]     = (q0 * ct - q1 * st) * s0;
    qkv[base + 1] = (q1 * ct + q0 * st) * s1;
    float k0 = qkv[base + 512], k1 = qkv[base + 513];
    qkv[base + 512] = (k0 * ct - k1 * st) * rs0;
    qkv[base + 513] = (k1 * ct + k0 * st) * rs1;
}

// ---------------- fused attention: one block per (b,h,i) row ----------------
__global__ __launch_bounds__(256) void k_attn(const float* __restrict__ qkv,
                                              float* __restrict__ y) {
    int bid = blockIdx.x;                 // ((b*8+h)*257 + i)
    int i = bid % 257;
    int bh = bid / 257;
    int h = bh & 7, b = bh >> 3;
    __shared__ float qs[64];
    __shared__ float sc[257];
    __shared__ float red[256];
    int tid = threadIdx.x;
    size_t qbase = ((size_t)(b * 257 + i)) * 1536 + h * 64;
    if (tid < 64) qs[tid] = qkv[qbase + tid] * 0.125f;   // HD^-0.5
    __syncthreads();
    for (int j = tid; j < 257; j += 256) {
        size_t kbase = ((size_t)(b * 257 + j)) * 1536 + 512 + h * 64;
        float s = 0.0f;
#pragma unroll 8
        for (int d = 0; d < 64; d++) s = fmaf(qs[d], qkv[kbase + d], s);
        sc[j] = s;
    }
    __syncthreads();
    float lm = -1e30f;
    for (int j = tid; j < 257; j += 256) lm = fmaxf(lm, sc[j]);
    red[tid] = lm;
    __syncthreads();
    for (int s = 128; s > 0; s >>= 1) { if (tid < s) red[tid] = fmaxf(red[tid], red[tid + s]); __syncthreads(); }
    float mx = red[0];
    __syncthreads();
    float ls = 0.0f;
    for (int j = tid; j < 257; j += 256) { float e = __expf(sc[j] - mx); sc[j] = e; ls += e; }
    red[tid] = ls;
    __syncthreads();
    for (int s = 128; s > 0; s >>= 1) { if (tid < s) red[tid] += red[tid + s]; __syncthreads(); }
    float inv = 1.0f / red[0];
    __syncthreads();
    int d = tid & 63, part = tid >> 6;
    float accv = 0.0f;
    for (int j = part; j < 257; j += 4) {
        size_t vbase = ((size_t)(b * 257 + j)) * 1536 + 1024 + h * 64;
        accv = fmaf(sc[j], qkv[vbase + d], accv);
    }
    red[tid] = accv;
    __syncthreads();
    if (tid < 64) {
        float r = red[tid] + red[tid + 64] + red[tid + 128] + red[tid + 192];
        y[((size_t)(b * 257 + i)) * 512 + h * 64 + tid] = r * inv;
    }
}

// ---------------- SwiGLU combine: h1 = silu(h1) * h2 ----------------
__global__ void k_swiglu(float* __restrict__ h1, const float* __restrict__ h2) {
    size_t idx = (size_t)blockIdx.x * 256 + threadIdx.x;
    float a = h1[idx];
    h1[idx] = a / (1.0f + __expf(-a)) * h2[idx];
}

// ---------------- host launch ----------------
extern "C" void kernel_launch(void* const* d_in, const int* in_sizes, int n_in,
                              void* d_out, int out_size, void* d_ws, size_t ws_size,
                              hipStream_t stream) {
    const float* x       = (const float*)d_in[0];
    const float* conv1_w = (const float*)d_in[1];
    const float* conv1_b = (const float*)d_in[2];
    const float* gn1_g   = (const float*)d_in[3];
    const float* gn1_b   = (const float*)d_in[4];
    const float* conv2_w = (const float*)d_in[5];
    const float* conv2_b = (const float*)d_in[6];
    const float* gn2_g   = (const float*)d_in[7];
    const float* gn2_b   = (const float*)d_in[8];
    const float* patch_w = (const float*)d_in[9];
    const float* patch_b = (const float*)d_in[10];
    const float* cls_tok = (const float*)d_in[11];
    const float* ln1_g   = (const float*)d_in[12];
    const float* ln1_b   = (const float*)d_in[13];
    const float* qkv_w   = (const float*)d_in[14];
    const float* qkv_b   = (const float*)d_in[15];
    const float* out_w   = (const float*)d_in[16];
    const float* out_b   = (const float*)d_in[17];
    const float* ln2_g   = (const float*)d_in[18];
    const float* ln2_b   = (const float*)d_in[19];
    const float* w1_w    = (const float*)d_in[20];
    const float* w1_b    = (const float*)d_in[21];
    const float* w2_w    = (const float*)d_in[22];
    const float* w2_b    = (const float*)d_in[23];
    const float* w3_w    = (const float*)d_in[24];
    const float* w3_b    = (const float*)d_in[25];
    const float* fn_g    = (const float*)d_in[26];
    const float* fn_b    = (const float*)d_in[27];
    float* out = (float*)d_out;
    float* ws  = (float*)d_ws;

    // workspace arena (floats), lifetime-aliased
    const size_t O_F1  = 0;                   // 16,777,216 : conv1 out (later: qkv 12.6M)
    const size_t O_F2  = 16777216;            // 33,685,504 : conv2 out (later: h1+h2)
    const size_t O_H1  = O_F2;
    const size_t O_H2  = O_F2 + 16842752;
    const size_t O_N   = 50462720;            // 4,210,688 : LN out
    const size_t O_Y   = 54673408;            // 4,210,688 : attn out
    const size_t O_XA  = 58884096;            // 4,210,688 : residual stream
    const size_t O_ST  = 63094784;            // 512  : GN stats
    const size_t O_PT  = 63095296;            // 131,072 : pos2d table
    const size_t O_RT  = 63226368;            // 2,048 : rope table
    const size_t O_W1T = 63228416;            // 1,024 : conv1 wT
    const size_t O_W2T = 63229440;            // 18,432 : conv2 wT
    const size_t NEEDF = 63247872;
    if (ws_size < NEEDF * sizeof(float)) {
        k_wsfail<<<1, 1, 0, stream>>>(out);   // sentinel: absmax ~1e9 => ws too small
        return;
    }
    float* f1     = ws + O_F1;
    float* qkv    = ws + O_F1;
    float* f2     = ws + O_F2;
    float* h1     = ws + O_H1;
    float* h2     = ws + O_H2;
    float* nb     = ws + O_N;
    float* yb     = ws + O_Y;
    float* xa     = ws + O_XA;
    float* stat   = ws + O_ST;
    float* postab = ws + O_PT;
    float* ropet  = ws + O_RT;
    float* w1t    = ws + O_W1T;
    float* w2t    = ws + O_W2T;

    k_wt<<<4, 256, 0, stream>>>(conv1_w, w1t, 32, 27);
    k_wt<<<72, 256, 0, stream>>>(conv2_w, w2t, 64, 288);
    k_tables<<<512, 256, 0, stream>>>(postab, ropet);

    // conv stem
    k_conv<3, 32><<<dim3(64, 32), 256, 0, stream>>>(x, w1t, conv1_b, f1);
    k_gnstats<<<128, 256, 0, stream>>>(f1, stat, 131072);
    k_gnapply<<<65536, 256, 0, stream>>>(f1, stat, gn1_g, gn1_b, 32, 16777216);
    k_conv<32, 64><<<dim3(64, 32), 256, 0, stream>>>(f1, w2t, conv2_b, f2);
    k_gnstats<<<256, 256, 0, stream>>>(f2, stat, 131072);
    k_gnapply<<<131072, 256, 0, stream>>>(f2, stat, gn2_g, gn2_b, 64, 33554432);

    // patch embed + pos + cls
    k_patchgemm<<<dim3(4, 64), 256, 0, stream>>>(f2, patch_w, patch_b, postab, xa);
    k_cls<<<64, 256, 0, stream>>>(cls_tok, xa);

    // transformer
    for (int l = 0; l < 8; l++) {
        k_ln<<<8224, 256, 0, stream>>>(xa, ln1_g + l * 512, ln1_b + l * 512, nb);
        k_gemm<1><<<dim3(12, 65), 256, 0, stream>>>(nb, qkv_w + (size_t)l * 512 * 1536,
                                                    qkv_b + l * 1536, qkv, 8224, 1536, 512);
        k_rope<<<8224, 256, 0, stream>>>(qkv, ropet);
        k_attn<<<65792, 256, 0, stream>>>(qkv, yb);
        k_gemm<2><<<dim3(4, 65), 256, 0, stream>>>(yb, out_w + (size_t)l * 512 * 512,
                                                   out_b + l * 512, xa, 8224, 512, 512);
        k_ln<<<8224, 256, 0, stream>>>(xa, ln2_g + l * 512, ln2_b + l * 512, nb);
        k_gemm<1><<<dim3(16, 65), 256, 0, stream>>>(nb, w1_w + (size_t)l * 512 * 2048,
                                                    w1_b + l * 2048, h1, 8224, 2048, 512);
        k_gemm<1><<<dim3(16, 65), 256, 0, stream>>>(nb, w2_w + (size_t)l * 512 * 2048,
                                                    w2_b + l * 2048, h2, 8224, 2048, 512);
        k_swiglu<<<65792, 256, 0, stream>>>(h1, h2);
        k_gemm<2><<<dim3(4, 65), 256, 0, stream>>>(h1, w3_w + (size_t)l * 2048 * 512,
                                                   w3_b + l * 512, xa, 8224, 512, 2048);
    }
    k_ln_out<<<8224, 256, 0, stream>>>(xa, fn_g, fn_b, out);
}

// Round 2
// 12365.801 us; speedup vs baseline: 1.4370x; 1.4370x over previous
//
#include <hip/hip_runtime.h>

#define EPSV 1e-5f

__device__ __forceinline__ float gelu_exact(float x) {
    return 0.5f * x * (1.0f + erff(x * 0.7071067811865475f));
}

// ---------------- tiny setup kernels ----------------
__global__ void k_wsfail(float* out) { out[0] = 1.0e9f; }

__global__ void k_wt(const float* __restrict__ w, float* __restrict__ wt, int cout, int cin9) {
    int idx = blockIdx.x * 256 + threadIdx.x;
    if (idx < cout * cin9) {
        int co = idx / cin9, k = idx % cin9;
        wt[k * cout + co] = w[idx];
    }
}

__global__ void k_tables(float* __restrict__ postab, float* __restrict__ ropetab) {
    int idx = blockIdx.x * 256 + threadIdx.x;
    if (idx < 256 * 512) {
        int p = idx >> 9, j = idx & 511;
        float coord = (j < 256) ? (float)(p >> 4) : (float)(p & 15);
        int jm = j & 127;
        float om = powf(10000.0f, -(float)jm / 128.0f);
        float arg = coord * om;
        postab[idx] = ((j >> 7) & 1) ? cosf(arg) : sinf(arg);
    }
    if (idx < 512) {
        // xpos tables indexed by HEAD h (reference quirk): n_pos = H = 8
        int h = idx >> 6, d = idx & 63;
        float freq = (float)h * powf(10000.0f, -(float)(d >> 1) / 32.0f);
        float sv = (2.0f * (float)(d & 31) + 25.6f) / 89.6f;
        float pw = ((float)h - 4.0f) / 512.0f;
        float sc = powf(sv, pw);
        ropetab[idx * 4 + 0] = cosf(freq);
        ropetab[idx * 4 + 1] = sinf(freq);
        ropetab[idx * 4 + 2] = sc;
        ropetab[idx * 4 + 3] = 1.0f / sc;
    }
}

__global__ void k_cls(const float* __restrict__ cls, float* __restrict__ xa) {
    int idx = blockIdx.x * 256 + threadIdx.x;
    int b = idx >> 9, d = idx & 511;
    xa[(size_t)(b * 257) * 512 + d] = cls[d];
}

// ---------------- direct conv (3x3, pad 1) ----------------
template <int CIN, int COUT>
__global__ __launch_bounds__(256) void k_conv(const float* __restrict__ in,
                                              const float* __restrict__ wt,   // [CIN*9][COUT]
                                              const float* __restrict__ bias,
                                              float* __restrict__ out) {
    __shared__ float s_in[CIN][18][18];
    int b = blockIdx.y;
    int tile = blockIdx.x;
    int y0 = (tile >> 3) << 4;
    int x0 = (tile & 7) << 4;
    int tid = threadIdx.x;
    const int TOT = CIN * 324;
    for (int idx = tid; idx < TOT; idx += 256) {
        int ci = idx / 324, r = idx % 324;
        int ly = r / 18, lx = r % 18;
        int gy = y0 + ly - 1, gx = x0 + lx - 1;
        float v = 0.0f;
        if (gy >= 0 && gy < 128 && gx >= 0 && gx < 128)
            v = in[((size_t)(b * CIN + ci) * 128 + gy) * 128 + gx];
        s_in[ci][ly][lx] = v;
    }
    __syncthreads();
    int py = tid >> 4, px = tid & 15;
    float acc[COUT];
#pragma unroll
    for (int co = 0; co < COUT; co++) acc[co] = bias[co];
    for (int ci = 0; ci < CIN; ci++) {
#pragma unroll
        for (int dy = 0; dy < 3; dy++) {
#pragma unroll
            for (int dx = 0; dx < 3; dx++) {
                float v = s_in[ci][py + dy][px + dx];
                const float* wr = &wt[(ci * 9 + dy * 3 + dx) * COUT];
#pragma unroll
                for (int co = 0; co < COUT; co++)
                    acc[co] = fmaf(wr[co], v, acc[co]);
            }
        }
    }
    int oy = y0 + py, ox = x0 + px;
#pragma unroll
    for (int co = 0; co < COUT; co++)
        out[((size_t)(b * COUT + co) * 128 + oy) * 128 + ox] = acc[co];
}

// ---------------- GroupNorm ----------------
__global__ __launch_bounds__(256) void k_gnstats(const float* __restrict__ x,
                                                 float* __restrict__ stat, int n) {
    int bid = blockIdx.x, tid = threadIdx.x;
    const float* xp = x + (size_t)bid * n;
    double ds = 0.0, dq = 0.0;
    for (int i = tid; i < n; i += 256) {
        float v = xp[i];
        ds += v;
        dq += (double)v * v;
    }
    __shared__ double rs[256], rq[256];
    rs[tid] = ds; rq[tid] = dq;
    __syncthreads();
    for (int s = 128; s > 0; s >>= 1) {
        if (tid < s) { rs[tid] += rs[tid + s]; rq[tid] += rq[tid + s]; }
        __syncthreads();
    }
    if (tid == 0) {
        double m = rs[0] / n;
        double var = rq[0] / n - m * m;
        stat[2 * bid] = (float)m;
        stat[2 * bid + 1] = (float)(1.0 / sqrt(var + 1e-5));
    }
}

__global__ void k_gnapply(float* __restrict__ x, const float* __restrict__ stat,
                          const float* __restrict__ g, const float* __restrict__ bta,
                          int C, int total) {
    int idx = blockIdx.x * 256 + threadIdx.x;
    if (idx >= total) return;
    int c = (idx >> 14) & (C - 1);
    int gidx = idx >> 17;
    float m = stat[2 * gidx], r = stat[2 * gidx + 1];
    float v = (x[idx] - m) * r * g[c] + bta[c];
    x[idx] = gelu_exact(v);
}

// ---------------- generic fp32 SGEMM ----------------
template <int EPI>
__global__ __launch_bounds__(256) void k_gemm(const float* __restrict__ A,
                                              const float* __restrict__ Bm,
                                              const float* __restrict__ bias,
                                              float* __restrict__ C,
                                              int M, int N, int K) {
    __shared__ float As[16][128];
    __shared__ float Bs[16][128];
    int bm = blockIdx.y * 128, bn = blockIdx.x * 128;
    int tid = threadIdx.x;
    int ty = tid >> 4, tx = tid & 15;
    float acc[8][8] = {};
    for (int k0 = 0; k0 < K; k0 += 16) {
#pragma unroll
        for (int i = 0; i < 2; i++) {
            int idx = tid + i * 256;
            int m = idx >> 2, kk = (idx & 3) << 2;
            int row = bm + m;
            float4 v = make_float4(0.f, 0.f, 0.f, 0.f);
            if (row < M) v = *(const float4*)&A[(size_t)row * K + k0 + kk];
            As[kk + 0][m] = v.x; As[kk + 1][m] = v.y; As[kk + 2][m] = v.z; As[kk + 3][m] = v.w;
        }
#pragma unroll
        for (int i = 0; i < 2; i++) {
            int idx = tid + i * 256;
            int kr = idx >> 5, n4 = (idx & 31) << 2;
            float4 v = *(const float4*)&Bm[(size_t)(k0 + kr) * N + bn + n4];
            *(float4*)&Bs[kr][n4] = v;
        }
        __syncthreads();
#pragma unroll
        for (int k = 0; k < 16; k++) {
            float a[8], bb[8];
#pragma unroll
            for (int i = 0; i < 8; i++) a[i] = As[k][ty * 8 + i];
#pragma unroll
            for (int j = 0; j < 8; j++) bb[j] = Bs[k][tx * 8 + j];
#pragma unroll
            for (int i = 0; i < 8; i++)
#pragma unroll
                for (int j = 0; j < 8; j++)
                    acc[i][j] = fmaf(a[i], bb[j], acc[i][j]);
        }
        __syncthreads();
    }
#pragma unroll
    for (int i = 0; i < 8; i++) {
        int row = bm + ty * 8 + i;
        if (row >= M) break;
#pragma unroll
        for (int j = 0; j < 8; j++) {
            int col = bn + tx * 8 + j;
            float v = acc[i][j] + bias[col];
            size_t o = (size_t)row * N + col;
            if (EPI == 2) C[o] += v;
            else C[o] = v;
        }
    }
}

// ---------------- patch embed as implicit-im2col GEMM ----------------
__global__ __launch_bounds__(256) void k_patchgemm(const float* __restrict__ f2,
                                                   const float* __restrict__ W,
                                                   const float* __restrict__ bias,
                                                   const float* __restrict__ postab,
                                                   float* __restrict__ xa) {
    __shared__ float As[16][128];
    __shared__ float Bs[16][128];
    int bm = blockIdx.y * 128, bn = blockIdx.x * 128;
    int tid = threadIdx.x;
    int ty = tid >> 4, tx = tid & 15;
    int bimg = bm >> 8;
    float acc[8][8] = {};
    for (int k0 = 0; k0 < 4096; k0 += 16) {
#pragma unroll
        for (int i = 0; i < 2; i++) {
            int idx = tid + i * 256;
            int m = idx >> 2, kk = (idx & 3) << 2;
            int row = bm + m;
            int p = row & 255;
            int k = k0 + kk;
            int ci = k >> 6, r = k & 63, ky = r >> 3, kx = r & 7;
            int gy = ((p >> 4) << 3) + ky, gx = ((p & 15) << 3) + kx;
            float4 v = *(const float4*)&f2[((size_t)(bimg * 64 + ci) * 128 + gy) * 128 + gx];
            As[kk + 0][m] = v.x; As[kk + 1][m] = v.y; As[kk + 2][m] = v.z; As[kk + 3][m] = v.w;
        }
#pragma unroll
        for (int i = 0; i < 2; i++) {
            int idx = tid + i * 256;
            int n = idx >> 2, kk = (idx & 3) << 2;
            float4 v = *(const float4*)&W[(size_t)(bn + n) * 4096 + k0 + kk];
            Bs[kk + 0][n] = v.x; Bs[kk + 1][n] = v.y; Bs[kk + 2][n] = v.z; Bs[kk + 3][n] = v.w;
        }
        __syncthreads();
#pragma unroll
        for (int k = 0; k < 16; k++) {
            float a[8], bb[8];
#pragma unroll
            for (int i = 0; i < 8; i++) a[i] = As[k][ty * 8 + i];
#pragma unroll
            for (int j = 0; j < 8; j++) bb[j] = Bs[k][tx * 8 + j];
#pragma unroll
            for (int i = 0; i < 8; i++)
#pragma unroll
                for (int j = 0; j < 8; j++)
                    acc[i][j] = fmaf(a[i], bb[j], acc[i][j]);
        }
        __syncthreads();
    }
#pragma unroll
    for (int i = 0; i < 8; i++) {
        int row = bm + ty * 8 + i;
        int p = row & 255;
#pragma unroll
        for (int j = 0; j < 8; j++) {
            int col = bn + tx * 8 + j;
            float v = acc[i][j] + bias[col] + postab[p * 512 + col];
            xa[((size_t)(bimg * 257) + 1 + p) * 512 + col] = v;
        }
    }
}

// ---------------- LayerNorm over D=512 ----------------
__global__ __launch_bounds__(256) void k_ln(const float* __restrict__ x,
                                            const float* __restrict__ g,
                                            const float* __restrict__ bta,
                                            float* __restrict__ o) {
    int row = blockIdx.x, tid = threadIdx.x;
    const float* xr = x + (size_t)row * 512;
    float v0 = xr[tid], v1 = xr[tid + 256];
    __shared__ float rs[256];
    rs[tid] = v0 + v1;
    __syncthreads();
    for (int s = 128; s > 0; s >>= 1) { if (tid < s) rs[tid] += rs[tid + s]; __syncthreads(); }
    float mean = rs[0] * (1.0f / 512.0f);
    __syncthreads();
    float d0 = v0 - mean, d1 = v1 - mean;
    rs[tid] = d0 * d0 + d1 * d1;
    __syncthreads();
    for (int s = 128; s > 0; s >>= 1) { if (tid < s) rs[tid] += rs[tid + s]; __syncthreads(); }
    float rstd = rsqrtf(rs[0] * (1.0f / 512.0f) + EPSV);
    float* orow = o + (size_t)row * 512;
    orow[tid] = d0 * rstd * g[tid] + bta[tid];
    orow[tid + 256] = d1 * rstd * g[tid + 256] + bta[tid + 256];
}

__global__ __launch_bounds__(256) void k_ln_out(const float* __restrict__ x,
                                                const float* __restrict__ g,
                                                const float* __restrict__ bta,
                                                float* __restrict__ out) {
    int row = blockIdx.x, tid = threadIdx.x;
    const float* xr = x + (size_t)row * 512;
    float v0 = xr[tid], v1 = xr[tid + 256];
    __shared__ float rs[256];
    rs[tid] = v0 + v1;
    __syncthreads();
    for (int s = 128; s > 0; s >>= 1) { if (tid < s) rs[tid] += rs[tid + s]; __syncthreads(); }
    float mean = rs[0] * (1.0f / 512.0f);
    __syncthreads();
    float d0 = v0 - mean, d1 = v1 - mean;
    rs[tid] = d0 * d0 + d1 * d1;
    __syncthreads();
    for (int s = 128; s > 0; s >>= 1) { if (tid < s) rs[tid] += rs[tid + s]; __syncthreads(); }
    float rstd = rsqrtf(rs[0] * (1.0f / 512.0f) + EPSV);
    int b = row / 257, t = row % 257;
    float* dst = (t == 0) ? out + (size_t)b * 512
                          : out + 16384 + (size_t)(b * 256 + (t - 1)) * 512;
    dst[tid] = d0 * rstd * g[tid] + bta[tid];
    dst[tid + 256] = d1 * rstd * g[tid + 256] + bta[tid + 256];
}

// ---------------- xPos rotary ----------------
__global__ void k_rope(float* __restrict__ qkv, const float* __restrict__ rt) {
    int idx = blockIdx.x * 256 + threadIdx.x;
    int d2 = idx & 31, h = (idx >> 5) & 7, bt = idx >> 8;
    int d0 = d2 * 2;
    size_t base = (size_t)bt * 1536 + h * 64 + d0;
    const float* r0 = &rt[(h * 64 + d0) * 4];
    float ct = r0[0], st = r0[1], s0 = r0[2], rs0 = r0[3];
    float s1 = r0[6], rs1 = r0[7];
    float q0 = qkv[base], q1 = qkv[base + 1];
    qkv[base]     = (q0 * ct - q1 * st) * s0;
    qkv[base + 1] = (q1 * ct + q0 * st) * s1;
    float k0 = qkv[base + 512], k1 = qkv[base + 513];
    qkv[base + 512] = (k0 * ct - k1 * st) * rs0;
    qkv[base + 513] = (k1 * ct + k0 * st) * rs1;
}

// ---------------- tiled attention: one block per (b,h,q-tile of 64) ----------------
// Two-pass: full score row (257) kept in LDS; 4x4 register blocking both phases.
__global__ __launch_bounds__(256) void k_attn(const float* __restrict__ qkv,
                                              float* __restrict__ y) {
    __shared__ float Qs[64][65];     // [qrow][d], pad 65 -> 2-way on b-side reads (free)
    __shared__ float Ks[64][65];     // K tile, reused as V tile
    __shared__ float sc[64][258];    // full score rows
    __shared__ float red[64][4];
    __shared__ float red2[64][4];
    __shared__ float invrow[64];

    int bid = blockIdx.x;            // ((b*8+h)*5 + qt)
    int qt = bid % 5;
    int bh = bid / 5;
    int h = bh & 7, b = bh >> 3;
    int q0 = qt * 64;
    int tid = threadIdx.x;
    int lrow = tid >> 2, lc4 = (tid & 3) * 16;
    int ty = tid >> 4, tx = tid & 15;

    // ---- load Q tile (scaled by HD^-0.5) ----
    {
        int grow = q0 + lrow;
        if (grow < 257) {
            const float* src = qkv + (size_t)(b * 257 + grow) * 1536 + h * 64 + lc4;
#pragma unroll
            for (int c = 0; c < 4; c++) {
                float4 v = *(const float4*)(src + c * 4);
                Qs[lrow][lc4 + c * 4 + 0] = v.x * 0.125f;
                Qs[lrow][lc4 + c * 4 + 1] = v.y * 0.125f;
                Qs[lrow][lc4 + c * 4 + 2] = v.z * 0.125f;
                Qs[lrow][lc4 + c * 4 + 3] = v.w * 0.125f;
            }
        } else {
#pragma unroll
            for (int c = 0; c < 16; c++) Qs[lrow][lc4 + c] = 0.0f;
        }
    }

    // ---- score phase: S = Q K^T over 5 K-tiles ----
    for (int t = 0; t < 5; t++) {
        int j0 = t * 64;
        {
            int grow = j0 + lrow;
            if (grow < 257) {
                const float* src = qkv + (size_t)(b * 257 + grow) * 1536 + 512 + h * 64 + lc4;
#pragma unroll
                for (int c = 0; c < 4; c++) {
                    float4 v = *(const float4*)(src + c * 4);
                    Ks[lrow][lc4 + c * 4 + 0] = v.x;
                    Ks[lrow][lc4 + c * 4 + 1] = v.y;
                    Ks[lrow][lc4 + c * 4 + 2] = v.z;
                    Ks[lrow][lc4 + c * 4 + 3] = v.w;
                }
            } else {
#pragma unroll
                for (int c = 0; c < 16; c++) Ks[lrow][lc4 + c] = 0.0f;
            }
        }
        __syncthreads();
        float accs[4][4] = {};
#pragma unroll 8
        for (int d = 0; d < 64; d++) {
            float a4[4], b4[4];
#pragma unroll
            for (int i = 0; i < 4; i++) a4[i] = Qs[ty * 4 + i][d];
#pragma unroll
            for (int j = 0; j < 4; j++) b4[j] = Ks[tx * 4 + j][d];
#pragma unroll
            for (int i = 0; i < 4; i++)
#pragma unroll
                for (int j = 0; j < 4; j++)
                    accs[i][j] = fmaf(a4[i], b4[j], accs[i][j]);
        }
#pragma unroll
        for (int i = 0; i < 4; i++)
#pragma unroll
            for (int j = 0; j < 4; j++) {
                int jj = j0 + tx * 4 + j;
                if (jj < 257) sc[ty * 4 + i][jj] = accs[i][j];
            }
        __syncthreads();
    }

    // ---- softmax over 257 (4 threads per row) ----
    {
        int r = tid >> 2, sub = tid & 3;
        float m = -1e30f;
        for (int j = sub; j < 257; j += 4) m = fmaxf(m, sc[r][j]);
        red[r][sub] = m;
        __syncthreads();
        float mx = fmaxf(fmaxf(red[r][0], red[r][1]), fmaxf(red[r][2], red[r][3]));
        float s = 0.0f;
        for (int j = sub; j < 257; j += 4) {
            float e = __expf(sc[r][j] - mx);
            sc[r][j] = e;
            s += e;
        }
        red2[r][sub] = s;
        __syncthreads();
        if (sub == 0)
            invrow[r] = 1.0f / (red2[r][0] + red2[r][1] + red2[r][2] + red2[r][3]);
        __syncthreads();
    }

    // ---- PV phase over 5 V-tiles ----
    float po[4][4] = {};
    for (int t = 0; t < 5; t++) {
        int j0 = t * 64;
        int jmax = (t == 4) ? 1 : 64;
        {
            int grow = j0 + lrow;
            if (grow < 257) {
                const float* src = qkv + (size_t)(b * 257 + grow) * 1536 + 1024 + h * 64 + lc4;
#pragma unroll
                for (int c = 0; c < 4; c++) {
                    float4 v = *(const float4*)(src + c * 4);
                    Ks[lrow][lc4 + c * 4 + 0] = v.x;
                    Ks[lrow][lc4 + c * 4 + 1] = v.y;
                    Ks[lrow][lc4 + c * 4 + 2] = v.z;
                    Ks[lrow][lc4 + c * 4 + 3] = v.w;
                }
            }
        }
        __syncthreads();
#pragma unroll 4
        for (int j = 0; j < jmax; j++) {
            float p4[4], v4[4];
#pragma unroll
            for (int i = 0; i < 4; i++) p4[i] = sc[ty * 4 + i][j0 + j];
#pragma unroll
            for (int jj = 0; jj < 4; jj++) v4[jj] = Ks[j][tx * 4 + jj];
#pragma unroll
            for (int i = 0; i < 4; i++)
#pragma unroll
                for (int jj = 0; jj < 4; jj++)
                    po[i][jj] = fmaf(p4[i], v4[jj], po[i][jj]);
        }
        __syncthreads();
    }

    // ---- write out ----
#pragma unroll
    for (int i = 0; i < 4; i++) {
        int grow = q0 + ty * 4 + i;
        if (grow < 257) {
            float inv = invrow[ty * 4 + i];
            float* dst = y + (size_t)(b * 257 + grow) * 512 + h * 64 + tx * 4;
#pragma unroll
            for (int jj = 0; jj < 4; jj++) dst[jj] = po[i][jj] * inv;
        }
    }
}

// ---------------- SwiGLU combine ----------------
__global__ void k_swiglu(float* __restrict__ h1, const float* __restrict__ h2) {
    size_t idx = (size_t)blockIdx.x * 256 + threadIdx.x;
    float a = h1[idx];
    h1[idx] = a / (1.0f + __expf(-a)) * h2[idx];
}

// ---------------- host launch ----------------
extern "C" void kernel_launch(void* const* d_in, const int* in_sizes, int n_in,
                              void* d_out, int out_size, void* d_ws, size_t ws_size,
                              hipStream_t stream) {
    const float* x       = (const float*)d_in[0];
    const float* conv1_w = (const float*)d_in[1];
    const float* conv1_b = (const float*)d_in[2];
    const float* gn1_g   = (const float*)d_in[3];
    const float* gn1_b   = (const float*)d_in[4];
    const float* conv2_w = (const float*)d_in[5];
    const float* conv2_b = (const float*)d_in[6];
    const float* gn2_g   = (const float*)d_in[7];
    const float* gn2_b   = (const float*)d_in[8];
    const float* patch_w = (const float*)d_in[9];
    const float* patch_b = (const float*)d_in[10];
    const float* cls_tok = (const float*)d_in[11];
    const float* ln1_g   = (const float*)d_in[12];
    const float* ln1_b   = (const float*)d_in[13];
    const float* qkv_w   = (const float*)d_in[14];
    const float* qkv_b   = (const float*)d_in[15];
    const float* out_w   = (const float*)d_in[16];
    const float* out_b   = (const float*)d_in[17];
    const float* ln2_g   = (const float*)d_in[18];
    const float* ln2_b   = (const float*)d_in[19];
    const float* w1_w    = (const float*)d_in[20];
    const float* w1_b    = (const float*)d_in[21];
    const float* w2_w    = (const float*)d_in[22];
    const float* w2_b    = (const float*)d_in[23];
    const float* w3_w    = (const float*)d_in[24];
    const float* w3_b    = (const float*)d_in[25];
    const float* fn_g    = (const float*)d_in[26];
    const float* fn_b    = (const float*)d_in[27];
    float* out = (float*)d_out;
    float* ws  = (float*)d_ws;

    const size_t O_F1  = 0;
    const size_t O_F2  = 16777216;
    const size_t O_H1  = O_F2;
    const size_t O_H2  = O_F2 + 16842752;
    const size_t O_N   = 50462720;
    const size_t O_Y   = 54673408;
    const size_t O_XA  = 58884096;
    const size_t O_ST  = 63094784;
    const size_t O_PT  = 63095296;
    const size_t O_RT  = 63226368;
    const size_t O_W1T = 63228416;
    const size_t O_W2T = 63229440;
    const size_t NEEDF = 63247872;
    if (ws_size < NEEDF * sizeof(float)) {
        k_wsfail<<<1, 1, 0, stream>>>(out);
        return;
    }
    float* f1     = ws + O_F1;
    float* qkv    = ws + O_F1;
    float* f2     = ws + O_F2;
    float* h1     = ws + O_H1;
    float* h2     = ws + O_H2;
    float* nb     = ws + O_N;
    float* yb     = ws + O_Y;
    float* xa     = ws + O_XA;
    float* stat   = ws + O_ST;
    float* postab = ws + O_PT;
    float* ropet  = ws + O_RT;
    float* w1t    = ws + O_W1T;
    float* w2t    = ws + O_W2T;

    k_wt<<<4, 256, 0, stream>>>(conv1_w, w1t, 32, 27);
    k_wt<<<72, 256, 0, stream>>>(conv2_w, w2t, 64, 288);
    k_tables<<<512, 256, 0, stream>>>(postab, ropet);

    k_conv<3, 32><<<dim3(64, 32), 256, 0, stream>>>(x, w1t, conv1_b, f1);
    k_gnstats<<<128, 256, 0, stream>>>(f1, stat, 131072);
    k_gnapply<<<65536, 256, 0, stream>>>(f1, stat, gn1_g, gn1_b, 32, 16777216);
    k_conv<32, 64><<<dim3(64, 32), 256, 0, stream>>>(f1, w2t, conv2_b, f2);
    k_gnstats<<<256, 256, 0, stream>>>(f2, stat, 131072);
    k_gnapply<<<131072, 256, 0, stream>>>(f2, stat, gn2_g, gn2_b, 64, 33554432);

    k_patchgemm<<<dim3(4, 64), 256, 0, stream>>>(f2, patch_w, patch_b, postab, xa);
    k_cls<<<64, 256, 0, stream>>>(cls_tok, xa);

    for (int l = 0; l < 8; l++) {
        k_ln<<<8224, 256, 0, stream>>>(xa, ln1_g + l * 512, ln1_b + l * 512, nb);
        k_gemm<1><<<dim3(12, 65), 256, 0, stream>>>(nb, qkv_w + (size_t)l * 512 * 1536,
                                                    qkv_b + l * 1536, qkv, 8224, 1536, 512);
        k_rope<<<8224, 256, 0, stream>>>(qkv, ropet);
        k_attn<<<1280, 256, 0, stream>>>(qkv, yb);
        k_gemm<2><<<dim3(4, 65), 256, 0, stream>>>(yb, out_w + (size_t)l * 512 * 512,
                                                   out_b + l * 512, xa, 8224, 512, 512);
        k_ln<<<8224, 256, 0, stream>>>(xa, ln2_g + l * 512, ln2_b + l * 512, nb);
        k_gemm<1><<<dim3(16, 65), 256, 0, stream>>>(nb, w1_w + (size_t)l * 512 * 2048,
                                                    w1_b + l * 2048, h1, 8224, 2048, 512);
        k_gemm<1><<<dim3(16, 65), 256, 0, stream>>>(nb, w2_w + (size_t)l * 512 * 2048,
                                                    w2_b + l * 2048, h2, 8224, 2048, 512);
        k_swiglu<<<65792, 256, 0, stream>>>(h1, h2);
        k_gemm<2><<<dim3(4, 65), 256, 0, stream>>>(h1, w3_w + (size_t)l * 2048 * 512,
                                                   w3_b + l * 512, xa, 8224, 512, 2048);
    }
    k_ln_out<<<8224, 256, 0, stream>>>(xa, fn_g, fn_b, out);
}

// Round 4
// 4600.633 us; speedup vs baseline: 3.8625x; 2.6878x over previous
//
#include <hip/hip_runtime.h>

#define EPSV 1e-5f
typedef unsigned short u16;
typedef short bf16x8 __attribute__((ext_vector_type(8)));
typedef float f32x4 __attribute__((ext_vector_type(4)));

__device__ __forceinline__ float gelu_exact(float x) {
    return 0.5f * x * (1.0f + erff(x * 0.7071067811865475f));
}
__device__ __forceinline__ u16 to_bf(float x) {
    union { float f; unsigned u; } c; c.f = x;
    unsigned r = c.u + 0x7fffu + ((c.u >> 16) & 1u);
    return (u16)(r >> 16);
}
__device__ __forceinline__ float to_f(u16 h) {
    union { unsigned u; float f; } c; c.u = ((unsigned)h) << 16;
    return c.f;
}
__device__ __forceinline__ void gload_lds16(const void* g, void* l) {
    __builtin_amdgcn_global_load_lds((const __attribute__((address_space(1))) unsigned int*)g,
                                     (__attribute__((address_space(3))) unsigned int*)l, 16, 0, 0);
}

// ---------------- tiny setup kernels ----------------
__global__ void k_wsfail(float* out) { out[0] = 1.0e9f; }

__global__ void k_wt(const float* __restrict__ w, float* __restrict__ wt, int cout, int cin9) {
    int idx = blockIdx.x * 256 + threadIdx.x;
    if (idx < cout * cin9) {
        int co = idx / cin9, k = idx % cin9;
        wt[k * cout + co] = w[idx];
    }
}

__global__ void k_tables(float* __restrict__ postab, float* __restrict__ ropetab) {
    int idx = blockIdx.x * 256 + threadIdx.x;
    if (idx < 256 * 512) {
        int p = idx >> 9, j = idx & 511;
        float coord = (j < 256) ? (float)(p >> 4) : (float)(p & 15);
        int jm = j & 127;
        float om = powf(10000.0f, -(float)jm / 128.0f);
        float arg = coord * om;
        postab[idx] = ((j >> 7) & 1) ? cosf(arg) : sinf(arg);
    }
    if (idx < 512) {
        // xpos tables indexed by HEAD h (reference quirk): n_pos = H = 8
        int h = idx >> 6, d = idx & 63;
        float freq = (float)h * powf(10000.0f, -(float)(d >> 1) / 32.0f);
        float sv = (2.0f * (float)(d & 31) + 25.6f) / 89.6f;
        float pw = ((float)h - 4.0f) / 512.0f;
        float sc = powf(sv, pw);
        ropetab[idx * 4 + 0] = cosf(freq);
        ropetab[idx * 4 + 1] = sinf(freq);
        ropetab[idx * 4 + 2] = sc;
        ropetab[idx * 4 + 3] = 1.0f / sc;
    }
}

__global__ void k_cls(const float* __restrict__ cls, float* __restrict__ xa) {
    int idx = blockIdx.x * 256 + threadIdx.x;
    int b = idx >> 9, d = idx & 511;
    xa[(size_t)(b * 257) * 512 + d] = cls[d];
}

// fp32 [K][N] -> bf16 [N][K] transpose-convert, z = layer (or z=0 with pre-offset ptrs)
__global__ __launch_bounds__(256) void k_wcvtT(const float* __restrict__ src,
                                               u16* __restrict__ dst, int K, int N) {
    __shared__ float s[32][33];
    int z = blockIdx.z;
    src += (size_t)z * K * N;
    dst += (size_t)z * K * N;
    int k0 = blockIdx.y * 32, n0 = blockIdx.x * 32;
    int t = threadIdx.x, r = t >> 3, c4 = (t & 7) * 4;
    float4 v = *(const float4*)&src[(size_t)(k0 + r) * N + n0 + c4];
    s[r][c4 + 0] = v.x; s[r][c4 + 1] = v.y; s[r][c4 + 2] = v.z; s[r][c4 + 3] = v.w;
    __syncthreads();
    ushort4 o;
    o.x = to_bf(s[c4 + 0][r]); o.y = to_bf(s[c4 + 1][r]);
    o.z = to_bf(s[c4 + 2][r]); o.w = to_bf(s[c4 + 3][r]);
    *(ushort4*)&dst[(size_t)(n0 + r) * K + k0 + c4] = o;
}

// elementwise fp32 -> bf16 (patch_w is already [N][K] with matching k-order)
__global__ void k_cvt(const float* __restrict__ src, u16* __restrict__ dst) {
    int i = (blockIdx.x * 256 + threadIdx.x) * 4;
    float4 v = *(const float4*)&src[i];
    ushort4 o;
    o.x = to_bf(v.x); o.y = to_bf(v.y); o.z = to_bf(v.z); o.w = to_bf(v.w);
    *(ushort4*)&dst[i] = o;
}

// ---------------- direct conv (3x3, pad 1) ----------------
template <int CIN, int COUT>
__global__ __launch_bounds__(256) void k_conv(const float* __restrict__ in,
                                              const float* __restrict__ wt,   // [CIN*9][COUT]
                                              const float* __restrict__ bias,
                                              float* __restrict__ out) {
    __shared__ float s_in[CIN][18][18];
    int b = blockIdx.y;
    int tile = blockIdx.x;
    int y0 = (tile >> 3) << 4;
    int x0 = (tile & 7) << 4;
    int tid = threadIdx.x;
    const int TOT = CIN * 324;
    for (int idx = tid; idx < TOT; idx += 256) {
        int ci = idx / 324, r = idx % 324;
        int ly = r / 18, lx = r % 18;
        int gy = y0 + ly - 1, gx = x0 + lx - 1;
        float v = 0.0f;
        if (gy >= 0 && gy < 128 && gx >= 0 && gx < 128)
            v = in[((size_t)(b * CIN + ci) * 128 + gy) * 128 + gx];
        s_in[ci][ly][lx] = v;
    }
    __syncthreads();
    int py = tid >> 4, px = tid & 15;
    float acc[COUT];
#pragma unroll
    for (int co = 0; co < COUT; co++) acc[co] = bias[co];
    for (int ci = 0; ci < CIN; ci++) {
#pragma unroll
        for (int dy = 0; dy < 3; dy++) {
#pragma unroll
            for (int dx = 0; dx < 3; dx++) {
                float v = s_in[ci][py + dy][px + dx];
                const float* wr = &wt[(ci * 9 + dy * 3 + dx) * COUT];
#pragma unroll
                for (int co = 0; co < COUT; co++)
                    acc[co] = fmaf(wr[co], v, acc[co]);
            }
        }
    }
    int oy = y0 + py, ox = x0 + px;
#pragma unroll
    for (int co = 0; co < COUT; co++)
        out[((size_t)(b * COUT + co) * 128 + oy) * 128 + ox] = acc[co];
}

// ---------------- GroupNorm ----------------
__global__ __launch_bounds__(256) void k_gnstats(const float* __restrict__ x,
                                                 float* __restrict__ stat, int n) {
    int bid = blockIdx.x, tid = threadIdx.x;
    const float* xp = x + (size_t)bid * n;
    double ds = 0.0, dq = 0.0;
    for (int i = tid; i < n; i += 256) {
        float v = xp[i];
        ds += v;
        dq += (double)v * v;
    }
    __shared__ double rs[256], rq[256];
    rs[tid] = ds; rq[tid] = dq;
    __syncthreads();
    for (int s = 128; s > 0; s >>= 1) {
        if (tid < s) { rs[tid] += rs[tid + s]; rq[tid] += rq[tid + s]; }
        __syncthreads();
    }
    if (tid == 0) {
        double m = rs[0] / n;
        double var = rq[0] / n - m * m;
        stat[2 * bid] = (float)m;
        stat[2 * bid + 1] = (float)(1.0 / sqrt(var + 1e-5));
    }
}

__global__ void k_gnapply(float* __restrict__ x, const float* __restrict__ stat,
                          const float* __restrict__ g, const float* __restrict__ bta,
                          int C, int total) {
    int idx = blockIdx.x * 256 + threadIdx.x;
    if (idx >= total) return;
    int c = (idx >> 14) & (C - 1);
    int gidx = idx >> 17;
    float m = stat[2 * gidx], r = stat[2 * gidx + 1];
    float v = (x[idx] - m) * r * g[c] + bta[c];
    x[idx] = gelu_exact(v);
}

// read fp32, write bf16 (for f2 -> patch GEMM input)
__global__ void k_gnapply_bf(const float* __restrict__ x, const float* __restrict__ stat,
                             const float* __restrict__ g, const float* __restrict__ bta,
                             u16* __restrict__ xb, int C, int total) {
    int idx = blockIdx.x * 256 + threadIdx.x;
    if (idx >= total) return;
    int c = (idx >> 14) & (C - 1);
    int gidx = idx >> 17;
    float m = stat[2 * gidx], r = stat[2 * gidx + 1];
    float v = (x[idx] - m) * r * g[c] + bta[c];
    xb[idx] = to_bf(gelu_exact(v));
}

// ---------------- bf16 MFMA GEMM ----------------
// A bf16 (MODE 0: [M,K] row-major; MODE 1: implicit im2col of f2b), Bt bf16 [N][K].
// EPI 1: fp32 C = acc+bias. EPI 2: fp32 C += acc+bias. EPI 4: bf16 C = acc+bias.
// EPI 3: patch -> xa scatter + postab.
template <int MODE, int EPI>
__global__ __launch_bounds__(256) void k_bgemm(const u16* __restrict__ A,
                                               const u16* __restrict__ Bt,
                                               const float* __restrict__ bias,
                                               void* __restrict__ Cp,
                                               const float* __restrict__ postab,
                                               int M, int N, int K) {
    __shared__ u16 ldsA[8192];   // [kg 8][row 128][8]
    __shared__ u16 ldsB[8192];   // [col 128][kg^swz 8][8]
    int tid = threadIdx.x;
    int w = tid >> 6, lane = tid & 63;
    int bm = blockIdx.y * 128, bn = blockIdx.x * 128;
    int wr = w >> 1, wc = w & 1;
    int l15 = lane & 15, l16 = lane >> 4;

    f32x4 acc[4][4];
    f32x4 zf = {0.f, 0.f, 0.f, 0.f};
#pragma unroll
    for (int m = 0; m < 4; m++)
#pragma unroll
        for (int n = 0; n < 4; n++) acc[m][n] = zf;

    for (int k0 = 0; k0 < K; k0 += 64) {
        // stage A tile: 8 kg x 128 rows x 16B
#pragma unroll
        for (int i = 0; i < 4; i++) {
            int chunk = (w * 4 + i) * 64 + lane;
            int kg = chunk >> 7, row = chunk & 127;
            const u16* src;
            if (MODE == 0) {
                int grow = bm + row;
                if (grow > M - 1) grow = M - 1;
                src = A + (size_t)grow * K + k0 + kg * 8;
            } else {
                int grow = bm + row;
                int bimg = grow >> 8, p = grow & 255;
                int kga = (k0 >> 3) + kg;
                int ci = kga >> 3, ky = kga & 7;
                int gy = ((p >> 4) << 3) + ky, gx0 = (p & 15) << 3;
                src = A + (((size_t)(bimg * 64 + ci) * 128 + gy) << 7) + gx0;
            }
            gload_lds16(src, &ldsA[(w * 4 + i) * 512]);
        }
        // stage B tile: 128 cols x 8 kg x 16B, kg XOR-preswizzled by col&7
#pragma unroll
        for (int i = 0; i < 4; i++) {
            int chunk = (w * 4 + i) * 64 + lane;
            int col = chunk >> 3, kgs = chunk & 7;
            int kg_src = kgs ^ (col & 7);
            const u16* src = Bt + (size_t)(bn + col) * K + k0 + kg_src * 8;
            gload_lds16(src, &ldsB[(w * 4 + i) * 512]);
        }
        __syncthreads();

        bf16x8 af[4][2], bfr[4][2];
#pragma unroll
        for (int kk = 0; kk < 2; kk++) {
            int kga = kk * 4 + l16;
#pragma unroll
            for (int m = 0; m < 4; m++) {
                int row_l = wr * 64 + m * 16 + l15;
                af[m][kk] = *(const bf16x8*)&ldsA[(kga * 128 + row_l) * 8];
            }
#pragma unroll
            for (int n = 0; n < 4; n++) {
                int col_l = wc * 64 + n * 16 + l15;
                bfr[n][kk] = *(const bf16x8*)&ldsB[(col_l * 8 + (kga ^ (col_l & 7))) * 8];
            }
        }
#pragma unroll
        for (int m = 0; m < 4; m++)
#pragma unroll
            for (int n = 0; n < 4; n++) {
                acc[m][n] = __builtin_amdgcn_mfma_f32_16x16x32_bf16(af[m][0], bfr[n][0], acc[m][n], 0, 0, 0);
                acc[m][n] = __builtin_amdgcn_mfma_f32_16x16x32_bf16(af[m][1], bfr[n][1], acc[m][n], 0, 0, 0);
            }
        __syncthreads();
    }

    // epilogue: C/D layout col = lane&15, row = (lane>>4)*4 + reg
#pragma unroll
    for (int n = 0; n < 4; n++) {
        int gcol = bn + wc * 64 + n * 16 + l15;
        float bv = bias[gcol];
#pragma unroll
        for (int m = 0; m < 4; m++) {
#pragma unroll
            for (int r = 0; r < 4; r++) {
                int grow = bm + wr * 64 + m * 16 + l16 * 4 + r;
                float v = acc[m][n][r] + bv;
                if (EPI == 1) {
                    if (grow < M) ((float*)Cp)[(size_t)grow * N + gcol] = v;
                } else if (EPI == 2) {
                    if (grow < M) ((float*)Cp)[(size_t)grow * N + gcol] += v;
                } else if (EPI == 4) {
                    if (grow < M) ((u16*)Cp)[(size_t)grow * N + gcol] = to_bf(v);
                } else {
                    int bimg = grow >> 8, p = grow & 255;
                    v += postab[p * 512 + gcol];
                    ((float*)Cp)[((size_t)(bimg * 257) + 1 + p) * 512 + gcol] = v;
                }
            }
        }
    }
}

// ---------------- LayerNorm over D=512, bf16 out ----------------
__global__ __launch_bounds__(256) void k_lnb(const float* __restrict__ x,
                                             const float* __restrict__ g,
                                             const float* __restrict__ bta,
                                             u16* __restrict__ o) {
    int row = blockIdx.x, tid = threadIdx.x;
    const float* xr = x + (size_t)row * 512;
    float v0 = xr[tid], v1 = xr[tid + 256];
    __shared__ float rs[256];
    rs[tid] = v0 + v1;
    __syncthreads();
    for (int s = 128; s > 0; s >>= 1) { if (tid < s) rs[tid] += rs[tid + s]; __syncthreads(); }
    float mean = rs[0] * (1.0f / 512.0f);
    __syncthreads();
    float d0 = v0 - mean, d1 = v1 - mean;
    rs[tid] = d0 * d0 + d1 * d1;
    __syncthreads();
    for (int s = 128; s > 0; s >>= 1) { if (tid < s) rs[tid] += rs[tid + s]; __syncthreads(); }
    float rstd = rsqrtf(rs[0] * (1.0f / 512.0f) + EPSV);
    u16* orow = o + (size_t)row * 512;
    orow[tid] = to_bf(d0 * rstd * g[tid] + bta[tid]);
    orow[tid + 256] = to_bf(d1 * rstd * g[tid + 256] + bta[tid + 256]);
}

// final LN with output remap (fp32 out)
__global__ __launch_bounds__(256) void k_ln_out(const float* __restrict__ x,
                                                const float* __restrict__ g,
                                                const float* __restrict__ bta,
                                                float* __restrict__ out) {
    int row = blockIdx.x, tid = threadIdx.x;
    const float* xr = x + (size_t)row * 512;
    float v0 = xr[tid], v1 = xr[tid + 256];
    __shared__ float rs[256];
    rs[tid] = v0 + v1;
    __syncthreads();
    for (int s = 128; s > 0; s >>= 1) { if (tid < s) rs[tid] += rs[tid + s]; __syncthreads(); }
    float mean = rs[0] * (1.0f / 512.0f);
    __syncthreads();
    float d0 = v0 - mean, d1 = v1 - mean;
    rs[tid] = d0 * d0 + d1 * d1;
    __syncthreads();
    for (int s = 128; s > 0; s >>= 1) { if (tid < s) rs[tid] += rs[tid + s]; __syncthreads(); }
    float rstd = rsqrtf(rs[0] * (1.0f / 512.0f) + EPSV);
    int b = row / 257, t = row % 257;
    float* dst = (t == 0) ? out + (size_t)b * 512
                          : out + 16384 + (size_t)(b * 256 + (t - 1)) * 512;
    dst[tid] = d0 * rstd * g[tid] + bta[tid];
    dst[tid + 256] = d1 * rstd * g[tid + 256] + bta[tid + 256];
}

// ---------------- xPos rotary (fp32 qkv in-place) ----------------
__global__ void k_rope(float* __restrict__ qkv, const float* __restrict__ rt) {
    int idx = blockIdx.x * 256 + threadIdx.x;
    int d2 = idx & 31, h = (idx >> 5) & 7, bt = idx >> 8;
    int d0 = d2 * 2;
    size_t base = (size_t)bt * 1536 + h * 64 + d0;
    const float* r0 = &rt[(h * 64 + d0) * 4];
    float ct = r0[0], st = r0[1], s0 = r0[2], rs0 = r0[3];
    float s1 = r0[6], rs1 = r0[7];
    float q0 = qkv[base], q1 = qkv[base + 1];
    qkv[base]     = (q0 * ct - q1 * st) * s0;
    qkv[base + 1] = (q1 * ct + q0 * st) * s1;
    float k0 = qkv[base + 512], k1 = qkv[base + 513];
    qkv[base + 512] = (k0 * ct - k1 * st) * rs0;
    qkv[base + 513] = (k1 * ct + k0 * st) * rs1;
}

// ---------------- tiled attention (fp32 compute, bf16 y out) ----------------
__global__ __launch_bounds__(256) void k_attn(const float* __restrict__ qkv,
                                              u16* __restrict__ y) {
    __shared__ float Qs[64][65];
    __shared__ float Ks[64][65];
    __shared__ float sc[64][258];
    __shared__ float red[64][4];
    __shared__ float red2[64][4];
    __shared__ float invrow[64];

    int bid = blockIdx.x;            // ((b*8+h)*5 + qt)
    int qt = bid % 5;
    int bh = bid / 5;
    int h = bh & 7, b = bh >> 3;
    int q0 = qt * 64;
    int tid = threadIdx.x;
    int lrow = tid >> 2, lc4 = (tid & 3) * 16;
    int ty = tid >> 4, tx = tid & 15;

    {
        int grow = q0 + lrow;
        if (grow < 257) {
            const float* src = qkv + (size_t)(b * 257 + grow) * 1536 + h * 64 + lc4;
#pragma unroll
            for (int c = 0; c < 4; c++) {
                float4 v = *(const float4*)(src + c * 4);
                Qs[lrow][lc4 + c * 4 + 0] = v.x * 0.125f;
                Qs[lrow][lc4 + c * 4 + 1] = v.y * 0.125f;
                Qs[lrow][lc4 + c * 4 + 2] = v.z * 0.125f;
                Qs[lrow][lc4 + c * 4 + 3] = v.w * 0.125f;
            }
        } else {
#pragma unroll
            for (int c = 0; c < 16; c++) Qs[lrow][lc4 + c] = 0.0f;
        }
    }

    for (int t = 0; t < 5; t++) {
        int j0 = t * 64;
        {
            int grow = j0 + lrow;
            if (grow < 257) {
                const float* src = qkv + (size_t)(b * 257 + grow) * 1536 + 512 + h * 64 + lc4;
#pragma unroll
                for (int c = 0; c < 4; c++) {
                    float4 v = *(const float4*)(src + c * 4);
                    Ks[lrow][lc4 + c * 4 + 0] = v.x;
                    Ks[lrow][lc4 + c * 4 + 1] = v.y;
                    Ks[lrow][lc4 + c * 4 + 2] = v.z;
                    Ks[lrow][lc4 + c * 4 + 3] = v.w;
                }
            } else {
#pragma unroll
                for (int c = 0; c < 16; c++) Ks[lrow][lc4 + c] = 0.0f;
            }
        }
        __syncthreads();
        float accs[4][4] = {};
#pragma unroll 8
        for (int d = 0; d < 64; d++) {
            float a4[4], b4[4];
#pragma unroll
            for (int i = 0; i < 4; i++) a4[i] = Qs[ty * 4 + i][d];
#pragma unroll
            for (int j = 0; j < 4; j++) b4[j] = Ks[tx * 4 + j][d];
#pragma unroll
            for (int i = 0; i < 4; i++)
#pragma unroll
                for (int j = 0; j < 4; j++)
                    accs[i][j] = fmaf(a4[i], b4[j], accs[i][j]);
        }
#pragma unroll
        for (int i = 0; i < 4; i++)
#pragma unroll
            for (int j = 0; j < 4; j++) {
                int jj = j0 + tx * 4 + j;
                if (jj < 257) sc[ty * 4 + i][jj] = accs[i][j];
            }
        __syncthreads();
    }

    {
        int r = tid >> 2, sub = tid & 3;
        float m = -1e30f;
        for (int j = sub; j < 257; j += 4) m = fmaxf(m, sc[r][j]);
        red[r][sub] = m;
        __syncthreads();
        float mx = fmaxf(fmaxf(red[r][0], red[r][1]), fmaxf(red[r][2], red[r][3]));
        float s = 0.0f;
        for (int j = sub; j < 257; j += 4) {
            float e = __expf(sc[r][j] - mx);
            sc[r][j] = e;
            s += e;
        }
        red2[r][sub] = s;
        __syncthreads();
        if (sub == 0)
            invrow[r] = 1.0f / (red2[r][0] + red2[r][1] + red2[r][2] + red2[r][3]);
        __syncthreads();
    }

    float po[4][4] = {};
    for (int t = 0; t < 5; t++) {
        int j0 = t * 64;
        int jmax = (t == 4) ? 1 : 64;
        {
            int grow = j0 + lrow;
            if (grow < 257) {
                const float* src = qkv + (size_t)(b * 257 + grow) * 1536 + 1024 + h * 64 + lc4;
#pragma unroll
                for (int c = 0; c < 4; c++) {
                    float4 v = *(const float4*)(src + c * 4);
                    Ks[lrow][lc4 + c * 4 + 0] = v.x;
                    Ks[lrow][lc4 + c * 4 + 1] = v.y;
                    Ks[lrow][lc4 + c * 4 + 2] = v.z;
                    Ks[lrow][lc4 + c * 4 + 3] = v.w;
                }
            }
        }
        __syncthreads();
#pragma unroll 4
        for (int j = 0; j < jmax; j++) {
            float p4[4], v4[4];
#pragma unroll
            for (int i = 0; i < 4; i++) p4[i] = sc[ty * 4 + i][j0 + j];
#pragma unroll
            for (int jj = 0; jj < 4; jj++) v4[jj] = Ks[j][tx * 4 + jj];
#pragma unroll
            for (int i = 0; i < 4; i++)
#pragma unroll
                for (int jj = 0; jj < 4; jj++)
                    po[i][jj] = fmaf(p4[i], v4[jj], po[i][jj]);
        }
        __syncthreads();
    }

#pragma unroll
    for (int i = 0; i < 4; i++) {
        int grow = q0 + ty * 4 + i;
        if (grow < 257) {
            float inv = invrow[ty * 4 + i];
            u16* dst = y + (size_t)(b * 257 + grow) * 512 + h * 64 + tx * 4;
#pragma unroll
            for (int jj = 0; jj < 4; jj++) dst[jj] = to_bf(po[i][jj] * inv);
        }
    }
}

// ---------------- SwiGLU combine: hb = silu(h1)*h2 (bf16 in/out) ----------------
__global__ void k_swiglu(const u16* __restrict__ h1, const u16* __restrict__ h2,
                         u16* __restrict__ hb) {
    int i = (blockIdx.x * 256 + threadIdx.x) * 4;
    ushort4 a = *(const ushort4*)&h1[i];
    ushort4 b = *(const ushort4*)&h2[i];
    ushort4 o;
    float x;
    x = to_f(a.x); o.x = to_bf(x / (1.0f + __expf(-x)) * to_f(b.x));
    x = to_f(a.y); o.y = to_bf(x / (1.0f + __expf(-x)) * to_f(b.y));
    x = to_f(a.z); o.z = to_bf(x / (1.0f + __expf(-x)) * to_f(b.z));
    x = to_f(a.w); o.w = to_bf(x / (1.0f + __expf(-x)) * to_f(b.w));
    *(ushort4*)&hb[i] = o;
}

// ---------------- host launch ----------------
extern "C" void kernel_launch(void* const* d_in, const int* in_sizes, int n_in,
                              void* d_out, int out_size, void* d_ws, size_t ws_size,
                              hipStream_t stream) {
    const float* x       = (const float*)d_in[0];
    const float* conv1_w = (const float*)d_in[1];
    const float* conv1_b = (const float*)d_in[2];
    const float* gn1_g   = (const float*)d_in[3];
    const float* gn1_b   = (const float*)d_in[4];
    const float* conv2_w = (const float*)d_in[5];
    const float* conv2_b = (const float*)d_in[6];
    const float* gn2_g   = (const float*)d_in[7];
    const float* gn2_b   = (const float*)d_in[8];
    const float* patch_w = (const float*)d_in[9];
    const float* patch_b = (const float*)d_in[10];
    const float* cls_tok = (const float*)d_in[11];
    const float* ln1_g   = (const float*)d_in[12];
    const float* ln1_b   = (const float*)d_in[13];
    const float* qkv_w   = (const float*)d_in[14];
    const float* qkv_b   = (const float*)d_in[15];
    const float* out_w   = (const float*)d_in[16];
    const float* out_b   = (const float*)d_in[17];
    const float* ln2_g   = (const float*)d_in[18];
    const float* ln2_b   = (const float*)d_in[19];
    const float* w1_w    = (const float*)d_in[20];
    const float* w1_b    = (const float*)d_in[21];
    const float* w2_w    = (const float*)d_in[22];
    const float* w2_b    = (const float*)d_in[23];
    const float* w3_w    = (const float*)d_in[24];
    const float* w3_b    = (const float*)d_in[25];
    const float* fn_g    = (const float*)d_in[26];
    const float* fn_b    = (const float*)d_in[27];
    float* out = (float*)d_out;
    char* wsb  = (char*)d_ws;

    // byte offsets (lifetime-aliased regions). Total 246,044,672 B (< 252,991,488 proven avail).
    const size_t O_R1    = 0;           // 134,217,728: f2 fp32 | {h1b,h2b,hb,nb,yb}
    const size_t O_H1B   = O_R1 + 0;
    const size_t O_H2B   = O_R1 + 33685504;
    const size_t O_HB    = O_R1 + 67371008;
    const size_t O_NB    = O_R1 + 101056512;
    const size_t O_Y     = O_R1 + 109477888;
    const size_t O_R2    = 134217728;   // 67,108,864: f1 fp32 | f2b bf16 | qkv fp32
    const size_t O_XA    = 201326592;   // 16,842,752
    const size_t O_PWT   = 218169344;   // patchT bf16 4,194,304
    const size_t O_QKVT  = 222363648;   // 12,582,912 (8 layers)
    const size_t O_OUTT  = 234946560;   // 4,194,304 (8 layers)
    const size_t O_WL    = 239140864;   // 6,291,456 per-layer rotating w1/w2/w3
    const size_t O_PT    = 245432320;   // postab 524,288
    const size_t O_RT    = 245956608;   // ropet 8,192
    const size_t O_CW1   = 245964800;   // conv1 wT 4,096
    const size_t O_CW2   = 245968896;   // conv2 wT 73,728
    const size_t O_ST    = 246042624;   // stat 2,048
    const size_t NEED    = 246044672;
    if (ws_size < NEED) {
        k_wsfail<<<1, 1, 0, stream>>>(out);
        return;
    }
    float* f2     = (float*)(wsb + O_R1);
    u16*   h1b    = (u16*)(wsb + O_H1B);
    u16*   h2b    = (u16*)(wsb + O_H2B);
    u16*   hb     = (u16*)(wsb + O_HB);
    u16*   nb     = (u16*)(wsb + O_NB);
    u16*   yb     = (u16*)(wsb + O_Y);
    float* f1     = (float*)(wsb + O_R2);
    u16*   f2bq   = (u16*)(wsb + O_R2);
    float* qkv    = (float*)(wsb + O_R2);
    float* xa     = (float*)(wsb + O_XA);
    u16*   patchT = (u16*)(wsb + O_PWT);
    u16*   qkvT   = (u16*)(wsb + O_QKVT);
    u16*   outT   = (u16*)(wsb + O_OUTT);
    u16*   w1Tl   = (u16*)(wsb + O_WL);
    u16*   w2Tl   = (u16*)(wsb + O_WL + 2097152);
    u16*   w3Tl   = (u16*)(wsb + O_WL + 4194304);
    float* postab = (float*)(wsb + O_PT);
    float* ropet  = (float*)(wsb + O_RT);
    float* w1t    = (float*)(wsb + O_CW1);
    float* w2t    = (float*)(wsb + O_CW2);
    float* stat   = (float*)(wsb + O_ST);

    // setup: tables + persistent weight conversion
    k_wt<<<4, 256, 0, stream>>>(conv1_w, w1t, 32, 27);
    k_wt<<<72, 256, 0, stream>>>(conv2_w, w2t, 64, 288);
    k_tables<<<512, 256, 0, stream>>>(postab, ropet);
    k_cvt<<<2048, 256, 0, stream>>>(patch_w, patchT);
    k_wcvtT<<<dim3(48, 16, 8), 256, 0, stream>>>(qkv_w, qkvT, 512, 1536);
    k_wcvtT<<<dim3(16, 16, 8), 256, 0, stream>>>(out_w, outT, 512, 512);

    // conv stem
    k_conv<3, 32><<<dim3(64, 32), 256, 0, stream>>>(x, w1t, conv1_b, f1);
    k_gnstats<<<128, 256, 0, stream>>>(f1, stat, 131072);
    k_gnapply<<<65536, 256, 0, stream>>>(f1, stat, gn1_g, gn1_b, 32, 16777216);
    k_conv<32, 64><<<dim3(64, 32), 256, 0, stream>>>(f1, w2t, conv2_b, f2);
    k_gnstats<<<256, 256, 0, stream>>>(f2, stat, 131072);
    k_gnapply_bf<<<131072, 256, 0, stream>>>(f2, stat, gn2_g, gn2_b, f2bq, 64, 33554432);

    // patch embed (bf16 MFMA, im2col) + cls
    k_bgemm<1, 3><<<dim3(4, 64), 256, 0, stream>>>(f2bq, patchT, patch_b, xa, postab, 8192, 512, 4096);
    k_cls<<<64, 256, 0, stream>>>(cls_tok, xa);

    // transformer (w1/w2/w3 converted per layer into rotating buffers)
    for (int l = 0; l < 8; l++) {
        k_wcvtT<<<dim3(64, 16, 1), 256, 0, stream>>>(w1_w + (size_t)l * 1048576, w1Tl, 512, 2048);
        k_wcvtT<<<dim3(64, 16, 1), 256, 0, stream>>>(w2_w + (size_t)l * 1048576, w2Tl, 512, 2048);
        k_wcvtT<<<dim3(16, 64, 1), 256, 0, stream>>>(w3_w + (size_t)l * 1048576, w3Tl, 2048, 512);

        k_lnb<<<8224, 256, 0, stream>>>(xa, ln1_g + l * 512, ln1_b + l * 512, nb);
        k_bgemm<0, 1><<<dim3(12, 65), 256, 0, stream>>>(nb, qkvT + (size_t)l * 786432,
                                                        qkv_b + l * 1536, qkv, nullptr, 8224, 1536, 512);
        k_rope<<<8224, 256, 0, stream>>>(qkv, ropet);
        k_attn<<<1280, 256, 0, stream>>>(qkv, yb);
        k_bgemm<0, 2><<<dim3(4, 65), 256, 0, stream>>>(yb, outT + (size_t)l * 262144,
                                                       out_b + l * 512, xa, nullptr, 8224, 512, 512);
        k_lnb<<<8224, 256, 0, stream>>>(xa, ln2_g + l * 512, ln2_b + l * 512, nb);
        k_bgemm<0, 4><<<dim3(16, 65), 256, 0, stream>>>(nb, w1Tl,
                                                        w1_b + l * 2048, h1b, nullptr, 8224, 2048, 512);
        k_bgemm<0, 4><<<dim3(16, 65), 256, 0, stream>>>(nb, w2Tl,
                                                        w2_b + l * 2048, h2b, nullptr, 8224, 2048, 512);
        k_swiglu<<<16448, 256, 0, stream>>>(h1b, h2b, hb);
        k_bgemm<0, 2><<<dim3(4, 65), 256, 0, stream>>>(hb, w3Tl,
                                                       w3_b + l * 512, xa, nullptr, 8224, 512, 2048);
    }
    k_ln_out<<<8224, 256, 0, stream>>>(xa, fn_g, fn_b, out);
}

// Round 5
// 3939.418 us; speedup vs baseline: 4.5108x; 1.1678x over previous
//
#include <hip/hip_runtime.h>

#define EPSV 1e-5f
typedef unsigned short u16;
typedef short bf16x8 __attribute__((ext_vector_type(8)));
typedef float f32x4 __attribute__((ext_vector_type(4)));

__device__ __forceinline__ float gelu_exact(float x) {
    return 0.5f * x * (1.0f + erff(x * 0.7071067811865475f));
}
__device__ __forceinline__ u16 to_bf(float x) {
    union { float f; unsigned u; } c; c.f = x;
    unsigned r = c.u + 0x7fffu + ((c.u >> 16) & 1u);
    return (u16)(r >> 16);
}
__device__ __forceinline__ float to_f(u16 h) {
    union { unsigned u; float f; } c; c.u = ((unsigned)h) << 16;
    return c.f;
}
__device__ __forceinline__ void gload_lds16(const void* g, void* l) {
    __builtin_amdgcn_global_load_lds((const __attribute__((address_space(1))) unsigned int*)g,
                                     (__attribute__((address_space(3))) unsigned int*)l, 16, 0, 0);
}
__device__ __forceinline__ void ld_bf16x16(const u16* p, float* f) {
    ushort4 a[4];
    a[0] = *(const ushort4*)p;       a[1] = *(const ushort4*)(p + 4);
    a[2] = *(const ushort4*)(p + 8); a[3] = *(const ushort4*)(p + 12);
#pragma unroll
    for (int i = 0; i < 4; i++) {
        f[i * 4 + 0] = to_f(a[i].x); f[i * 4 + 1] = to_f(a[i].y);
        f[i * 4 + 2] = to_f(a[i].z); f[i * 4 + 3] = to_f(a[i].w);
    }
}

// ---------------- tiny setup kernels ----------------
__global__ void k_wsfail(float* out) { out[0] = 1.0e9f; }

__global__ void k_wt(const float* __restrict__ w, float* __restrict__ wt, int cout, int cin9) {
    int idx = blockIdx.x * 256 + threadIdx.x;
    if (idx < cout * cin9) {
        int co = idx / cin9, k = idx % cin9;
        wt[k * cout + co] = w[idx];
    }
}

__global__ void k_tables(float* __restrict__ postab, float* __restrict__ ropetab) {
    int idx = blockIdx.x * 256 + threadIdx.x;
    if (idx < 256 * 512) {
        int p = idx >> 9, j = idx & 511;
        float coord = (j < 256) ? (float)(p >> 4) : (float)(p & 15);
        int jm = j & 127;
        float om = powf(10000.0f, -(float)jm / 128.0f);
        float arg = coord * om;
        postab[idx] = ((j >> 7) & 1) ? cosf(arg) : sinf(arg);
    }
    if (idx < 512) {
        // xpos tables indexed by HEAD h (reference quirk): n_pos = H = 8
        int h = idx >> 6, d = idx & 63;
        float freq = (float)h * powf(10000.0f, -(float)(d >> 1) / 32.0f);
        float sv = (2.0f * (float)(d & 31) + 25.6f) / 89.6f;
        float pw = ((float)h - 4.0f) / 512.0f;
        float sc = powf(sv, pw);
        ropetab[idx * 4 + 0] = cosf(freq);
        ropetab[idx * 4 + 1] = sinf(freq);
        ropetab[idx * 4 + 2] = sc;
        ropetab[idx * 4 + 3] = 1.0f / sc;
    }
}

__global__ void k_cls(const float* __restrict__ cls, float* __restrict__ xa) {
    int idx = blockIdx.x * 256 + threadIdx.x;
    int b = idx >> 9, d = idx & 511;
    xa[(size_t)(b * 257) * 512 + d] = cls[d];
}

// fp32 [K][N] -> bf16 [N][K] transpose-convert
__global__ __launch_bounds__(256) void k_wcvtT(const float* __restrict__ src,
                                               u16* __restrict__ dst, int K, int N) {
    __shared__ float s[32][33];
    int z = blockIdx.z;
    src += (size_t)z * K * N;
    dst += (size_t)z * K * N;
    int k0 = blockIdx.y * 32, n0 = blockIdx.x * 32;
    int t = threadIdx.x, r = t >> 3, c4 = (t & 7) * 4;
    float4 v = *(const float4*)&src[(size_t)(k0 + r) * N + n0 + c4];
    s[r][c4 + 0] = v.x; s[r][c4 + 1] = v.y; s[r][c4 + 2] = v.z; s[r][c4 + 3] = v.w;
    __syncthreads();
    ushort4 o;
    o.x = to_bf(s[c4 + 0][r]); o.y = to_bf(s[c4 + 1][r]);
    o.z = to_bf(s[c4 + 2][r]); o.w = to_bf(s[c4 + 3][r]);
    *(ushort4*)&dst[(size_t)(n0 + r) * K + k0 + c4] = o;
}

// elementwise fp32 -> bf16
__global__ void k_cvt(const float* __restrict__ src, u16* __restrict__ dst) {
    int i = (blockIdx.x * 256 + threadIdx.x) * 4;
    float4 v = *(const float4*)&src[i];
    ushort4 o;
    o.x = to_bf(v.x); o.y = to_bf(v.y); o.z = to_bf(v.z); o.w = to_bf(v.w);
    *(ushort4*)&dst[i] = o;
}

// ---------------- direct conv (3x3, pad 1) ----------------
template <int CIN, int COUT>
__global__ __launch_bounds__(256) void k_conv(const float* __restrict__ in,
                                              const float* __restrict__ wt,   // [CIN*9][COUT]
                                              const float* __restrict__ bias,
                                              float* __restrict__ out) {
    __shared__ float s_in[CIN][18][18];
    int b = blockIdx.y;
    int tile = blockIdx.x;
    int y0 = (tile >> 3) << 4;
    int x0 = (tile & 7) << 4;
    int tid = threadIdx.x;
    const int TOT = CIN * 324;
    for (int idx = tid; idx < TOT; idx += 256) {
        int ci = idx / 324, r = idx % 324;
        int ly = r / 18, lx = r % 18;
        int gy = y0 + ly - 1, gx = x0 + lx - 1;
        float v = 0.0f;
        if (gy >= 0 && gy < 128 && gx >= 0 && gx < 128)
            v = in[((size_t)(b * CIN + ci) * 128 + gy) * 128 + gx];
        s_in[ci][ly][lx] = v;
    }
    __syncthreads();
    int py = tid >> 4, px = tid & 15;
    float acc[COUT];
#pragma unroll
    for (int co = 0; co < COUT; co++) acc[co] = bias[co];
    for (int ci = 0; ci < CIN; ci++) {
#pragma unroll
        for (int dy = 0; dy < 3; dy++) {
#pragma unroll
            for (int dx = 0; dx < 3; dx++) {
                float v = s_in[ci][py + dy][px + dx];
                const float* wr = &wt[(ci * 9 + dy * 3 + dx) * COUT];
#pragma unroll
                for (int co = 0; co < COUT; co++)
                    acc[co] = fmaf(wr[co], v, acc[co]);
            }
        }
    }
    int oy = y0 + py, ox = x0 + px;
#pragma unroll
    for (int co = 0; co < COUT; co++)
        out[((size_t)(b * COUT + co) * 128 + oy) * 128 + ox] = acc[co];
}

// ---------------- GroupNorm ----------------
__global__ __launch_bounds__(256) void k_gnstats(const float* __restrict__ x,
                                                 float* __restrict__ stat, int n) {
    int bid = blockIdx.x, tid = threadIdx.x;
    const float* xp = x + (size_t)bid * n;
    double ds = 0.0, dq = 0.0;
    for (int i = tid; i < n; i += 256) {
        float v = xp[i];
        ds += v;
        dq += (double)v * v;
    }
    __shared__ double rs[256], rq[256];
    rs[tid] = ds; rq[tid] = dq;
    __syncthreads();
    for (int s = 128; s > 0; s >>= 1) {
        if (tid < s) { rs[tid] += rs[tid + s]; rq[tid] += rq[tid + s]; }
        __syncthreads();
    }
    if (tid == 0) {
        double m = rs[0] / n;
        double var = rq[0] / n - m * m;
        stat[2 * bid] = (float)m;
        stat[2 * bid + 1] = (float)(1.0 / sqrt(var + 1e-5));
    }
}

__global__ void k_gnapply(float* __restrict__ x, const float* __restrict__ stat,
                          const float* __restrict__ g, const float* __restrict__ bta,
                          int C, int total) {
    int idx = blockIdx.x * 256 + threadIdx.x;
    if (idx >= total) return;
    int c = (idx >> 14) & (C - 1);
    int gidx = idx >> 17;
    float m = stat[2 * gidx], r = stat[2 * gidx + 1];
    float v = (x[idx] - m) * r * g[c] + bta[c];
    x[idx] = gelu_exact(v);
}

__global__ void k_gnapply_bf(const float* __restrict__ x, const float* __restrict__ stat,
                             const float* __restrict__ g, const float* __restrict__ bta,
                             u16* __restrict__ xb, int C, int total) {
    int idx = blockIdx.x * 256 + threadIdx.x;
    if (idx >= total) return;
    int c = (idx >> 14) & (C - 1);
    int gidx = idx >> 17;
    float m = stat[2 * gidx], r = stat[2 * gidx + 1];
    float v = (x[idx] - m) * r * g[c] + bta[c];
    xb[idx] = to_bf(gelu_exact(v));
}

// ---------------- bf16 MFMA GEMM ----------------
// A bf16 (MODE 0: [M,K]; MODE 1: implicit im2col of f2b), Bt bf16 [N][K].
// EPI 1: fp32 C = acc+bias. EPI 2: fp32 C += acc+bias. EPI 3: patch scatter + postab.
// EPI 4: bf16 C = acc+bias. EPI 5: bf16 C = silu(aux)* (acc+bias).
template <int MODE, int EPI>
__global__ __launch_bounds__(256) void k_bgemm(const u16* __restrict__ A,
                                               const u16* __restrict__ Bt,
                                               const float* __restrict__ bias,
                                               void* __restrict__ Cp,
                                               const float* __restrict__ postab,
                                               const u16* __restrict__ aux,
                                               int M, int N, int K) {
    __shared__ u16 ldsA[8192];   // [kg 8][row 128][8]
    __shared__ u16 ldsB[8192];   // [col 128][kg^swz 8][8]
    int tid = threadIdx.x;
    int w = tid >> 6, lane = tid & 63;
    int bm = blockIdx.y * 128, bn = blockIdx.x * 128;
    int wr = w >> 1, wc = w & 1;
    int l15 = lane & 15, l16 = lane >> 4;

    f32x4 acc[4][4];
    f32x4 zf = {0.f, 0.f, 0.f, 0.f};
#pragma unroll
    for (int m = 0; m < 4; m++)
#pragma unroll
        for (int n = 0; n < 4; n++) acc[m][n] = zf;

    for (int k0 = 0; k0 < K; k0 += 64) {
#pragma unroll
        for (int i = 0; i < 4; i++) {
            int chunk = (w * 4 + i) * 64 + lane;
            int kg = chunk >> 7, row = chunk & 127;
            const u16* src;
            if (MODE == 0) {
                int grow = bm + row;
                if (grow > M - 1) grow = M - 1;
                src = A + (size_t)grow * K + k0 + kg * 8;
            } else {
                int grow = bm + row;
                int bimg = grow >> 8, p = grow & 255;
                int kga = (k0 >> 3) + kg;
                int ci = kga >> 3, ky = kga & 7;
                int gy = ((p >> 4) << 3) + ky, gx0 = (p & 15) << 3;
                src = A + (((size_t)(bimg * 64 + ci) * 128 + gy) << 7) + gx0;
            }
            gload_lds16(src, &ldsA[(w * 4 + i) * 512]);
        }
#pragma unroll
        for (int i = 0; i < 4; i++) {
            int chunk = (w * 4 + i) * 64 + lane;
            int col = chunk >> 3, kgs = chunk & 7;
            int kg_src = kgs ^ (col & 7);
            const u16* src = Bt + (size_t)(bn + col) * K + k0 + kg_src * 8;
            gload_lds16(src, &ldsB[(w * 4 + i) * 512]);
        }
        __syncthreads();

        bf16x8 af[4][2], bfr[4][2];
#pragma unroll
        for (int kk = 0; kk < 2; kk++) {
            int kga = kk * 4 + l16;
#pragma unroll
            for (int m = 0; m < 4; m++) {
                int row_l = wr * 64 + m * 16 + l15;
                af[m][kk] = *(const bf16x8*)&ldsA[(kga * 128 + row_l) * 8];
            }
#pragma unroll
            for (int n = 0; n < 4; n++) {
                int col_l = wc * 64 + n * 16 + l15;
                bfr[n][kk] = *(const bf16x8*)&ldsB[(col_l * 8 + (kga ^ (col_l & 7))) * 8];
            }
        }
#pragma unroll
        for (int m = 0; m < 4; m++)
#pragma unroll
            for (int n = 0; n < 4; n++) {
                acc[m][n] = __builtin_amdgcn_mfma_f32_16x16x32_bf16(af[m][0], bfr[n][0], acc[m][n], 0, 0, 0);
                acc[m][n] = __builtin_amdgcn_mfma_f32_16x16x32_bf16(af[m][1], bfr[n][1], acc[m][n], 0, 0, 0);
            }
        __syncthreads();
    }

#pragma unroll
    for (int n = 0; n < 4; n++) {
        int gcol = bn + wc * 64 + n * 16 + l15;
        float bv = bias[gcol];
#pragma unroll
        for (int m = 0; m < 4; m++) {
#pragma unroll
            for (int r = 0; r < 4; r++) {
                int grow = bm + wr * 64 + m * 16 + l16 * 4 + r;
                float v = acc[m][n][r] + bv;
                if (EPI == 1) {
                    if (grow < M) ((float*)Cp)[(size_t)grow * N + gcol] = v;
                } else if (EPI == 2) {
                    if (grow < M) ((float*)Cp)[(size_t)grow * N + gcol] += v;
                } else if (EPI == 4) {
                    if (grow < M) ((u16*)Cp)[(size_t)grow * N + gcol] = to_bf(v);
                } else if (EPI == 5) {
                    if (grow < M) {
                        float a = to_f(aux[(size_t)grow * N + gcol]);
                        float sl = a / (1.0f + __expf(-a));
                        ((u16*)Cp)[(size_t)grow * N + gcol] = to_bf(sl * v);
                    }
                } else {
                    int bimg = grow >> 8, p = grow & 255;
                    v += postab[p * 512 + gcol];
                    ((float*)Cp)[((size_t)(bimg * 257) + 1 + p) * 512 + gcol] = v;
                }
            }
        }
    }
}

// ---------------- LayerNorm over D=512, bf16 out ----------------
__global__ __launch_bounds__(256) void k_lnb(const float* __restrict__ x,
                                             const float* __restrict__ g,
                                             const float* __restrict__ bta,
                                             u16* __restrict__ o) {
    int row = blockIdx.x, tid = threadIdx.x;
    const float* xr = x + (size_t)row * 512;
    float v0 = xr[tid], v1 = xr[tid + 256];
    __shared__ float rs[256];
    rs[tid] = v0 + v1;
    __syncthreads();
    for (int s = 128; s > 0; s >>= 1) { if (tid < s) rs[tid] += rs[tid + s]; __syncthreads(); }
    float mean = rs[0] * (1.0f / 512.0f);
    __syncthreads();
    float d0 = v0 - mean, d1 = v1 - mean;
    rs[tid] = d0 * d0 + d1 * d1;
    __syncthreads();
    for (int s = 128; s > 0; s >>= 1) { if (tid < s) rs[tid] += rs[tid + s]; __syncthreads(); }
    float rstd = rsqrtf(rs[0] * (1.0f / 512.0f) + EPSV);
    u16* orow = o + (size_t)row * 512;
    orow[tid] = to_bf(d0 * rstd * g[tid] + bta[tid]);
    orow[tid + 256] = to_bf(d1 * rstd * g[tid + 256] + bta[tid + 256]);
}

// final LN with output remap (fp32 out)
__global__ __launch_bounds__(256) void k_ln_out(const float* __restrict__ x,
                                                const float* __restrict__ g,
                                                const float* __restrict__ bta,
                                                float* __restrict__ out) {
    int row = blockIdx.x, tid = threadIdx.x;
    const float* xr = x + (size_t)row * 512;
    float v0 = xr[tid], v1 = xr[tid + 256];
    __shared__ float rs[256];
    rs[tid] = v0 + v1;
    __syncthreads();
    for (int s = 128; s > 0; s >>= 1) { if (tid < s) rs[tid] += rs[tid + s]; __syncthreads(); }
    float mean = rs[0] * (1.0f / 512.0f);
    __syncthreads();
    float d0 = v0 - mean, d1 = v1 - mean;
    rs[tid] = d0 * d0 + d1 * d1;
    __syncthreads();
    for (int s = 128; s > 0; s >>= 1) { if (tid < s) rs[tid] += rs[tid + s]; __syncthreads(); }
    float rstd = rsqrtf(rs[0] * (1.0f / 512.0f) + EPSV);
    int b = row / 257, t = row % 257;
    float* dst = (t == 0) ? out + (size_t)b * 512
                          : out + 16384 + (size_t)(b * 256 + (t - 1)) * 512;
    dst[tid] = d0 * rstd * g[tid] + bta[tid];
    dst[tid + 256] = d1 * rstd * g[tid + 256] + bta[tid + 256];
}

// ---------------- MFMA attention, rope fused at staging ----------------
// qkv bf16 [8224][1536]; one block per (b,h,qtile64). Two-pass: scores fp32 in LDS,
// wave-parallel softmax, P bf16, PV with transpose-staged V.
__global__ __launch_bounds__(256) void k_attn_mfma(const u16* __restrict__ qkv,
                                                   const float* __restrict__ rt,
                                                   u16* __restrict__ y) {
    __shared__ u16 Qs[64][72];        // 144B rows (9x16) -> 2-way free
    __shared__ u16 KV[64][72];        // K tile, then V^T tile
    __shared__ float sc[64][260];     // 1040B rows (260 dw === 4 mod 32)
    __shared__ u16 Pb[64][328];       // 656B rows (164 dw === 4 mod 32)
    __shared__ float red1[64][4];
    __shared__ float red2[64][4];
    __shared__ float invr[64];

    int bid = blockIdx.x;
    int qt = bid % 5, bh = bid / 5;
    int h = bh & 7, b = bh >> 3;
    int q0 = qt * 64;
    int tid = threadIdx.x;
    int w = tid >> 6, lane = tid & 63;
    int l15 = lane & 15, l16 = lane >> 4;
    int wq = w >> 1, wk = w & 1;

    int srow = tid >> 2;              // staging: row 0..63
    int sc16 = (tid & 3) * 16;        // staging: d0

    // ---- stage Q (rope + 0.125 scale) ----
    {
        int grow = q0 + srow; if (grow > 256) grow = 256;
        const u16* qp = qkv + (size_t)(b * 257 + grow) * 1536 + h * 64 + sc16;
        float f[16]; ld_bf16x16(qp, f);
        const float* rb = rt + (h * 64 + sc16) * 4;
        u16 o[16];
#pragma unroll
        for (int i = 0; i < 16; i += 2) {
            float c = rb[i * 4], s = rb[i * 4 + 1], sa = rb[i * 4 + 2], sb = rb[i * 4 + 6];
            o[i]     = to_bf((f[i] * c - f[i + 1] * s) * sa * 0.125f);
            o[i + 1] = to_bf((f[i + 1] * c + f[i] * s) * sb * 0.125f);
        }
        ushort4* dst = (ushort4*)&Qs[srow][sc16];
#pragma unroll
        for (int i = 0; i < 4; i++)
            dst[i] = make_ushort4(o[i * 4], o[i * 4 + 1], o[i * 4 + 2], o[i * 4 + 3]);
    }
    __syncthreads();

    // hoist Q fragments (Qs constant hereafter)
    bf16x8 aq[2][2];
#pragma unroll
    for (int m = 0; m < 2; m++)
#pragma unroll
        for (int kk = 0; kk < 2; kk++)
            aq[m][kk] = *(const bf16x8*)&Qs[wq * 32 + m * 16 + l15][kk * 32 + l16 * 8];

    // ---- pass 1: scores over 5 K-tiles ----
    for (int t = 0; t < 5; t++) {
        int j0 = t * 64;
        {
            int gk = j0 + srow;
            u16 o[16];
            if (gk <= 256) {
                const u16* kp = qkv + (size_t)(b * 257 + gk) * 1536 + 512 + h * 64 + sc16;
                float f[16]; ld_bf16x16(kp, f);
                const float* rb = rt + (h * 64 + sc16) * 4;
#pragma unroll
                for (int i = 0; i < 16; i += 2) {
                    float c = rb[i * 4], s = rb[i * 4 + 1], sa = rb[i * 4 + 3], sb = rb[i * 4 + 7];
                    o[i]     = to_bf((f[i] * c - f[i + 1] * s) * sa);
                    o[i + 1] = to_bf((f[i + 1] * c + f[i] * s) * sb);
                }
            } else {
#pragma unroll
                for (int i = 0; i < 16; i++) o[i] = 0;
            }
            ushort4* dst = (ushort4*)&KV[srow][sc16];
#pragma unroll
            for (int i = 0; i < 4; i++)
                dst[i] = make_ushort4(o[i * 4], o[i * 4 + 1], o[i * 4 + 2], o[i * 4 + 3]);
        }
        __syncthreads();

        bf16x8 bk[2][2];
#pragma unroll
        for (int n = 0; n < 2; n++)
#pragma unroll
            for (int kk = 0; kk < 2; kk++)
                bk[n][kk] = *(const bf16x8*)&KV[wk * 32 + n * 16 + l15][kk * 32 + l16 * 8];
        f32x4 acc[2][2];
        f32x4 zf = {0.f, 0.f, 0.f, 0.f};
#pragma unroll
        for (int m = 0; m < 2; m++)
#pragma unroll
            for (int n = 0; n < 2; n++) {
                acc[m][n] = zf;
                acc[m][n] = __builtin_amdgcn_mfma_f32_16x16x32_bf16(aq[m][0], bk[n][0], acc[m][n], 0, 0, 0);
                acc[m][n] = __builtin_amdgcn_mfma_f32_16x16x32_bf16(aq[m][1], bk[n][1], acc[m][n], 0, 0, 0);
            }
#pragma unroll
        for (int m = 0; m < 2; m++)
#pragma unroll
            for (int n = 0; n < 2; n++)
#pragma unroll
                for (int r = 0; r < 4; r++) {
                    int col = j0 + wk * 32 + n * 16 + l15;
                    if (col < 257)
                        sc[wq * 32 + m * 16 + l16 * 4 + r][col] = acc[m][n][r];
                }
        __syncthreads();
    }

    // ---- softmax (4 threads per row), P = exp(s-max) bf16, 1/sum deferred ----
    {
        int r = tid >> 2, sub = tid & 3;
        float mx = -1e30f;
        for (int j = sub; j < 257; j += 4) mx = fmaxf(mx, sc[r][j]);
        red1[r][sub] = mx;
        __syncthreads();
        mx = fmaxf(fmaxf(red1[r][0], red1[r][1]), fmaxf(red1[r][2], red1[r][3]));
        float sm = 0.0f;
        for (int j = sub; j < 257; j += 4) {
            float e = __expf(sc[r][j] - mx);
            Pb[r][j] = to_bf(e);
            sm += e;
        }
        for (int j = 257 + sub; j < 328; j += 4) Pb[r][j] = 0;
        red2[r][sub] = sm;
        __syncthreads();
        if (sub == 0)
            invr[r] = 1.0f / (red2[r][0] + red2[r][1] + red2[r][2] + red2[r][3]);
        __syncthreads();
    }

    // ---- pass 2: PV over 5 V-tiles (V transpose-staged to [d][key]) ----
    f32x4 oacc[2][2];
    {
        f32x4 zf = {0.f, 0.f, 0.f, 0.f};
#pragma unroll
        for (int m = 0; m < 2; m++)
#pragma unroll
            for (int n = 0; n < 2; n++) oacc[m][n] = zf;
    }
    int wd = w & 1;
    for (int t = 0; t < 5; t++) {
        int j0 = t * 64;
        {
            int vk = tid & 63, vd0 = (tid >> 6) * 16;
            int gk = j0 + vk;
            u16 o[16];
            if (gk <= 256) {
                const u16* vp = qkv + (size_t)(b * 257 + gk) * 1536 + 1024 + h * 64 + vd0;
                ushort4 a0 = *(const ushort4*)vp, a1 = *(const ushort4*)(vp + 4);
                ushort4 a2 = *(const ushort4*)(vp + 8), a3 = *(const ushort4*)(vp + 12);
                o[0] = a0.x; o[1] = a0.y; o[2] = a0.z; o[3] = a0.w;
                o[4] = a1.x; o[5] = a1.y; o[6] = a1.z; o[7] = a1.w;
                o[8] = a2.x; o[9] = a2.y; o[10] = a2.z; o[11] = a2.w;
                o[12] = a3.x; o[13] = a3.y; o[14] = a3.z; o[15] = a3.w;
            } else {
#pragma unroll
                for (int i = 0; i < 16; i++) o[i] = 0;
            }
#pragma unroll
            for (int i = 0; i < 16; i++) KV[vd0 + i][vk] = o[i];
        }
        __syncthreads();

        bf16x8 ap[2][2], bv[2][2];
#pragma unroll
        for (int m = 0; m < 2; m++)
#pragma unroll
            for (int kk = 0; kk < 2; kk++)
                ap[m][kk] = *(const bf16x8*)&Pb[wq * 32 + m * 16 + l15][j0 + kk * 32 + l16 * 8];
#pragma unroll
        for (int n = 0; n < 2; n++)
#pragma unroll
            for (int kk = 0; kk < 2; kk++)
                bv[n][kk] = *(const bf16x8*)&KV[wd * 32 + n * 16 + l15][kk * 32 + l16 * 8];
#pragma unroll
        for (int m = 0; m < 2; m++)
#pragma unroll
            for (int n = 0; n < 2; n++) {
                oacc[m][n] = __builtin_amdgcn_mfma_f32_16x16x32_bf16(ap[m][0], bv[n][0], oacc[m][n], 0, 0, 0);
                oacc[m][n] = __builtin_amdgcn_mfma_f32_16x16x32_bf16(ap[m][1], bv[n][1], oacc[m][n], 0, 0, 0);
            }
        __syncthreads();
    }

    // ---- write y ----
#pragma unroll
    for (int m = 0; m < 2; m++)
#pragma unroll
        for (int n = 0; n < 2; n++)
#pragma unroll
            for (int r = 0; r < 4; r++) {
                int lr = wq * 32 + m * 16 + l16 * 4 + r;
                int grow = q0 + lr;
                int gd = wd * 32 + n * 16 + l15;
                if (grow < 257)
                    y[(size_t)(b * 257 + grow) * 512 + h * 64 + gd] = to_bf(oacc[m][n][r] * invr[lr]);
            }
}

// ---------------- host launch ----------------
extern "C" void kernel_launch(void* const* d_in, const int* in_sizes, int n_in,
                              void* d_out, int out_size, void* d_ws, size_t ws_size,
                              hipStream_t stream) {
    const float* x       = (const float*)d_in[0];
    const float* conv1_w = (const float*)d_in[1];
    const float* conv1_b = (const float*)d_in[2];
    const float* gn1_g   = (const float*)d_in[3];
    const float* gn1_b   = (const float*)d_in[4];
    const float* conv2_w = (const float*)d_in[5];
    const float* conv2_b = (const float*)d_in[6];
    const float* gn2_g   = (const float*)d_in[7];
    const float* gn2_b   = (const float*)d_in[8];
    const float* patch_w = (const float*)d_in[9];
    const float* patch_b = (const float*)d_in[10];
    const float* cls_tok = (const float*)d_in[11];
    const float* ln1_g   = (const float*)d_in[12];
    const float* ln1_b   = (const float*)d_in[13];
    const float* qkv_w   = (const float*)d_in[14];
    const float* qkv_b   = (const float*)d_in[15];
    const float* out_w   = (const float*)d_in[16];
    const float* out_b   = (const float*)d_in[17];
    const float* ln2_g   = (const float*)d_in[18];
    const float* ln2_b   = (const float*)d_in[19];
    const float* w1_w    = (const float*)d_in[20];
    const float* w1_b    = (const float*)d_in[21];
    const float* w2_w    = (const float*)d_in[22];
    const float* w2_b    = (const float*)d_in[23];
    const float* w3_w    = (const float*)d_in[24];
    const float* w3_b    = (const float*)d_in[25];
    const float* fn_g    = (const float*)d_in[26];
    const float* fn_b    = (const float*)d_in[27];
    float* out = (float*)d_out;
    char* wsb  = (char*)d_ws;

    // byte offsets (lifetime-aliased). Total 246,044,672 (fits: R2's 252,991,488 layout ran)
    const size_t O_R1    = 0;
    const size_t O_H1B   = O_R1 + 0;
    const size_t O_H2B   = O_R1 + 33685504;   // (hb region; h2b slot kept for layout stability)
    const size_t O_HB    = O_R1 + 67371008;
    const size_t O_NB    = O_R1 + 101056512;
    const size_t O_Y     = O_R1 + 109477888;
    const size_t O_R2    = 134217728;         // f1 fp32 | f2b bf16 | qkv bf16
    const size_t O_XA    = 201326592;
    const size_t O_PWT   = 218169344;
    const size_t O_QKVT  = 222363648;
    const size_t O_OUTT  = 234946560;
    const size_t O_WL    = 239140864;
    const size_t O_PT    = 245432320;
    const size_t O_RT    = 245956608;
    const size_t O_CW1   = 245964800;
    const size_t O_CW2   = 245968896;
    const size_t O_ST    = 246042624;
    const size_t NEED    = 246044672;
    if (ws_size < NEED) {
        k_wsfail<<<1, 1, 0, stream>>>(out);
        return;
    }
    float* f2     = (float*)(wsb + O_R1);
    u16*   h1b    = (u16*)(wsb + O_H1B);
    u16*   hb     = (u16*)(wsb + O_HB);
    u16*   nb     = (u16*)(wsb + O_NB);
    u16*   yb     = (u16*)(wsb + O_Y);
    float* f1     = (float*)(wsb + O_R2);
    u16*   f2bq   = (u16*)(wsb + O_R2);
    u16*   qkvb   = (u16*)(wsb + O_R2);
    float* xa     = (float*)(wsb + O_XA);
    u16*   patchT = (u16*)(wsb + O_PWT);
    u16*   qkvT   = (u16*)(wsb + O_QKVT);
    u16*   outT   = (u16*)(wsb + O_OUTT);
    u16*   w1Tl   = (u16*)(wsb + O_WL);
    u16*   w2Tl   = (u16*)(wsb + O_WL + 2097152);
    u16*   w3Tl   = (u16*)(wsb + O_WL + 4194304);
    float* postab = (float*)(wsb + O_PT);
    float* ropet  = (float*)(wsb + O_RT);
    float* w1t    = (float*)(wsb + O_CW1);
    float* w2t    = (float*)(wsb + O_CW2);
    float* stat   = (float*)(wsb + O_ST);

    // setup
    k_wt<<<4, 256, 0, stream>>>(conv1_w, w1t, 32, 27);
    k_wt<<<72, 256, 0, stream>>>(conv2_w, w2t, 64, 288);
    k_tables<<<512, 256, 0, stream>>>(postab, ropet);
    k_cvt<<<2048, 256, 0, stream>>>(patch_w, patchT);
    k_wcvtT<<<dim3(48, 16, 8), 256, 0, stream>>>(qkv_w, qkvT, 512, 1536);
    k_wcvtT<<<dim3(16, 16, 8), 256, 0, stream>>>(out_w, outT, 512, 512);

    // conv stem
    k_conv<3, 32><<<dim3(64, 32), 256, 0, stream>>>(x, w1t, conv1_b, f1);
    k_gnstats<<<128, 256, 0, stream>>>(f1, stat, 131072);
    k_gnapply<<<65536, 256, 0, stream>>>(f1, stat, gn1_g, gn1_b, 32, 16777216);
    k_conv<32, 64><<<dim3(64, 32), 256, 0, stream>>>(f1, w2t, conv2_b, f2);
    k_gnstats<<<256, 256, 0, stream>>>(f2, stat, 131072);
    k_gnapply_bf<<<131072, 256, 0, stream>>>(f2, stat, gn2_g, gn2_b, f2bq, 64, 33554432);

    // patch embed + cls
    k_bgemm<1, 3><<<dim3(4, 64), 256, 0, stream>>>(f2bq, patchT, patch_b, xa, postab, nullptr, 8192, 512, 4096);
    k_cls<<<64, 256, 0, stream>>>(cls_tok, xa);

    // transformer
    for (int l = 0; l < 8; l++) {
        k_wcvtT<<<dim3(64, 16, 1), 256, 0, stream>>>(w1_w + (size_t)l * 1048576, w1Tl, 512, 2048);
        k_wcvtT<<<dim3(64, 16, 1), 256, 0, stream>>>(w2_w + (size_t)l * 1048576, w2Tl, 512, 2048);
        k_wcvtT<<<dim3(16, 64, 1), 256, 0, stream>>>(w3_w + (size_t)l * 1048576, w3Tl, 2048, 512);

        k_lnb<<<8224, 256, 0, stream>>>(xa, ln1_g + l * 512, ln1_b + l * 512, nb);
        k_bgemm<0, 4><<<dim3(12, 65), 256, 0, stream>>>(nb, qkvT + (size_t)l * 786432,
                                                        qkv_b + l * 1536, qkvb, nullptr, nullptr, 8224, 1536, 512);
        k_attn_mfma<<<1280, 256, 0, stream>>>(qkvb, ropet, yb);
        k_bgemm<0, 2><<<dim3(4, 65), 256, 0, stream>>>(yb, outT + (size_t)l * 262144,
                                                       out_b + l * 512, xa, nullptr, nullptr, 8224, 512, 512);
        k_lnb<<<8224, 256, 0, stream>>>(xa, ln2_g + l * 512, ln2_b + l * 512, nb);
        k_bgemm<0, 4><<<dim3(16, 65), 256, 0, stream>>>(nb, w1Tl,
                                                        w1_b + l * 2048, h1b, nullptr, nullptr, 8224, 2048, 512);
        k_bgemm<0, 5><<<dim3(16, 65), 256, 0, stream>>>(nb, w2Tl,
                                                        w2_b + l * 2048, hb, nullptr, h1b, 8224, 2048, 512);
        k_bgemm<0, 2><<<dim3(4, 65), 256, 0, stream>>>(hb, w3Tl,
                                                       w3_b + l * 512, xa, nullptr, nullptr, 8224, 512, 2048);
    }
    k_ln_out<<<8224, 256, 0, stream>>>(xa, fn_g, fn_b, out);
}

// Round 6
// 3463.213 us; speedup vs baseline: 5.1310x; 1.1375x over previous
//
#include <hip/hip_runtime.h>

#define EPSV 1e-5f
typedef unsigned short u16;
typedef short bf16x8 __attribute__((ext_vector_type(8)));
typedef float f32x4 __attribute__((ext_vector_type(4)));

__device__ __forceinline__ float gelu_exact(float x) {
    return 0.5f * x * (1.0f + erff(x * 0.7071067811865475f));
}
__device__ __forceinline__ u16 to_bf(float x) {
    union { float f; unsigned u; } c; c.f = x;
    unsigned r = c.u + 0x7fffu + ((c.u >> 16) & 1u);
    return (u16)(r >> 16);
}
__device__ __forceinline__ float to_f(u16 h) {
    union { unsigned u; float f; } c; c.u = ((unsigned)h) << 16;
    return c.f;
}
__device__ __forceinline__ void gload_lds16(const void* g, void* l) {
    __builtin_amdgcn_global_load_lds((const __attribute__((address_space(1))) unsigned int*)g,
                                     (__attribute__((address_space(3))) unsigned int*)l, 16, 0, 0);
}

// ---------------- tiny setup kernels ----------------
__global__ void k_wsfail(float* out) { out[0] = 1.0e9f; }

__global__ void k_zero(float* p, int n) {
    int i = blockIdx.x * 256 + threadIdx.x;
    if (i < n) p[i] = 0.0f;
}

__global__ void k_wt(const float* __restrict__ w, float* __restrict__ wt, int cout, int cin9) {
    int idx = blockIdx.x * 256 + threadIdx.x;
    if (idx < cout * cin9) {
        int co = idx / cin9, k = idx % cin9;
        wt[k * cout + co] = w[idx];
    }
}

// conv2 weights [64][32][3][3] -> bf16 [tap 9][cout 64][ci 32]
__global__ void k_wpack(const float* __restrict__ w, u16* __restrict__ wp) {
    int idx = blockIdx.x * 256 + threadIdx.x;
    if (idx < 18432) {
        int ci = idx & 31, tc = idx >> 5;
        int tap = tc >> 6, co = tc & 63;
        wp[idx] = to_bf(w[co * 288 + ci * 9 + tap]);
    }
}

// patch_w [512][64][8][8] ([cout][ci][ky][kx]) -> bf16 [cout][tap*64+ci] (tap=ky*8+kx)
__global__ void k_pperm(const float* __restrict__ w, u16* __restrict__ wp) {
    int idx = blockIdx.x * 256 + threadIdx.x;
    int cout = idx >> 12, rem = idx & 4095;
    int tap = rem >> 6, ci = rem & 63;
    wp[idx] = to_bf(w[cout * 4096 + ci * 64 + tap]);
}

__global__ void k_tables(float* __restrict__ postab, float* __restrict__ ropetab) {
    int idx = blockIdx.x * 256 + threadIdx.x;
    if (idx < 256 * 512) {
        int p = idx >> 9, j = idx & 511;
        float coord = (j < 256) ? (float)(p >> 4) : (float)(p & 15);
        int jm = j & 127;
        float om = powf(10000.0f, -(float)jm / 128.0f);
        float arg = coord * om;
        postab[idx] = ((j >> 7) & 1) ? cosf(arg) : sinf(arg);
    }
    if (idx < 512) {
        // xpos tables indexed by HEAD h (reference quirk): n_pos = H = 8
        int h = idx >> 6, d = idx & 63;
        float freq = (float)h * powf(10000.0f, -(float)(d >> 1) / 32.0f);
        float sv = (2.0f * (float)(d & 31) + 25.6f) / 89.6f;
        float pw = ((float)h - 4.0f) / 512.0f;
        float sc = powf(sv, pw);
        ropetab[idx * 4 + 0] = cosf(freq);
        ropetab[idx * 4 + 1] = sinf(freq);
        ropetab[idx * 4 + 2] = sc;
        ropetab[idx * 4 + 3] = 1.0f / sc;
    }
}

__global__ void k_cls(const float* __restrict__ cls, float* __restrict__ xa) {
    int idx = blockIdx.x * 256 + threadIdx.x;
    int b = idx >> 9, d = idx & 511;
    xa[(size_t)(b * 257) * 512 + d] = cls[d];
}

// fp32 [K][N] -> bf16 [N][K] transpose-convert
__global__ __launch_bounds__(256) void k_wcvtT(const float* __restrict__ src,
                                               u16* __restrict__ dst, int K, int N) {
    __shared__ float s[32][33];
    int z = blockIdx.z;
    src += (size_t)z * K * N;
    dst += (size_t)z * K * N;
    int k0 = blockIdx.y * 32, n0 = blockIdx.x * 32;
    int t = threadIdx.x, r = t >> 3, c4 = (t & 7) * 4;
    float4 v = *(const float4*)&src[(size_t)(k0 + r) * N + n0 + c4];
    s[r][c4 + 0] = v.x; s[r][c4 + 1] = v.y; s[r][c4 + 2] = v.z; s[r][c4 + 3] = v.w;
    __syncthreads();
    ushort4 o;
    o.x = to_bf(s[c4 + 0][r]); o.y = to_bf(s[c4 + 1][r]);
    o.z = to_bf(s[c4 + 2][r]); o.w = to_bf(s[c4 + 3][r]);
    *(ushort4*)&dst[(size_t)(n0 + r) * K + k0 + c4] = o;
}

// ---------------- conv1: fp32 direct, bf16 NHWC out + GN partial sums ----------------
__global__ __launch_bounds__(256) void k_conv1(const float* __restrict__ in,
                                               const float* __restrict__ wt,   // [27][32]
                                               const float* __restrict__ bias,
                                               u16* __restrict__ f1n,
                                               float* __restrict__ sacc) {
    __shared__ float s_in[3][18][18];
    __shared__ float rs[4][4], rq[4][4];
    int b = blockIdx.y;
    int tile = blockIdx.x;
    int y0 = (tile >> 3) << 4;
    int x0 = (tile & 7) << 4;
    int tid = threadIdx.x;
    for (int idx = tid; idx < 972; idx += 256) {
        int ci = idx / 324, r = idx % 324;
        int ly = r / 18, lx = r % 18;
        int gy = y0 + ly - 1, gx = x0 + lx - 1;
        float v = 0.0f;
        if (gy >= 0 && gy < 128 && gx >= 0 && gx < 128)
            v = in[((size_t)(b * 3 + ci) * 128 + gy) * 128 + gx];
        s_in[ci][ly][lx] = v;
    }
    __syncthreads();
    int py = tid >> 4, px = tid & 15;
    float acc[32];
#pragma unroll
    for (int co = 0; co < 32; co++) acc[co] = bias[co];
#pragma unroll
    for (int ci = 0; ci < 3; ci++)
#pragma unroll
        for (int dy = 0; dy < 3; dy++)
#pragma unroll
            for (int dx = 0; dx < 3; dx++) {
                float v = s_in[ci][py + dy][px + dx];
                const float* wr = &wt[(ci * 9 + dy * 3 + dx) * 32];
#pragma unroll
                for (int co = 0; co < 32; co++)
                    acc[co] = fmaf(wr[co], v, acc[co]);
            }
    // round, write NHWC, partial GN sums (4 groups of 8)
    float s[4] = {0.f, 0.f, 0.f, 0.f}, q[4] = {0.f, 0.f, 0.f, 0.f};
    u16 ob[32];
#pragma unroll
    for (int co = 0; co < 32; co++) {
        u16 hv = to_bf(acc[co]);
        ob[co] = hv;
        float v = to_f(hv);
        s[co >> 3] += v;
        q[co >> 3] += v * v;
    }
    int oy = y0 + py, ox = x0 + px;
    u16* dst = f1n + ((size_t)(b * 16384 + oy * 128 + ox) << 5);
#pragma unroll
    for (int i = 0; i < 8; i++)
        *(ushort4*)(dst + i * 4) = make_ushort4(ob[i * 4], ob[i * 4 + 1], ob[i * 4 + 2], ob[i * 4 + 3]);
    // wave reduce (all lanes same role)
#pragma unroll
    for (int g = 0; g < 4; g++) {
#pragma unroll
        for (int off = 1; off < 64; off <<= 1) {
            s[g] += __shfl_xor(s[g], off);
            q[g] += __shfl_xor(q[g], off);
        }
    }
    int w = tid >> 6, lane = tid & 63;
    if (lane == 0)
#pragma unroll
        for (int g = 0; g < 4; g++) { rs[g][w] = s[g]; rq[g][w] = q[g]; }
    __syncthreads();
    if (tid < 4) {
        int g = tid;
        float S = rs[g][0] + rs[g][1] + rs[g][2] + rs[g][3];
        float Q = rq[g][0] + rq[g][1] + rq[g][2] + rq[g][3];
        atomicAdd(&sacc[(b * 4 + g) * 2], S);
        atomicAdd(&sacc[(b * 4 + g) * 2 + 1], Q);
    }
}

// finalize GN stats: mean, rstd (group size 131072 for both GNs)
__global__ void k_gnfin(const float* __restrict__ sacc, float* __restrict__ st, int entries) {
    int i = blockIdx.x * 256 + threadIdx.x;
    if (i < entries) {
        float m = sacc[2 * i] * (1.0f / 131072.0f);
        float var = sacc[2 * i + 1] * (1.0f / 131072.0f) - m * m;
        st[2 * i] = m;
        st[2 * i + 1] = rsqrtf(var + 1e-5f);
    }
}

// GN apply + GELU, bf16 NHWC in-place. cm = C-1, sh = log2(16384*C), gsh groups/img shift
__global__ void k_gnap(u16* __restrict__ xio, const float* __restrict__ st,
                       const float* __restrict__ gg, const float* __restrict__ bb,
                       int cm, int sh, int gmul) {
    int idx = blockIdx.x * 256 + threadIdx.x;
    long e = (long)idx * 4;
    int c0 = (int)(e & cm);
    int b = (int)(e >> sh);
    int sid = b * gmul + (c0 >> 3);
    float m = st[2 * sid], r = st[2 * sid + 1];
    ushort4 a = *(ushort4*)&xio[e];
    ushort4 o;
    o.x = to_bf(gelu_exact((to_f(a.x) - m) * r * gg[c0 + 0] + bb[c0 + 0]));
    o.y = to_bf(gelu_exact((to_f(a.y) - m) * r * gg[c0 + 1] + bb[c0 + 1]));
    o.z = to_bf(gelu_exact((to_f(a.z) - m) * r * gg[c0 + 2] + bb[c0 + 2]));
    o.w = to_bf(gelu_exact((to_f(a.w) - m) * r * gg[c0 + 3] + bb[c0 + 3]));
    *(ushort4*)&xio[e] = o;
}

// ---------------- conv2 as MFMA implicit GEMM (NHWC bf16) ----------------
// block: 16x16 spatial tile x 64 cout, 4 waves; K = 9 taps x 32 ci.
__global__ __launch_bounds__(256) void k_conv2m(const u16* __restrict__ f1b,
                                                const u16* __restrict__ wp,   // [9][64][32]
                                                const float* __restrict__ bias,
                                                u16* __restrict__ f2n,
                                                float* __restrict__ sacc) {
    __shared__ u16 In[324 * 34];   // [pixel(18x18)][ci 32 +2 pad]
    __shared__ u16 Ws[576 * 34];   // [tap*64+cout][ci 32 +2 pad]
    int b = blockIdx.y;
    int tile = blockIdx.x;
    int y0 = (tile >> 3) << 4;
    int x0 = (tile & 7) << 4;
    int tid = threadIdx.x;
    int w = tid >> 6, lane = tid & 63;
    int l15 = lane & 15, l16 = lane >> 4;

    for (int idx = tid; idx < 2304; idx += 256) {
        int tc = idx >> 2, qd = idx & 3;
        *(ushort4*)&Ws[tc * 34 + qd * 8]     = *(const ushort4*)&wp[tc * 32 + qd * 8];
        *(ushort4*)&Ws[tc * 34 + qd * 8 + 4] = *(const ushort4*)&wp[tc * 32 + qd * 8 + 4];
    }
    for (int idx = tid; idx < 648; idx += 256) {
        int pix = idx >> 1, half = idx & 1;
        int pr = pix / 18, pc = pix % 18;
        int gy = y0 + pr - 1, gx = x0 + pc - 1;
        if (gy >= 0 && gy < 128 && gx >= 0 && gx < 128) {
            const u16* src = f1b + ((size_t)(b * 16384 + gy * 128 + gx) << 5) + half * 16;
            *(ushort4*)&In[pix * 34 + half * 16]      = *(const ushort4*)src;
            *(ushort4*)&In[pix * 34 + half * 16 + 4]  = *(const ushort4*)(src + 4);
            *(ushort4*)&In[pix * 34 + half * 16 + 8]  = *(const ushort4*)(src + 8);
            *(ushort4*)&In[pix * 34 + half * 16 + 12] = *(const ushort4*)(src + 12);
        } else {
            ushort4 z = make_ushort4(0, 0, 0, 0);
            *(ushort4*)&In[pix * 34 + half * 16]      = z;
            *(ushort4*)&In[pix * 34 + half * 16 + 4]  = z;
            *(ushort4*)&In[pix * 34 + half * 16 + 8]  = z;
            *(ushort4*)&In[pix * 34 + half * 16 + 12] = z;
        }
    }
    __syncthreads();

    f32x4 acc[4][4];
    f32x4 zf = {0.f, 0.f, 0.f, 0.f};
#pragma unroll
    for (int m = 0; m < 4; m++)
#pragma unroll
        for (int n = 0; n < 4; n++) acc[m][n] = zf;

#pragma unroll
    for (int tap = 0; tap < 9; tap++) {
        int dy = tap / 3, dx = tap % 3;
        bf16x8 af[4], bk[4];
#pragma unroll
        for (int m = 0; m < 4; m++)
            af[m] = *(const bf16x8*)&In[((w * 4 + m + dy) * 18 + l15 + dx) * 34 + l16 * 8];
#pragma unroll
        for (int n = 0; n < 4; n++)
            bk[n] = *(const bf16x8*)&Ws[(tap * 64 + n * 16 + l15) * 34 + l16 * 8];
#pragma unroll
        for (int m = 0; m < 4; m++)
#pragma unroll
            for (int n = 0; n < 4; n++)
                acc[m][n] = __builtin_amdgcn_mfma_f32_16x16x32_bf16(af[m], bk[n], acc[m][n], 0, 0, 0);
    }

    // epilogue: write NHWC bf16 + GN partial sums (8 groups)
#pragma unroll
    for (int n = 0; n < 4; n++) {
        int gco = n * 16 + l15;
        float bv = bias[gco];
        float sn = 0.0f, qn = 0.0f;
#pragma unroll
        for (int m = 0; m < 4; m++) {
            int py = w * 4 + m;
#pragma unroll
            for (int r = 0; r < 4; r++) {
                int px = l16 * 4 + r;
                float v = acc[m][n][r] + bv;
                u16 hv = to_bf(v);
                f2n[((size_t)(b * 16384 + (y0 + py) * 128 + x0 + px) << 6) + gco] = hv;
                float vf = to_f(hv);
                sn += vf;
                qn += vf * vf;
            }
        }
        // reduce over 32 lanes sharing (l15>>3): xor {1,2,4,16,32}
#pragma unroll
        for (int off = 1; off <= 4; off <<= 1) { sn += __shfl_xor(sn, off); qn += __shfl_xor(qn, off); }
        sn += __shfl_xor(sn, 16); qn += __shfl_xor(qn, 16);
        sn += __shfl_xor(sn, 32); qn += __shfl_xor(qn, 32);
        if (lane == 0 || lane == 8) {
            int g = n * 2 + (lane >> 3);
            atomicAdd(&sacc[(b * 8 + g) * 2], sn);
            atomicAdd(&sacc[(b * 8 + g) * 2 + 1], qn);
        }
    }
}

// ---------------- bf16 MFMA GEMM ----------------
// MODE 0: A [M,K] row-major. MODE 1: implicit im2col of f2b NHWC (k = tap*64+ci).
// EPI 1: fp32 C = acc+bias. EPI 2: fp32 C += acc+bias. EPI 3: patch scatter + postab.
// EPI 4: bf16 C = acc+bias. EPI 5: bf16 C = silu(aux)*(acc+bias).
template <int MODE, int EPI>
__global__ __launch_bounds__(256) void k_bgemm(const u16* __restrict__ A,
                                               const u16* __restrict__ Bt,
                                               const float* __restrict__ bias,
                                               void* __restrict__ Cp,
                                               const float* __restrict__ postab,
                                               const u16* __restrict__ aux,
                                               int M, int N, int K) {
    __shared__ u16 ldsA[8192];   // [kg 8][row 128][8]
    __shared__ u16 ldsB[8192];   // [col 128][kg^swz 8][8]
    int tid = threadIdx.x;
    int w = tid >> 6, lane = tid & 63;
    int bm = blockIdx.y * 128, bn = blockIdx.x * 128;
    int wr = w >> 1, wc = w & 1;
    int l15 = lane & 15, l16 = lane >> 4;

    f32x4 acc[4][4];
    f32x4 zf = {0.f, 0.f, 0.f, 0.f};
#pragma unroll
    for (int m = 0; m < 4; m++)
#pragma unroll
        for (int n = 0; n < 4; n++) acc[m][n] = zf;

    for (int k0 = 0; k0 < K; k0 += 64) {
#pragma unroll
        for (int i = 0; i < 4; i++) {
            int chunk = (w * 4 + i) * 64 + lane;
            int kg = chunk >> 7, row = chunk & 127;
            const u16* src;
            if (MODE == 0) {
                int grow = bm + row;
                if (grow > M - 1) grow = M - 1;
                src = A + (size_t)grow * K + k0 + kg * 8;
            } else {
                int grow = bm + row;
                int bimg = grow >> 8, p = grow & 255;
                int kga = (k0 >> 3) + kg;
                int tap = kga >> 3, cq = kga & 7;
                int ky = tap >> 3, kx = tap & 7;
                int gy = ((p >> 4) << 3) + ky, gx = ((p & 15) << 3) + kx;
                src = A + (((size_t)(bimg * 16384 + gy * 128 + gx)) << 6) + cq * 8;
            }
            gload_lds16(src, &ldsA[(w * 4 + i) * 512]);
        }
#pragma unroll
        for (int i = 0; i < 4; i++) {
            int chunk = (w * 4 + i) * 64 + lane;
            int col = chunk >> 3, kgs = chunk & 7;
            int kg_src = kgs ^ (col & 7);
            const u16* src = Bt + (size_t)(bn + col) * K + k0 + kg_src * 8;
            gload_lds16(src, &ldsB[(w * 4 + i) * 512]);
        }
        __syncthreads();

        bf16x8 af[4][2], bfr[4][2];
#pragma unroll
        for (int kk = 0; kk < 2; kk++) {
            int kga = kk * 4 + l16;
#pragma unroll
            for (int m = 0; m < 4; m++) {
                int row_l = wr * 64 + m * 16 + l15;
                af[m][kk] = *(const bf16x8*)&ldsA[(kga * 128 + row_l) * 8];
            }
#pragma unroll
            for (int n = 0; n < 4; n++) {
                int col_l = wc * 64 + n * 16 + l15;
                bfr[n][kk] = *(const bf16x8*)&ldsB[(col_l * 8 + (kga ^ (col_l & 7))) * 8];
            }
        }
#pragma unroll
        for (int m = 0; m < 4; m++)
#pragma unroll
            for (int n = 0; n < 4; n++) {
                acc[m][n] = __builtin_amdgcn_mfma_f32_16x16x32_bf16(af[m][0], bfr[n][0], acc[m][n], 0, 0, 0);
                acc[m][n] = __builtin_amdgcn_mfma_f32_16x16x32_bf16(af[m][1], bfr[n][1], acc[m][n], 0, 0, 0);
            }
        __syncthreads();
    }

#pragma unroll
    for (int n = 0; n < 4; n++) {
        int gcol = bn + wc * 64 + n * 16 + l15;
        float bv = bias[gcol];
#pragma unroll
        for (int m = 0; m < 4; m++) {
#pragma unroll
            for (int r = 0; r < 4; r++) {
                int grow = bm + wr * 64 + m * 16 + l16 * 4 + r;
                float v = acc[m][n][r] + bv;
                if (EPI == 1) {
                    if (grow < M) ((float*)Cp)[(size_t)grow * N + gcol] = v;
                } else if (EPI == 2) {
                    if (grow < M) ((float*)Cp)[(size_t)grow * N + gcol] += v;
                } else if (EPI == 4) {
                    if (grow < M) ((u16*)Cp)[(size_t)grow * N + gcol] = to_bf(v);
                } else if (EPI == 5) {
                    if (grow < M) {
                        float a = to_f(aux[(size_t)grow * N + gcol]);
                        float sl = a / (1.0f + __expf(-a));
                        ((u16*)Cp)[(size_t)grow * N + gcol] = to_bf(sl * v);
                    }
                } else {
                    int bimg = grow >> 8, p = grow & 255;
                    v += postab[p * 512 + gcol];
                    ((float*)Cp)[((size_t)(bimg * 257) + 1 + p) * 512 + gcol] = v;
                }
            }
        }
    }
}

// ---------------- LayerNorm over D=512, bf16 out ----------------
__global__ __launch_bounds__(256) void k_lnb(const float* __restrict__ x,
                                             const float* __restrict__ g,
                                             const float* __restrict__ bta,
                                             u16* __restrict__ o) {
    int row = blockIdx.x, tid = threadIdx.x;
    const float* xr = x + (size_t)row * 512;
    float v0 = xr[tid], v1 = xr[tid + 256];
    __shared__ float rs[256];
    rs[tid] = v0 + v1;
    __syncthreads();
    for (int s = 128; s > 0; s >>= 1) { if (tid < s) rs[tid] += rs[tid + s]; __syncthreads(); }
    float mean = rs[0] * (1.0f / 512.0f);
    __syncthreads();
    float d0 = v0 - mean, d1 = v1 - mean;
    rs[tid] = d0 * d0 + d1 * d1;
    __syncthreads();
    for (int s = 128; s > 0; s >>= 1) { if (tid < s) rs[tid] += rs[tid + s]; __syncthreads(); }
    float rstd = rsqrtf(rs[0] * (1.0f / 512.0f) + EPSV);
    u16* orow = o + (size_t)row * 512;
    orow[tid] = to_bf(d0 * rstd * g[tid] + bta[tid]);
    orow[tid + 256] = to_bf(d1 * rstd * g[tid + 256] + bta[tid + 256]);
}

__global__ __launch_bounds__(256) void k_ln_out(const float* __restrict__ x,
                                                const float* __restrict__ g,
                                                const float* __restrict__ bta,
                                                float* __restrict__ out) {
    int row = blockIdx.x, tid = threadIdx.x;
    const float* xr = x + (size_t)row * 512;
    float v0 = xr[tid], v1 = xr[tid + 256];
    __shared__ float rs[256];
    rs[tid] = v0 + v1;
    __syncthreads();
    for (int s = 128; s > 0; s >>= 1) { if (tid < s) rs[tid] += rs[tid + s]; __syncthreads(); }
    float mean = rs[0] * (1.0f / 512.0f);
    __syncthreads();
    float d0 = v0 - mean, d1 = v1 - mean;
    rs[tid] = d0 * d0 + d1 * d1;
    __syncthreads();
    for (int s = 128; s > 0; s >>= 1) { if (tid < s) rs[tid] += rs[tid + s]; __syncthreads(); }
    float rstd = rsqrtf(rs[0] * (1.0f / 512.0f) + EPSV);
    int b = row / 257, t = row % 257;
    float* dst = (t == 0) ? out + (size_t)b * 512
                          : out + 16384 + (size_t)(b * 256 + (t - 1)) * 512;
    dst[tid] = d0 * rstd * g[tid] + bta[tid];
    dst[tid + 256] = d1 * rstd * g[tid + 256] + bta[tid + 256];
}

// ---------------- MFMA attention, 32-row q tiles, rope fused ----------------
__global__ __launch_bounds__(256) void k_attn_mfma(const u16* __restrict__ qkv,
                                                   const float* __restrict__ rt,
                                                   u16* __restrict__ y) {
    __shared__ u16 Qs[32][72];
    __shared__ u16 KV[64][72];
    __shared__ float sc[32][260];
    __shared__ u16 Pb[32][328];
    __shared__ float red1[32][8];
    __shared__ float red2[32][8];
    __shared__ float invr[32];

    int bid = blockIdx.x;                 // ((b*8+h)*9 + qt)
    int qt = bid % 9, bh = bid / 9;
    int h = bh & 7, b = bh >> 3;
    int q0 = qt * 32;
    int tid = threadIdx.x;
    int w = tid >> 6, lane = tid & 63;
    int l15 = lane & 15, l16 = lane >> 4;

    // ---- stage Q (32 rows, rope + 0.125) ----
    {
        int srow = tid >> 3, d0 = (tid & 7) * 8;
        int grow = q0 + srow; if (grow > 256) grow = 256;
        const u16* qp = qkv + (size_t)(b * 257 + grow) * 1536 + h * 64 + d0;
        ushort4 a0 = *(const ushort4*)qp, a1 = *(const ushort4*)(qp + 4);
        float f[8] = {to_f(a0.x), to_f(a0.y), to_f(a0.z), to_f(a0.w),
                      to_f(a1.x), to_f(a1.y), to_f(a1.z), to_f(a1.w)};
        const float* rb = rt + (h * 64 + d0) * 4;
        u16 o[8];
#pragma unroll
        for (int i = 0; i < 8; i += 2) {
            float c = rb[i * 4], s = rb[i * 4 + 1], sa = rb[i * 4 + 2], sb = rb[i * 4 + 6];
            o[i]     = to_bf((f[i] * c - f[i + 1] * s) * sa * 0.125f);
            o[i + 1] = to_bf((f[i + 1] * c + f[i] * s) * sb * 0.125f);
        }
        *(ushort4*)&Qs[srow][d0]     = make_ushort4(o[0], o[1], o[2], o[3]);
        *(ushort4*)&Qs[srow][d0 + 4] = make_ushort4(o[4], o[5], o[6], o[7]);
    }
    __syncthreads();

    bf16x8 aq[2][2];
#pragma unroll
    for (int m = 0; m < 2; m++)
#pragma unroll
        for (int kk = 0; kk < 2; kk++)
            aq[m][kk] = *(const bf16x8*)&Qs[m * 16 + l15][kk * 32 + l16 * 8];

    // ---- pass 1: scores over 5 K-tiles of 64 ----
    for (int t = 0; t < 5; t++) {
        int j0 = t * 64;
        {
            int srow = tid >> 2, d0 = (tid & 3) * 16;
            int gk = j0 + srow;
            u16 o[16];
            if (gk <= 256) {
                const u16* kp = qkv + (size_t)(b * 257 + gk) * 1536 + 512 + h * 64 + d0;
                ushort4 a0 = *(const ushort4*)kp, a1 = *(const ushort4*)(kp + 4);
                ushort4 a2 = *(const ushort4*)(kp + 8), a3 = *(const ushort4*)(kp + 12);
                float f[16] = {to_f(a0.x), to_f(a0.y), to_f(a0.z), to_f(a0.w),
                               to_f(a1.x), to_f(a1.y), to_f(a1.z), to_f(a1.w),
                               to_f(a2.x), to_f(a2.y), to_f(a2.z), to_f(a2.w),
                               to_f(a3.x), to_f(a3.y), to_f(a3.z), to_f(a3.w)};
                const float* rb = rt + (h * 64 + d0) * 4;
#pragma unroll
                for (int i = 0; i < 16; i += 2) {
                    float c = rb[i * 4], s = rb[i * 4 + 1], sa = rb[i * 4 + 3], sb = rb[i * 4 + 7];
                    o[i]     = to_bf((f[i] * c - f[i + 1] * s) * sa);
                    o[i + 1] = to_bf((f[i + 1] * c + f[i] * s) * sb);
                }
            } else {
#pragma unroll
                for (int i = 0; i < 16; i++) o[i] = 0;
            }
#pragma unroll
            for (int i = 0; i < 4; i++)
                *(ushort4*)&KV[tid >> 2][d0 + i * 4] =
                    make_ushort4(o[i * 4], o[i * 4 + 1], o[i * 4 + 2], o[i * 4 + 3]);
        }
        __syncthreads();

        bf16x8 bk[2];
#pragma unroll
        for (int kk = 0; kk < 2; kk++)
            bk[kk] = *(const bf16x8*)&KV[w * 16 + l15][kk * 32 + l16 * 8];
        f32x4 a2[2];
        f32x4 zf = {0.f, 0.f, 0.f, 0.f};
#pragma unroll
        for (int m = 0; m < 2; m++) {
            a2[m] = zf;
            a2[m] = __builtin_amdgcn_mfma_f32_16x16x32_bf16(aq[m][0], bk[0], a2[m], 0, 0, 0);
            a2[m] = __builtin_amdgcn_mfma_f32_16x16x32_bf16(aq[m][1], bk[1], a2[m], 0, 0, 0);
        }
        int col = j0 + w * 16 + l15;
#pragma unroll
        for (int m = 0; m < 2; m++)
#pragma unroll
            for (int r = 0; r < 4; r++)
                if (col < 257) sc[m * 16 + l16 * 4 + r][col] = a2[m][r];
        __syncthreads();
    }

    // ---- softmax: 8 threads per row ----
    {
        int r = tid >> 3, sub = tid & 7;
        float mx = -1e30f;
        for (int j = sub; j < 257; j += 8) mx = fmaxf(mx, sc[r][j]);
        red1[r][sub] = mx;
        __syncthreads();
        mx = red1[r][0];
#pragma unroll
        for (int i = 1; i < 8; i++) mx = fmaxf(mx, red1[r][i]);
        float sm = 0.0f;
        for (int j = sub; j < 257; j += 8) {
            float e = __expf(sc[r][j] - mx);
            Pb[r][j] = to_bf(e);
            sm += e;
        }
        for (int j = 257 + sub; j < 320; j += 8) Pb[r][j] = 0;
        red2[r][sub] = sm;
        __syncthreads();
        if (sub == 0) {
            float t = red2[r][0];
#pragma unroll
            for (int i = 1; i < 8; i++) t += red2[r][i];
            invr[r] = 1.0f / t;
        }
        __syncthreads();
    }

    // ---- pass 2: PV over 5 V-tiles (V transposed to [d][key]) ----
    f32x4 oacc[2];
    {
        f32x4 zf = {0.f, 0.f, 0.f, 0.f};
        oacc[0] = zf; oacc[1] = zf;
    }
    for (int t = 0; t < 5; t++) {
        int j0 = t * 64;
        {
            int vk = tid & 63, vd0 = (tid >> 6) * 16;
            int gk = j0 + vk;
            u16 o[16];
            if (gk <= 256) {
                const u16* vp = qkv + (size_t)(b * 257 + gk) * 1536 + 1024 + h * 64 + vd0;
                ushort4 a0 = *(const ushort4*)vp, a1 = *(const ushort4*)(vp + 4);
                ushort4 a2v = *(const ushort4*)(vp + 8), a3 = *(const ushort4*)(vp + 12);
                o[0] = a0.x; o[1] = a0.y; o[2] = a0.z; o[3] = a0.w;
                o[4] = a1.x; o[5] = a1.y; o[6] = a1.z; o[7] = a1.w;
                o[8] = a2v.x; o[9] = a2v.y; o[10] = a2v.z; o[11] = a2v.w;
                o[12] = a3.x; o[13] = a3.y; o[14] = a3.z; o[15] = a3.w;
            } else {
#pragma unroll
                for (int i = 0; i < 16; i++) o[i] = 0;
            }
#pragma unroll
            for (int i = 0; i < 16; i++) KV[vd0 + i][vk] = o[i];
        }
        __syncthreads();

        bf16x8 ap[2][2], bv[2];
#pragma unroll
        for (int m = 0; m < 2; m++)
#pragma unroll
            for (int kk = 0; kk < 2; kk++)
                ap[m][kk] = *(const bf16x8*)&Pb[m * 16 + l15][j0 + kk * 32 + l16 * 8];
#pragma unroll
        for (int kk = 0; kk < 2; kk++)
            bv[kk] = *(const bf16x8*)&KV[w * 16 + l15][kk * 32 + l16 * 8];
#pragma unroll
        for (int m = 0; m < 2; m++) {
            oacc[m] = __builtin_amdgcn_mfma_f32_16x16x32_bf16(ap[m][0], bv[0], oacc[m], 0, 0, 0);
            oacc[m] = __builtin_amdgcn_mfma_f32_16x16x32_bf16(ap[m][1], bv[1], oacc[m], 0, 0, 0);
        }
        __syncthreads();
    }

#pragma unroll
    for (int m = 0; m < 2; m++)
#pragma unroll
        for (int r = 0; r < 4; r++) {
            int lr = m * 16 + l16 * 4 + r;
            int grow = q0 + lr;
            if (grow < 257)
                y[(size_t)(b * 257 + grow) * 512 + h * 64 + w * 16 + l15] =
                    to_bf(oacc[m][r] * invr[lr]);
        }
}

// ---------------- host launch ----------------
extern "C" void kernel_launch(void* const* d_in, const int* in_sizes, int n_in,
                              void* d_out, int out_size, void* d_ws, size_t ws_size,
                              hipStream_t stream) {
    const float* x       = (const float*)d_in[0];
    const float* conv1_w = (const float*)d_in[1];
    const float* conv1_b = (const float*)d_in[2];
    const float* gn1_g   = (const float*)d_in[3];
    const float* gn1_b   = (const float*)d_in[4];
    const float* conv2_w = (const float*)d_in[5];
    const float* conv2_b = (const float*)d_in[6];
    const float* gn2_g   = (const float*)d_in[7];
    const float* gn2_b   = (const float*)d_in[8];
    const float* patch_w = (const float*)d_in[9];
    const float* patch_b = (const float*)d_in[10];
    const float* cls_tok = (const float*)d_in[11];
    const float* ln1_g   = (const float*)d_in[12];
    const float* ln1_b   = (const float*)d_in[13];
    const float* qkv_w   = (const float*)d_in[14];
    const float* qkv_b   = (const float*)d_in[15];
    const float* out_w   = (const float*)d_in[16];
    const float* out_b   = (const float*)d_in[17];
    const float* ln2_g   = (const float*)d_in[18];
    const float* ln2_b   = (const float*)d_in[19];
    const float* w1_w    = (const float*)d_in[20];
    const float* w1_b    = (const float*)d_in[21];
    const float* w2_w    = (const float*)d_in[22];
    const float* w2_b    = (const float*)d_in[23];
    const float* w3_w    = (const float*)d_in[24];
    const float* w3_b    = (const float*)d_in[25];
    const float* fn_g    = (const float*)d_in[26];
    const float* fn_b    = (const float*)d_in[27];
    float* out = (float*)d_out;
    char* wsb  = (char*)d_ws;

    // arena (bytes), lifetime-aliased. Total 246,050,816 < 252,991,488 proven avail.
    const size_t O_R1    = 0;                 // f2n bf16 NHWC 67.1MB | transformer bufs
    const size_t O_H1B   = O_R1 + 0;
    const size_t O_HB    = O_R1 + 67371008;
    const size_t O_NB    = O_R1 + 101056512;
    const size_t O_Y     = O_R1 + 109477888;
    const size_t O_R2    = 134217728;         // f1n bf16 NHWC 33.5MB | qkvb bf16 25.3MB
    const size_t O_XA    = 201326592;
    const size_t O_PWT   = 218169344;
    const size_t O_QKVT  = 222363648;
    const size_t O_OUTT  = 234946560;
    const size_t O_WL    = 239140864;
    const size_t O_PT    = 245432320;
    const size_t O_RT    = 245956608;
    const size_t O_CW1   = 245964800;
    const size_t O_CW2   = 245968896;         // wpack bf16 36,864
    const size_t O_ST    = 246042624;         // stat 768 floats (GN1 256 + GN2 512)
    const size_t O_SA    = 246046720;         // statacc 768 floats
    const size_t NEED    = 246050816;
    if (ws_size < NEED) {
        k_wsfail<<<1, 1, 0, stream>>>(out);
        return;
    }
    u16*   f2n    = (u16*)(wsb + O_R1);
    u16*   h1b    = (u16*)(wsb + O_H1B);
    u16*   hb     = (u16*)(wsb + O_HB);
    u16*   nb     = (u16*)(wsb + O_NB);
    u16*   yb     = (u16*)(wsb + O_Y);
    u16*   f1n    = (u16*)(wsb + O_R2);
    u16*   qkvb   = (u16*)(wsb + O_R2);
    float* xa     = (float*)(wsb + O_XA);
    u16*   patchT = (u16*)(wsb + O_PWT);
    u16*   qkvT   = (u16*)(wsb + O_QKVT);
    u16*   outT   = (u16*)(wsb + O_OUTT);
    u16*   w1Tl   = (u16*)(wsb + O_WL);
    u16*   w2Tl   = (u16*)(wsb + O_WL + 2097152);
    u16*   w3Tl   = (u16*)(wsb + O_WL + 4194304);
    float* postab = (float*)(wsb + O_PT);
    float* ropet  = (float*)(wsb + O_RT);
    float* w1t    = (float*)(wsb + O_CW1);
    u16*   wpack  = (u16*)(wsb + O_CW2);
    float* stat   = (float*)(wsb + O_ST);     // stat1 = stat, stat2 = stat+256
    float* sacc   = (float*)(wsb + O_SA);     // sacc1 = sacc, sacc2 = sacc+256

    // setup
    k_zero<<<3, 256, 0, stream>>>(sacc, 768);
    k_wt<<<4, 256, 0, stream>>>(conv1_w, w1t, 32, 27);
    k_wpack<<<72, 256, 0, stream>>>(conv2_w, wpack);
    k_tables<<<512, 256, 0, stream>>>(postab, ropet);
    k_pperm<<<8192, 256, 0, stream>>>(patch_w, patchT);
    k_wcvtT<<<dim3(48, 16, 8), 256, 0, stream>>>(qkv_w, qkvT, 512, 1536);
    k_wcvtT<<<dim3(16, 16, 8), 256, 0, stream>>>(out_w, outT, 512, 512);

    // conv stem (NHWC bf16, fused GN stats)
    k_conv1<<<dim3(64, 32), 256, 0, stream>>>(x, w1t, conv1_b, f1n, sacc);
    k_gnfin<<<1, 256, 0, stream>>>(sacc, stat, 128);
    k_gnap<<<16384, 256, 0, stream>>>(f1n, stat, gn1_g, gn1_b, 31, 19, 4);
    k_conv2m<<<dim3(64, 32), 256, 0, stream>>>(f1n, wpack, conv2_b, f2n, sacc + 256);
    k_gnfin<<<1, 256, 0, stream>>>(sacc + 256, stat + 256, 256);
    k_gnap<<<32768, 256, 0, stream>>>(f2n, stat + 256, gn2_g, gn2_b, 63, 20, 8);

    // patch embed + cls
    k_bgemm<1, 3><<<dim3(4, 64), 256, 0, stream>>>(f2n, patchT, patch_b, xa, postab, nullptr, 8192, 512, 4096);
    k_cls<<<64, 256, 0, stream>>>(cls_tok, xa);

    // transformer
    for (int l = 0; l < 8; l++) {
        k_wcvtT<<<dim3(64, 16, 1), 256, 0, stream>>>(w1_w + (size_t)l * 1048576, w1Tl, 512, 2048);
        k_wcvtT<<<dim3(64, 16, 1), 256, 0, stream>>>(w2_w + (size_t)l * 1048576, w2Tl, 512, 2048);
        k_wcvtT<<<dim3(16, 64, 1), 256, 0, stream>>>(w3_w + (size_t)l * 1048576, w3Tl, 2048, 512);

        k_lnb<<<8224, 256, 0, stream>>>(xa, ln1_g + l * 512, ln1_b + l * 512, nb);
        k_bgemm<0, 4><<<dim3(12, 65), 256, 0, stream>>>(nb, qkvT + (size_t)l * 786432,
                                                        qkv_b + l * 1536, qkvb, nullptr, nullptr, 8224, 1536, 512);
        k_attn_mfma<<<2304, 256, 0, stream>>>(qkvb, ropet, yb);
        k_bgemm<0, 2><<<dim3(4, 65), 256, 0, stream>>>(yb, outT + (size_t)l * 262144,
                                                       out_b + l * 512, xa, nullptr, nullptr, 8224, 512, 512);
        k_lnb<<<8224, 256, 0, stream>>>(xa, ln2_g + l * 512, ln2_b + l * 512, nb);
        k_bgemm<0, 4><<<dim3(16, 65), 256, 0, stream>>>(nb, w1Tl,
                                                        w1_b + l * 2048, h1b, nullptr, nullptr, 8224, 2048, 512);
        k_bgemm<0, 5><<<dim3(16, 65), 256, 0, stream>>>(nb, w2Tl,
                                                        w2_b + l * 2048, hb, nullptr, h1b, 8224, 2048, 512);
        k_bgemm<0, 2><<<dim3(4, 65), 256, 0, stream>>>(hb, w3Tl,
                                                       w3_b + l * 512, xa, nullptr, nullptr, 8224, 512, 2048);
    }
    k_ln_out<<<8224, 256, 0, stream>>>(xa, fn_g, fn_b, out);
}

// Round 7
// 3133.965 us; speedup vs baseline: 5.6701x; 1.1051x over previous
//
#include <hip/hip_runtime.h>

#define EPSV 1e-5f
typedef unsigned short u16;
typedef short bf16x8 __attribute__((ext_vector_type(8)));
typedef float f32x4 __attribute__((ext_vector_type(4)));

__device__ __forceinline__ float gelu_exact(float x) {
    return 0.5f * x * (1.0f + erff(x * 0.7071067811865475f));
}
__device__ __forceinline__ u16 to_bf(float x) {
    union { float f; unsigned u; } c; c.f = x;
    unsigned r = c.u + 0x7fffu + ((c.u >> 16) & 1u);
    return (u16)(r >> 16);
}
__device__ __forceinline__ float to_f(u16 h) {
    union { unsigned u; float f; } c; c.u = ((unsigned)h) << 16;
    return c.f;
}
__device__ __forceinline__ void gload_lds16(const void* g, void* l) {
    __builtin_amdgcn_global_load_lds((const __attribute__((address_space(1))) unsigned int*)g,
                                     (__attribute__((address_space(3))) unsigned int*)l, 16, 0, 0);
}

// ---------------- tiny setup kernels ----------------
__global__ void k_wsfail(float* out) { out[0] = 1.0e9f; }

__global__ void k_zero(float* p, int n) {
    int i = blockIdx.x * 256 + threadIdx.x;
    if (i < n) p[i] = 0.0f;
}

__global__ void k_wt(const float* __restrict__ w, float* __restrict__ wt, int cout, int cin9) {
    int idx = blockIdx.x * 256 + threadIdx.x;
    if (idx < cout * cin9) {
        int co = idx / cin9, k = idx % cin9;
        wt[k * cout + co] = w[idx];
    }
}

// conv2 weights [64][32][3][3] -> bf16 [tap 9][cout 64][ci 32]
__global__ void k_wpack(const float* __restrict__ w, u16* __restrict__ wp) {
    int idx = blockIdx.x * 256 + threadIdx.x;
    if (idx < 18432) {
        int ci = idx & 31, tc = idx >> 5;
        int tap = tc >> 6, co = tc & 63;
        wp[idx] = to_bf(w[co * 288 + ci * 9 + tap]);
    }
}

// patch_w [512][64][8][8] ([cout][ci][ky][kx]) -> bf16 [cout][tap*64+ci] (tap=ky*8+kx)
__global__ void k_pperm(const float* __restrict__ w, u16* __restrict__ wp) {
    int idx = blockIdx.x * 256 + threadIdx.x;
    int cout = idx >> 12, rem = idx & 4095;
    int tap = rem >> 6, ci = rem & 63;
    wp[idx] = to_bf(w[cout * 4096 + ci * 64 + tap]);
}

// concat w1_b/w2_b -> bias12 [8][4096]
__global__ void k_biascat(const float* __restrict__ b1, const float* __restrict__ b2,
                          float* __restrict__ o) {
    int idx = blockIdx.x * 256 + threadIdx.x;
    if (idx < 32768) {
        int l = idx >> 12, c = idx & 4095;
        o[idx] = (c < 2048) ? b1[l * 2048 + c] : b2[l * 2048 + c - 2048];
    }
}

__global__ void k_tables(float* __restrict__ postab, float* __restrict__ ropetab) {
    int idx = blockIdx.x * 256 + threadIdx.x;
    if (idx < 256 * 512) {
        int p = idx >> 9, j = idx & 511;
        float coord = (j < 256) ? (float)(p >> 4) : (float)(p & 15);
        int jm = j & 127;
        float om = powf(10000.0f, -(float)jm / 128.0f);
        float arg = coord * om;
        postab[idx] = ((j >> 7) & 1) ? cosf(arg) : sinf(arg);
    }
    if (idx < 512) {
        // xpos tables indexed by HEAD h (reference quirk): n_pos = H = 8
        int h = idx >> 6, d = idx & 63;
        float freq = (float)h * powf(10000.0f, -(float)(d >> 1) / 32.0f);
        float sv = (2.0f * (float)(d & 31) + 25.6f) / 89.6f;
        float pw = ((float)h - 4.0f) / 512.0f;
        float sc = powf(sv, pw);
        ropetab[idx * 4 + 0] = cosf(freq);
        ropetab[idx * 4 + 1] = sinf(freq);
        ropetab[idx * 4 + 2] = sc;
        ropetab[idx * 4 + 3] = 1.0f / sc;
    }
}

__global__ void k_cls(const float* __restrict__ cls, float* __restrict__ xa) {
    int idx = blockIdx.x * 256 + threadIdx.x;
    int b = idx >> 9, d = idx & 511;
    xa[(size_t)(b * 257) * 512 + d] = cls[d];
}

// fp32 [K][N] -> bf16 [N][K] transpose-convert
__global__ __launch_bounds__(256) void k_wcvtT(const float* __restrict__ src,
                                               u16* __restrict__ dst, int K, int N) {
    __shared__ float s[32][33];
    int z = blockIdx.z;
    src += (size_t)z * K * N;
    dst += (size_t)z * K * N;
    int k0 = blockIdx.y * 32, n0 = blockIdx.x * 32;
    int t = threadIdx.x, r = t >> 3, c4 = (t & 7) * 4;
    float4 v = *(const float4*)&src[(size_t)(k0 + r) * N + n0 + c4];
    s[r][c4 + 0] = v.x; s[r][c4 + 1] = v.y; s[r][c4 + 2] = v.z; s[r][c4 + 3] = v.w;
    __syncthreads();
    ushort4 o;
    o.x = to_bf(s[c4 + 0][r]); o.y = to_bf(s[c4 + 1][r]);
    o.z = to_bf(s[c4 + 2][r]); o.w = to_bf(s[c4 + 3][r]);
    *(ushort4*)&dst[(size_t)(n0 + r) * K + k0 + c4] = o;
}

// dual-source transpose-convert: z selects src (s1|s2), dst offset z*K*N
__global__ __launch_bounds__(256) void k_wcvtT2(const float* __restrict__ s1,
                                                const float* __restrict__ s2,
                                                u16* __restrict__ dst, int K, int N) {
    __shared__ float s[32][33];
    int z = blockIdx.z;
    const float* src = z ? s2 : s1;
    dst += (size_t)z * K * N;
    int k0 = blockIdx.y * 32, n0 = blockIdx.x * 32;
    int t = threadIdx.x, r = t >> 3, c4 = (t & 7) * 4;
    float4 v = *(const float4*)&src[(size_t)(k0 + r) * N + n0 + c4];
    s[r][c4 + 0] = v.x; s[r][c4 + 1] = v.y; s[r][c4 + 2] = v.z; s[r][c4 + 3] = v.w;
    __syncthreads();
    ushort4 o;
    o.x = to_bf(s[c4 + 0][r]); o.y = to_bf(s[c4 + 1][r]);
    o.z = to_bf(s[c4 + 2][r]); o.w = to_bf(s[c4 + 3][r]);
    *(ushort4*)&dst[(size_t)(n0 + r) * K + k0 + c4] = o;
}

// ---------------- conv1: fp32 direct, bf16 NHWC out + GN partial sums ----------------
__global__ __launch_bounds__(256) void k_conv1(const float* __restrict__ in,
                                               const float* __restrict__ wt,   // [27][32]
                                               const float* __restrict__ bias,
                                               u16* __restrict__ f1n,
                                               float* __restrict__ sacc) {
    __shared__ float s_in[3][18][18];
    __shared__ float rs[4][4], rq[4][4];
    int b = blockIdx.y;
    int tile = blockIdx.x;
    int y0 = (tile >> 3) << 4;
    int x0 = (tile & 7) << 4;
    int tid = threadIdx.x;
    for (int idx = tid; idx < 972; idx += 256) {
        int ci = idx / 324, r = idx % 324;
        int ly = r / 18, lx = r % 18;
        int gy = y0 + ly - 1, gx = x0 + lx - 1;
        float v = 0.0f;
        if (gy >= 0 && gy < 128 && gx >= 0 && gx < 128)
            v = in[((size_t)(b * 3 + ci) * 128 + gy) * 128 + gx];
        s_in[ci][ly][lx] = v;
    }
    __syncthreads();
    int py = tid >> 4, px = tid & 15;
    float acc[32];
#pragma unroll
    for (int co = 0; co < 32; co++) acc[co] = bias[co];
#pragma unroll
    for (int ci = 0; ci < 3; ci++)
#pragma unroll
        for (int dy = 0; dy < 3; dy++)
#pragma unroll
            for (int dx = 0; dx < 3; dx++) {
                float v = s_in[ci][py + dy][px + dx];
                const float* wr = &wt[(ci * 9 + dy * 3 + dx) * 32];
#pragma unroll
                for (int co = 0; co < 32; co++)
                    acc[co] = fmaf(wr[co], v, acc[co]);
            }
    float s[4] = {0.f, 0.f, 0.f, 0.f}, q[4] = {0.f, 0.f, 0.f, 0.f};
    u16 ob[32];
#pragma unroll
    for (int co = 0; co < 32; co++) {
        u16 hv = to_bf(acc[co]);
        ob[co] = hv;
        float v = to_f(hv);
        s[co >> 3] += v;
        q[co >> 3] += v * v;
    }
    int oy = y0 + py, ox = x0 + px;
    u16* dst = f1n + ((size_t)(b * 16384 + oy * 128 + ox) << 5);
#pragma unroll
    for (int i = 0; i < 8; i++)
        *(ushort4*)(dst + i * 4) = make_ushort4(ob[i * 4], ob[i * 4 + 1], ob[i * 4 + 2], ob[i * 4 + 3]);
#pragma unroll
    for (int g = 0; g < 4; g++) {
#pragma unroll
        for (int off = 1; off < 64; off <<= 1) {
            s[g] += __shfl_xor(s[g], off);
            q[g] += __shfl_xor(q[g], off);
        }
    }
    int w = tid >> 6, lane = tid & 63;
    if (lane == 0)
#pragma unroll
        for (int g = 0; g < 4; g++) { rs[g][w] = s[g]; rq[g][w] = q[g]; }
    __syncthreads();
    if (tid < 4) {
        int g = tid;
        float S = rs[g][0] + rs[g][1] + rs[g][2] + rs[g][3];
        float Q = rq[g][0] + rq[g][1] + rq[g][2] + rq[g][3];
        atomicAdd(&sacc[(b * 4 + g) * 2], S);
        atomicAdd(&sacc[(b * 4 + g) * 2 + 1], Q);
    }
}

// finalize GN stats
__global__ void k_gnfin(const float* __restrict__ sacc, float* __restrict__ st, int entries) {
    int i = blockIdx.x * 256 + threadIdx.x;
    if (i < entries) {
        float m = sacc[2 * i] * (1.0f / 131072.0f);
        float var = sacc[2 * i + 1] * (1.0f / 131072.0f) - m * m;
        st[2 * i] = m;
        st[2 * i + 1] = rsqrtf(var + 1e-5f);
    }
}

// GN apply + GELU, bf16 NHWC in-place
__global__ void k_gnap(u16* __restrict__ xio, const float* __restrict__ st,
                       const float* __restrict__ gg, const float* __restrict__ bb,
                       int cm, int sh, int gmul) {
    int idx = blockIdx.x * 256 + threadIdx.x;
    long e = (long)idx * 4;
    int c0 = (int)(e & cm);
    int b = (int)(e >> sh);
    int sid = b * gmul + (c0 >> 3);
    float m = st[2 * sid], r = st[2 * sid + 1];
    ushort4 a = *(ushort4*)&xio[e];
    ushort4 o;
    o.x = to_bf(gelu_exact((to_f(a.x) - m) * r * gg[c0 + 0] + bb[c0 + 0]));
    o.y = to_bf(gelu_exact((to_f(a.y) - m) * r * gg[c0 + 1] + bb[c0 + 1]));
    o.z = to_bf(gelu_exact((to_f(a.z) - m) * r * gg[c0 + 2] + bb[c0 + 2]));
    o.w = to_bf(gelu_exact((to_f(a.w) - m) * r * gg[c0 + 3] + bb[c0 + 3]));
    *(ushort4*)&xio[e] = o;
}

// ---------------- conv2 as MFMA implicit GEMM (NHWC bf16) ----------------
__global__ __launch_bounds__(256) void k_conv2m(const u16* __restrict__ f1b,
                                                const u16* __restrict__ wp,   // [9][64][32]
                                                const float* __restrict__ bias,
                                                u16* __restrict__ f2n,
                                                float* __restrict__ sacc) {
    __shared__ u16 In[324 * 34];   // [pixel(18x18)][ci 32 +2 pad]
    __shared__ u16 Ws[576 * 34];   // [tap*64+cout][ci 32 +2 pad]
    int b = blockIdx.y;
    int tile = blockIdx.x;
    int y0 = (tile >> 3) << 4;
    int x0 = (tile & 7) << 4;
    int tid = threadIdx.x;
    int w = tid >> 6, lane = tid & 63;
    int l15 = lane & 15, l16 = lane >> 4;

    for (int idx = tid; idx < 2304; idx += 256) {
        int tc = idx >> 2, qd = idx & 3;
        *(ushort4*)&Ws[tc * 34 + qd * 8]     = *(const ushort4*)&wp[tc * 32 + qd * 8];
        *(ushort4*)&Ws[tc * 34 + qd * 8 + 4] = *(const ushort4*)&wp[tc * 32 + qd * 8 + 4];
    }
    for (int idx = tid; idx < 648; idx += 256) {
        int pix = idx >> 1, half = idx & 1;
        int pr = pix / 18, pc = pix % 18;
        int gy = y0 + pr - 1, gx = x0 + pc - 1;
        if (gy >= 0 && gy < 128 && gx >= 0 && gx < 128) {
            const u16* src = f1b + ((size_t)(b * 16384 + gy * 128 + gx) << 5) + half * 16;
            *(ushort4*)&In[pix * 34 + half * 16]      = *(const ushort4*)src;
            *(ushort4*)&In[pix * 34 + half * 16 + 4]  = *(const ushort4*)(src + 4);
            *(ushort4*)&In[pix * 34 + half * 16 + 8]  = *(const ushort4*)(src + 8);
            *(ushort4*)&In[pix * 34 + half * 16 + 12] = *(const ushort4*)(src + 12);
        } else {
            ushort4 z = make_ushort4(0, 0, 0, 0);
            *(ushort4*)&In[pix * 34 + half * 16]      = z;
            *(ushort4*)&In[pix * 34 + half * 16 + 4]  = z;
            *(ushort4*)&In[pix * 34 + half * 16 + 8]  = z;
            *(ushort4*)&In[pix * 34 + half * 16 + 12] = z;
        }
    }
    __syncthreads();

    f32x4 acc[4][4];
    f32x4 zf = {0.f, 0.f, 0.f, 0.f};
#pragma unroll
    for (int m = 0; m < 4; m++)
#pragma unroll
        for (int n = 0; n < 4; n++) acc[m][n] = zf;

#pragma unroll
    for (int tap = 0; tap < 9; tap++) {
        int dy = tap / 3, dx = tap % 3;
        bf16x8 af[4], bk[4];
#pragma unroll
        for (int m = 0; m < 4; m++)
            af[m] = *(const bf16x8*)&In[((w * 4 + m + dy) * 18 + l15 + dx) * 34 + l16 * 8];
#pragma unroll
        for (int n = 0; n < 4; n++)
            bk[n] = *(const bf16x8*)&Ws[(tap * 64 + n * 16 + l15) * 34 + l16 * 8];
#pragma unroll
        for (int m = 0; m < 4; m++)
#pragma unroll
            for (int n = 0; n < 4; n++)
                acc[m][n] = __builtin_amdgcn_mfma_f32_16x16x32_bf16(af[m], bk[n], acc[m][n], 0, 0, 0);
    }

#pragma unroll
    for (int n = 0; n < 4; n++) {
        int gco = n * 16 + l15;
        float bv = bias[gco];
        float sn = 0.0f, qn = 0.0f;
#pragma unroll
        for (int m = 0; m < 4; m++) {
            int py = w * 4 + m;
#pragma unroll
            for (int r = 0; r < 4; r++) {
                int px = l16 * 4 + r;
                float v = acc[m][n][r] + bv;
                u16 hv = to_bf(v);
                f2n[((size_t)(b * 16384 + (y0 + py) * 128 + x0 + px) << 6) + gco] = hv;
                float vf = to_f(hv);
                sn += vf;
                qn += vf * vf;
            }
        }
#pragma unroll
        for (int off = 1; off <= 4; off <<= 1) { sn += __shfl_xor(sn, off); qn += __shfl_xor(qn, off); }
        sn += __shfl_xor(sn, 16); qn += __shfl_xor(qn, 16);
        sn += __shfl_xor(sn, 32); qn += __shfl_xor(qn, 32);
        if (lane == 0 || lane == 8) {
            int g = n * 2 + (lane >> 3);
            atomicAdd(&sacc[(b * 8 + g) * 2], sn);
            atomicAdd(&sacc[(b * 8 + g) * 2 + 1], qn);
        }
    }
}

// ---------------- bf16 MFMA GEMM ----------------
// MODE 0: A [M,K] row-major. MODE 1: implicit im2col of f2n NHWC (k = tap*64+ci).
// EPI 1: fp32 C = acc+bias. EPI 2: fp32 C += acc+bias. EPI 3: patch scatter + postab.
// EPI 4: bf16 C = acc+bias.
template <int MODE, int EPI>
__global__ __launch_bounds__(256) void k_bgemm(const u16* __restrict__ A,
                                               const u16* __restrict__ Bt,
                                               const float* __restrict__ bias,
                                               void* __restrict__ Cp,
                                               const float* __restrict__ postab,
                                               int M, int N, int K) {
    __shared__ u16 ldsA[8192];   // [kg 8][row 128][8]
    __shared__ u16 ldsB[8192];   // [col 128][kg^swz 8][8]
    int tid = threadIdx.x;
    int w = tid >> 6, lane = tid & 63;
    int bm = blockIdx.y * 128, bn = blockIdx.x * 128;
    int wr = w >> 1, wc = w & 1;
    int l15 = lane & 15, l16 = lane >> 4;

    f32x4 acc[4][4];
    f32x4 zf = {0.f, 0.f, 0.f, 0.f};
#pragma unroll
    for (int m = 0; m < 4; m++)
#pragma unroll
        for (int n = 0; n < 4; n++) acc[m][n] = zf;

    for (int k0 = 0; k0 < K; k0 += 64) {
#pragma unroll
        for (int i = 0; i < 4; i++) {
            int chunk = (w * 4 + i) * 64 + lane;
            int kg = chunk >> 7, row = chunk & 127;
            const u16* src;
            if (MODE == 0) {
                int grow = bm + row;
                if (grow > M - 1) grow = M - 1;
                src = A + (size_t)grow * K + k0 + kg * 8;
            } else {
                int grow = bm + row;
                int bimg = grow >> 8, p = grow & 255;
                int kga = (k0 >> 3) + kg;
                int tap = kga >> 3, cq = kga & 7;
                int ky = tap >> 3, kx = tap & 7;
                int gy = ((p >> 4) << 3) + ky, gx = ((p & 15) << 3) + kx;
                src = A + (((size_t)(bimg * 16384 + gy * 128 + gx)) << 6) + cq * 8;
            }
            gload_lds16(src, &ldsA[(w * 4 + i) * 512]);
        }
#pragma unroll
        for (int i = 0; i < 4; i++) {
            int chunk = (w * 4 + i) * 64 + lane;
            int col = chunk >> 3, kgs = chunk & 7;
            int kg_src = kgs ^ (col & 7);
            const u16* src = Bt + (size_t)(bn + col) * K + k0 + kg_src * 8;
            gload_lds16(src, &ldsB[(w * 4 + i) * 512]);
        }
        __syncthreads();

        bf16x8 af[4][2], bfr[4][2];
#pragma unroll
        for (int kk = 0; kk < 2; kk++) {
            int kga = kk * 4 + l16;
#pragma unroll
            for (int m = 0; m < 4; m++) {
                int row_l = wr * 64 + m * 16 + l15;
                af[m][kk] = *(const bf16x8*)&ldsA[(kga * 128 + row_l) * 8];
            }
#pragma unroll
            for (int n = 0; n < 4; n++) {
                int col_l = wc * 64 + n * 16 + l15;
                bfr[n][kk] = *(const bf16x8*)&ldsB[(col_l * 8 + (kga ^ (col_l & 7))) * 8];
            }
        }
#pragma unroll
        for (int m = 0; m < 4; m++)
#pragma unroll
            for (int n = 0; n < 4; n++) {
                acc[m][n] = __builtin_amdgcn_mfma_f32_16x16x32_bf16(af[m][0], bfr[n][0], acc[m][n], 0, 0, 0);
                acc[m][n] = __builtin_amdgcn_mfma_f32_16x16x32_bf16(af[m][1], bfr[n][1], acc[m][n], 0, 0, 0);
            }
        __syncthreads();
    }

#pragma unroll
    for (int n = 0; n < 4; n++) {
        int gcol = bn + wc * 64 + n * 16 + l15;
        float bv = bias[gcol];
#pragma unroll
        for (int m = 0; m < 4; m++) {
#pragma unroll
            for (int r = 0; r < 4; r++) {
                int grow = bm + wr * 64 + m * 16 + l16 * 4 + r;
                float v = acc[m][n][r] + bv;
                if (EPI == 1) {
                    if (grow < M) ((float*)Cp)[(size_t)grow * N + gcol] = v;
                } else if (EPI == 2) {
                    if (grow < M) ((float*)Cp)[(size_t)grow * N + gcol] += v;
                } else if (EPI == 4) {
                    if (grow < M) ((u16*)Cp)[(size_t)grow * N + gcol] = to_bf(v);
                } else {
                    int bimg = grow >> 8, p = grow & 255;
                    v += postab[p * 512 + gcol];
                    ((float*)Cp)[((size_t)(bimg * 257) + 1 + p) * 512 + gcol] = v;
                }
            }
        }
    }
}

// ---------------- LayerNorm, wave-per-row (4 rows/block), bf16 out ----------------
__global__ __launch_bounds__(256) void k_lnb(const float* __restrict__ x,
                                             const float* __restrict__ g,
                                             const float* __restrict__ bta,
                                             u16* __restrict__ o) {
    int row = blockIdx.x * 4 + (threadIdx.x >> 6);
    int lane = threadIdx.x & 63;
    const float4* xr = (const float4*)(x + (size_t)row * 512);
    float4 a = xr[lane * 2], b = xr[lane * 2 + 1];
    float s = a.x + a.y + a.z + a.w + b.x + b.y + b.z + b.w;
#pragma unroll
    for (int off = 1; off < 64; off <<= 1) s += __shfl_xor(s, off);
    float mean = s * (1.0f / 512.0f);
    float d[8] = {a.x - mean, a.y - mean, a.z - mean, a.w - mean,
                  b.x - mean, b.y - mean, b.z - mean, b.w - mean};
    float q = 0.0f;
#pragma unroll
    for (int i = 0; i < 8; i++) q += d[i] * d[i];
#pragma unroll
    for (int off = 1; off < 64; off <<= 1) q += __shfl_xor(q, off);
    float rstd = rsqrtf(q * (1.0f / 512.0f) + EPSV);
    int c0 = lane * 8;
    float4 g0 = *(const float4*)&g[c0], g1 = *(const float4*)&g[c0 + 4];
    float4 b0 = *(const float4*)&bta[c0], b1 = *(const float4*)&bta[c0 + 4];
    u16* orow = o + (size_t)row * 512 + c0;
    *(ushort4*)orow = make_ushort4(to_bf(d[0] * rstd * g0.x + b0.x), to_bf(d[1] * rstd * g0.y + b0.y),
                                   to_bf(d[2] * rstd * g0.z + b0.z), to_bf(d[3] * rstd * g0.w + b0.w));
    *(ushort4*)(orow + 4) = make_ushort4(to_bf(d[4] * rstd * g1.x + b1.x), to_bf(d[5] * rstd * g1.y + b1.y),
                                         to_bf(d[6] * rstd * g1.z + b1.z), to_bf(d[7] * rstd * g1.w + b1.w));
}

// final LN, wave-per-row, output remap (fp32 out)
__global__ __launch_bounds__(256) void k_ln_out(const float* __restrict__ x,
                                                const float* __restrict__ g,
                                                const float* __restrict__ bta,
                                                float* __restrict__ out) {
    int row = blockIdx.x * 4 + (threadIdx.x >> 6);
    int lane = threadIdx.x & 63;
    const float4* xr = (const float4*)(x + (size_t)row * 512);
    float4 a = xr[lane * 2], b = xr[lane * 2 + 1];
    float s = a.x + a.y + a.z + a.w + b.x + b.y + b.z + b.w;
#pragma unroll
    for (int off = 1; off < 64; off <<= 1) s += __shfl_xor(s, off);
    float mean = s * (1.0f / 512.0f);
    float d[8] = {a.x - mean, a.y - mean, a.z - mean, a.w - mean,
                  b.x - mean, b.y - mean, b.z - mean, b.w - mean};
    float q = 0.0f;
#pragma unroll
    for (int i = 0; i < 8; i++) q += d[i] * d[i];
#pragma unroll
    for (int off = 1; off < 64; off <<= 1) q += __shfl_xor(q, off);
    float rstd = rsqrtf(q * (1.0f / 512.0f) + EPSV);
    int bb = row / 257, t = row % 257;
    float* dst = (t == 0) ? out + (size_t)bb * 512
                          : out + 16384 + (size_t)(bb * 256 + (t - 1)) * 512;
    int c0 = lane * 8;
    float4 g0 = *(const float4*)&g[c0], g1 = *(const float4*)&g[c0 + 4];
    float4 b0 = *(const float4*)&bta[c0], b1 = *(const float4*)&bta[c0 + 4];
    *(float4*)(dst + c0) = make_float4(d[0] * rstd * g0.x + b0.x, d[1] * rstd * g0.y + b0.y,
                                       d[2] * rstd * g0.z + b0.z, d[3] * rstd * g0.w + b0.w);
    *(float4*)(dst + c0 + 4) = make_float4(d[4] * rstd * g1.x + b1.x, d[5] * rstd * g1.y + b1.y,
                                           d[6] * rstd * g1.z + b1.z, d[7] * rstd * g1.w + b1.w);
}

// ---------------- MFMA attention, 32-row q tiles, rope fused ----------------
__global__ __launch_bounds__(256) void k_attn_mfma(const u16* __restrict__ qkv,
                                                   const float* __restrict__ rt,
                                                   u16* __restrict__ y) {
    __shared__ u16 Qs[32][72];
    __shared__ u16 KV[64][72];
    __shared__ float sc[32][260];
    __shared__ u16 Pb[32][328];
    __shared__ float red1[32][8];
    __shared__ float red2[32][8];
    __shared__ float invr[32];

    int bid = blockIdx.x;                 // ((b*8+h)*9 + qt)
    int qt = bid % 9, bh = bid / 9;
    int h = bh & 7, b = bh >> 3;
    int q0 = qt * 32;
    int tid = threadIdx.x;
    int w = tid >> 6, lane = tid & 63;
    int l15 = lane & 15, l16 = lane >> 4;

    {
        int srow = tid >> 3, d0 = (tid & 7) * 8;
        int grow = q0 + srow; if (grow > 256) grow = 256;
        const u16* qp = qkv + (size_t)(b * 257 + grow) * 1536 + h * 64 + d0;
        ushort4 a0 = *(const ushort4*)qp, a1 = *(const ushort4*)(qp + 4);
        float f[8] = {to_f(a0.x), to_f(a0.y), to_f(a0.z), to_f(a0.w),
                      to_f(a1.x), to_f(a1.y), to_f(a1.z), to_f(a1.w)};
        const float* rb = rt + (h * 64 + d0) * 4;
        u16 o[8];
#pragma unroll
        for (int i = 0; i < 8; i += 2) {
            float c = rb[i * 4], s = rb[i * 4 + 1], sa = rb[i * 4 + 2], sb = rb[i * 4 + 6];
            o[i]     = to_bf((f[i] * c - f[i + 1] * s) * sa * 0.125f);
            o[i + 1] = to_bf((f[i + 1] * c + f[i] * s) * sb * 0.125f);
        }
        *(ushort4*)&Qs[srow][d0]     = make_ushort4(o[0], o[1], o[2], o[3]);
        *(ushort4*)&Qs[srow][d0 + 4] = make_ushort4(o[4], o[5], o[6], o[7]);
    }
    __syncthreads();

    bf16x8 aq[2][2];
#pragma unroll
    for (int m = 0; m < 2; m++)
#pragma unroll
        for (int kk = 0; kk < 2; kk++)
            aq[m][kk] = *(const bf16x8*)&Qs[m * 16 + l15][kk * 32 + l16 * 8];

    for (int t = 0; t < 5; t++) {
        int j0 = t * 64;
        {
            int srow = tid >> 2, d0 = (tid & 3) * 16;
            int gk = j0 + srow;
            u16 o[16];
            if (gk <= 256) {
                const u16* kp = qkv + (size_t)(b * 257 + gk) * 1536 + 512 + h * 64 + d0;
                ushort4 a0 = *(const ushort4*)kp, a1 = *(const ushort4*)(kp + 4);
                ushort4 a2 = *(const ushort4*)(kp + 8), a3 = *(const ushort4*)(kp + 12);
                float f[16] = {to_f(a0.x), to_f(a0.y), to_f(a0.z), to_f(a0.w),
                               to_f(a1.x), to_f(a1.y), to_f(a1.z), to_f(a1.w),
                               to_f(a2.x), to_f(a2.y), to_f(a2.z), to_f(a2.w),
                               to_f(a3.x), to_f(a3.y), to_f(a3.z), to_f(a3.w)};
                const float* rb = rt + (h * 64 + d0) * 4;
#pragma unroll
                for (int i = 0; i < 16; i += 2) {
                    float c = rb[i * 4], s = rb[i * 4 + 1], sa = rb[i * 4 + 3], sb = rb[i * 4 + 7];
                    o[i]     = to_bf((f[i] * c - f[i + 1] * s) * sa);
                    o[i + 1] = to_bf((f[i + 1] * c + f[i] * s) * sb);
                }
            } else {
#pragma unroll
                for (int i = 0; i < 16; i++) o[i] = 0;
            }
#pragma unroll
            for (int i = 0; i < 4; i++)
                *(ushort4*)&KV[tid >> 2][d0 + i * 4] =
                    make_ushort4(o[i * 4], o[i * 4 + 1], o[i * 4 + 2], o[i * 4 + 3]);
        }
        __syncthreads();

        bf16x8 bk[2];
#pragma unroll
        for (int kk = 0; kk < 2; kk++)
            bk[kk] = *(const bf16x8*)&KV[w * 16 + l15][kk * 32 + l16 * 8];
        f32x4 a2[2];
        f32x4 zf = {0.f, 0.f, 0.f, 0.f};
#pragma unroll
        for (int m = 0; m < 2; m++) {
            a2[m] = zf;
            a2[m] = __builtin_amdgcn_mfma_f32_16x16x32_bf16(aq[m][0], bk[0], a2[m], 0, 0, 0);
            a2[m] = __builtin_amdgcn_mfma_f32_16x16x32_bf16(aq[m][1], bk[1], a2[m], 0, 0, 0);
        }
        int col = j0 + w * 16 + l15;
#pragma unroll
        for (int m = 0; m < 2; m++)
#pragma unroll
            for (int r = 0; r < 4; r++)
                if (col < 257) sc[m * 16 + l16 * 4 + r][col] = a2[m][r];
        __syncthreads();
    }

    {
        int r = tid >> 3, sub = tid & 7;
        float mx = -1e30f;
        for (int j = sub; j < 257; j += 8) mx = fmaxf(mx, sc[r][j]);
        red1[r][sub] = mx;
        __syncthreads();
        mx = red1[r][0];
#pragma unroll
        for (int i = 1; i < 8; i++) mx = fmaxf(mx, red1[r][i]);
        float sm = 0.0f;
        for (int j = sub; j < 257; j += 8) {
            float e = __expf(sc[r][j] - mx);
            Pb[r][j] = to_bf(e);
            sm += e;
        }
        for (int j = 257 + sub; j < 320; j += 8) Pb[r][j] = 0;
        red2[r][sub] = sm;
        __syncthreads();
        if (sub == 0) {
            float t = red2[r][0];
#pragma unroll
            for (int i = 1; i < 8; i++) t += red2[r][i];
            invr[r] = 1.0f / t;
        }
        __syncthreads();
    }

    f32x4 oacc[2];
    {
        f32x4 zf = {0.f, 0.f, 0.f, 0.f};
        oacc[0] = zf; oacc[1] = zf;
    }
    for (int t = 0; t < 5; t++) {
        int j0 = t * 64;
        {
            int vk = tid & 63, vd0 = (tid >> 6) * 16;
            int gk = j0 + vk;
            u16 o[16];
            if (gk <= 256) {
                const u16* vp = qkv + (size_t)(b * 257 + gk) * 1536 + 1024 + h * 64 + vd0;
                ushort4 a0 = *(const ushort4*)vp, a1 = *(const ushort4*)(vp + 4);
                ushort4 a2v = *(const ushort4*)(vp + 8), a3 = *(const ushort4*)(vp + 12);
                o[0] = a0.x; o[1] = a0.y; o[2] = a0.z; o[3] = a0.w;
                o[4] = a1.x; o[5] = a1.y; o[6] = a1.z; o[7] = a1.w;
                o[8] = a2v.x; o[9] = a2v.y; o[10] = a2v.z; o[11] = a2v.w;
                o[12] = a3.x; o[13] = a3.y; o[14] = a3.z; o[15] = a3.w;
            } else {
#pragma unroll
                for (int i = 0; i < 16; i++) o[i] = 0;
            }
#pragma unroll
            for (int i = 0; i < 16; i++) KV[vd0 + i][vk] = o[i];
        }
        __syncthreads();

        bf16x8 ap[2][2], bv[2];
#pragma unroll
        for (int m = 0; m < 2; m++)
#pragma unroll
            for (int kk = 0; kk < 2; kk++)
                ap[m][kk] = *(const bf16x8*)&Pb[m * 16 + l15][j0 + kk * 32 + l16 * 8];
#pragma unroll
        for (int kk = 0; kk < 2; kk++)
            bv[kk] = *(const bf16x8*)&KV[w * 16 + l15][kk * 32 + l16 * 8];
#pragma unroll
        for (int m = 0; m < 2; m++) {
            oacc[m] = __builtin_amdgcn_mfma_f32_16x16x32_bf16(ap[m][0], bv[0], oacc[m], 0, 0, 0);
            oacc[m] = __builtin_amdgcn_mfma_f32_16x16x32_bf16(ap[m][1], bv[1], oacc[m], 0, 0, 0);
        }
        __syncthreads();
    }

#pragma unroll
    for (int m = 0; m < 2; m++)
#pragma unroll
        for (int r = 0; r < 4; r++) {
            int lr = m * 16 + l16 * 4 + r;
            int grow = q0 + lr;
            if (grow < 257)
                y[(size_t)(b * 257 + grow) * 512 + h * 64 + w * 16 + l15] =
                    to_bf(oacc[m][r] * invr[lr]);
        }
}

// ---------------- SwiGLU on merged h12: hb = silu(h12[:, :2048]) * h12[:, 2048:] ----------------
__global__ void k_swiglu2(const u16* __restrict__ h12, u16* __restrict__ hb) {
    int idx = blockIdx.x * 256 + threadIdx.x;
    long e = (long)idx * 4;
    long row = e >> 11;
    int c = (int)(e & 2047);
    const u16* p1 = h12 + row * 4096 + c;
    ushort4 a = *(const ushort4*)p1;
    ushort4 b = *(const ushort4*)(p1 + 2048);
    ushort4 o;
    float x;
    x = to_f(a.x); o.x = to_bf(x / (1.0f + __expf(-x)) * to_f(b.x));
    x = to_f(a.y); o.y = to_bf(x / (1.0f + __expf(-x)) * to_f(b.y));
    x = to_f(a.z); o.z = to_bf(x / (1.0f + __expf(-x)) * to_f(b.z));
    x = to_f(a.w); o.w = to_bf(x / (1.0f + __expf(-x)) * to_f(b.w));
    *(ushort4*)&hb[row * 2048 + c] = o;
}

// ---------------- host launch ----------------
extern "C" void kernel_launch(void* const* d_in, const int* in_sizes, int n_in,
                              void* d_out, int out_size, void* d_ws, size_t ws_size,
                              hipStream_t stream) {
    const float* x       = (const float*)d_in[0];
    const float* conv1_w = (const float*)d_in[1];
    const float* conv1_b = (const float*)d_in[2];
    const float* gn1_g   = (const float*)d_in[3];
    const float* gn1_b   = (const float*)d_in[4];
    const float* conv2_w = (const float*)d_in[5];
    const float* conv2_b = (const float*)d_in[6];
    const float* gn2_g   = (const float*)d_in[7];
    const float* gn2_b   = (const float*)d_in[8];
    const float* patch_w = (const float*)d_in[9];
    const float* patch_b = (const float*)d_in[10];
    const float* cls_tok = (const float*)d_in[11];
    const float* ln1_g   = (const float*)d_in[12];
    const float* ln1_b   = (const float*)d_in[13];
    const float* qkv_w   = (const float*)d_in[14];
    const float* qkv_b   = (const float*)d_in[15];
    const float* out_w   = (const float*)d_in[16];
    const float* out_b   = (const float*)d_in[17];
    const float* ln2_g   = (const float*)d_in[18];
    const float* ln2_b   = (const float*)d_in[19];
    const float* w1_w    = (const float*)d_in[20];
    const float* w1_b    = (const float*)d_in[21];
    const float* w2_w    = (const float*)d_in[22];
    const float* w2_b    = (const float*)d_in[23];
    const float* w3_w    = (const float*)d_in[24];
    const float* w3_b    = (const float*)d_in[25];
    const float* fn_g    = (const float*)d_in[26];
    const float* fn_b    = (const float*)d_in[27];
    float* out = (float*)d_out;
    char* wsb  = (char*)d_ws;

    // arena (bytes), lifetime-aliased. Total 246,181,888 < 252,991,488 proven avail.
    const size_t O_R1    = 0;                 // f2n 67.1MB | h12b 67.4MB (sequential lifetimes)
    const size_t O_H12   = O_R1 + 0;          // 67,371,008
    const size_t O_HB    = O_R1 + 67371008;   // 33,685,504
    const size_t O_NB    = O_R1 + 101056512;  // 8,421,376
    const size_t O_Y     = O_R1 + 109477888;  // 8,421,376
    const size_t O_R2    = 134217728;         // f1n bf16 33.5MB | qkvb bf16 25.3MB
    const size_t O_XA    = 201326592;
    const size_t O_PWT   = 218169344;
    const size_t O_QKVT  = 222363648;
    const size_t O_OUTT  = 234946560;
    const size_t O_WL    = 239140864;         // w12Tl 4,194,304 + w3Tl 2,097,152
    const size_t O_PT    = 245432320;
    const size_t O_RT    = 245956608;
    const size_t O_CW1   = 245964800;
    const size_t O_CW2   = 245968896;
    const size_t O_ST    = 246042624;
    const size_t O_SA    = 246046720;
    const size_t O_B12   = 246050816;         // bias12 131,072
    const size_t NEED    = 246181888;
    if (ws_size < NEED) {
        k_wsfail<<<1, 1, 0, stream>>>(out);
        return;
    }
    u16*   f2n    = (u16*)(wsb + O_R1);
    u16*   h12b   = (u16*)(wsb + O_H12);
    u16*   hb     = (u16*)(wsb + O_HB);
    u16*   nb     = (u16*)(wsb + O_NB);
    u16*   yb     = (u16*)(wsb + O_Y);
    u16*   f1n    = (u16*)(wsb + O_R2);
    u16*   qkvb   = (u16*)(wsb + O_R2);
    float* xa     = (float*)(wsb + O_XA);
    u16*   patchT = (u16*)(wsb + O_PWT);
    u16*   qkvT   = (u16*)(wsb + O_QKVT);
    u16*   outT   = (u16*)(wsb + O_OUTT);
    u16*   w12Tl  = (u16*)(wsb + O_WL);
    u16*   w3Tl   = (u16*)(wsb + O_WL + 4194304);
    float* postab = (float*)(wsb + O_PT);
    float* ropet  = (float*)(wsb + O_RT);
    float* w1t    = (float*)(wsb + O_CW1);
    u16*   wpack  = (u16*)(wsb + O_CW2);
    float* stat   = (float*)(wsb + O_ST);
    float* sacc   = (float*)(wsb + O_SA);
    float* bias12 = (float*)(wsb + O_B12);

    // setup
    k_zero<<<3, 256, 0, stream>>>(sacc, 768);
    k_wt<<<4, 256, 0, stream>>>(conv1_w, w1t, 32, 27);
    k_wpack<<<72, 256, 0, stream>>>(conv2_w, wpack);
    k_tables<<<512, 256, 0, stream>>>(postab, ropet);
    k_pperm<<<8192, 256, 0, stream>>>(patch_w, patchT);
    k_biascat<<<128, 256, 0, stream>>>(w1_b, w2_b, bias12);
    k_wcvtT<<<dim3(48, 16, 8), 256, 0, stream>>>(qkv_w, qkvT, 512, 1536);
    k_wcvtT<<<dim3(16, 16, 8), 256, 0, stream>>>(out_w, outT, 512, 512);

    // conv stem (NHWC bf16, fused GN stats)
    k_conv1<<<dim3(64, 32), 256, 0, stream>>>(x, w1t, conv1_b, f1n, sacc);
    k_gnfin<<<1, 256, 0, stream>>>(sacc, stat, 128);
    k_gnap<<<16384, 256, 0, stream>>>(f1n, stat, gn1_g, gn1_b, 31, 19, 4);
    k_conv2m<<<dim3(64, 32), 256, 0, stream>>>(f1n, wpack, conv2_b, f2n, sacc + 256);
    k_gnfin<<<1, 256, 0, stream>>>(sacc + 256, stat + 256, 256);
    k_gnap<<<32768, 256, 0, stream>>>(f2n, stat + 256, gn2_g, gn2_b, 63, 20, 8);

    // patch embed + cls
    k_bgemm<1, 3><<<dim3(4, 64), 256, 0, stream>>>(f2n, patchT, patch_b, xa, postab, 8192, 512, 4096);
    k_cls<<<64, 256, 0, stream>>>(cls_tok, xa);

    // transformer
    for (int l = 0; l < 8; l++) {
        k_wcvtT2<<<dim3(64, 16, 2), 256, 0, stream>>>(w1_w + (size_t)l * 1048576,
                                                      w2_w + (size_t)l * 1048576, w12Tl, 512, 2048);
        k_wcvtT<<<dim3(16, 64, 1), 256, 0, stream>>>(w3_w + (size_t)l * 1048576, w3Tl, 2048, 512);

        k_lnb<<<2056, 256, 0, stream>>>(xa, ln1_g + l * 512, ln1_b + l * 512, nb);
        k_bgemm<0, 4><<<dim3(12, 65), 256, 0, stream>>>(nb, qkvT + (size_t)l * 786432,
                                                        qkv_b + l * 1536, qkvb, nullptr, 8224, 1536, 512);
        k_attn_mfma<<<2304, 256, 0, stream>>>(qkvb, ropet, yb);
        k_bgemm<0, 2><<<dim3(4, 65), 256, 0, stream>>>(yb, outT + (size_t)l * 262144,
                                                       out_b + l * 512, xa, nullptr, 8224, 512, 512);
        k_lnb<<<2056, 256, 0, stream>>>(xa, ln2_g + l * 512, ln2_b + l * 512, nb);
        k_bgemm<0, 4><<<dim3(32, 65), 256, 0, stream>>>(nb, w12Tl,
                                                        bias12 + l * 4096, h12b, nullptr, 8224, 4096, 512);
        k_swiglu2<<<16448, 256, 0, stream>>>(h12b, hb);
        k_bgemm<0, 2><<<dim3(4, 65), 256, 0, stream>>>(hb, w3Tl,
                                                       w3_b + l * 512, xa, nullptr, 8224, 512, 2048);
    }
    k_ln_out<<<2056, 256, 0, stream>>>(xa, fn_g, fn_b, out);
}

// Round 8
// 3019.971 us; speedup vs baseline: 5.8841x; 1.0377x over previous
//
#include <hip/hip_runtime.h>

#define EPSV 1e-5f
typedef unsigned short u16;
typedef short bf16x8 __attribute__((ext_vector_type(8)));
typedef float f32x4 __attribute__((ext_vector_type(4)));

__device__ __forceinline__ float gelu_exact(float x) {
    return 0.5f * x * (1.0f + erff(x * 0.7071067811865475f));
}
__device__ __forceinline__ u16 to_bf(float x) {
    union { float f; unsigned u; } c; c.f = x;
    unsigned r = c.u + 0x7fffu + ((c.u >> 16) & 1u);
    return (u16)(r >> 16);
}
__device__ __forceinline__ float to_f(u16 h) {
    union { unsigned u; float f; } c; c.u = ((unsigned)h) << 16;
    return c.f;
}
__device__ __forceinline__ void gload_lds16(const void* g, void* l) {
    __builtin_amdgcn_global_load_lds((const __attribute__((address_space(1))) unsigned int*)g,
                                     (__attribute__((address_space(3))) unsigned int*)l, 16, 0, 0);
}

// ---------------- tiny setup kernels ----------------
__global__ void k_wsfail(float* out) { out[0] = 1.0e9f; }

__global__ void k_zero(float* p, int n) {
    int i = blockIdx.x * 256 + threadIdx.x;
    if (i < n) p[i] = 0.0f;
}

__global__ void k_wt(const float* __restrict__ w, float* __restrict__ wt, int cout, int cin9) {
    int idx = blockIdx.x * 256 + threadIdx.x;
    if (idx < cout * cin9) {
        int co = idx / cin9, k = idx % cin9;
        wt[k * cout + co] = w[idx];
    }
}

// conv2 weights [64][32][3][3] -> bf16 [tap 9][cout 64][ci 32]
__global__ void k_wpack(const float* __restrict__ w, u16* __restrict__ wp) {
    int idx = blockIdx.x * 256 + threadIdx.x;
    if (idx < 18432) {
        int ci = idx & 31, tc = idx >> 5;
        int tap = tc >> 6, co = tc & 63;
        wp[idx] = to_bf(w[co * 288 + ci * 9 + tap]);
    }
}

// patch_w [512][64][8][8] ([cout][ci][ky][kx]) -> bf16 [cout][tap*64+ci] (tap=ky*8+kx)
__global__ void k_pperm(const float* __restrict__ w, u16* __restrict__ wp) {
    int idx = blockIdx.x * 256 + threadIdx.x;
    int cout = idx >> 12, rem = idx & 4095;
    int tap = rem >> 6, ci = rem & 63;
    wp[idx] = to_bf(w[cout * 4096 + ci * 64 + tap]);
}

// concat w1_b/w2_b -> bias12 [8][4096]
__global__ void k_biascat(const float* __restrict__ b1, const float* __restrict__ b2,
                          float* __restrict__ o) {
    int idx = blockIdx.x * 256 + threadIdx.x;
    if (idx < 32768) {
        int l = idx >> 12, c = idx & 4095;
        o[idx] = (c < 2048) ? b1[l * 2048 + c] : b2[l * 2048 + c - 2048];
    }
}

__global__ void k_tables(float* __restrict__ postab, float* __restrict__ ropetab) {
    int idx = blockIdx.x * 256 + threadIdx.x;
    if (idx < 256 * 512) {
        int p = idx >> 9, j = idx & 511;
        float coord = (j < 256) ? (float)(p >> 4) : (float)(p & 15);
        int jm = j & 127;
        float om = powf(10000.0f, -(float)jm / 128.0f);
        float arg = coord * om;
        postab[idx] = ((j >> 7) & 1) ? cosf(arg) : sinf(arg);
    }
    if (idx < 512) {
        // xpos tables indexed by HEAD h (reference quirk): n_pos = H = 8
        int h = idx >> 6, d = idx & 63;
        float freq = (float)h * powf(10000.0f, -(float)(d >> 1) / 32.0f);
        float sv = (2.0f * (float)(d & 31) + 25.6f) / 89.6f;
        float pw = ((float)h - 4.0f) / 512.0f;
        float sc = powf(sv, pw);
        ropetab[idx * 4 + 0] = cosf(freq);
        ropetab[idx * 4 + 1] = sinf(freq);
        ropetab[idx * 4 + 2] = sc * 0.125f;   // q scale, HD^-0.5 folded
        ropetab[idx * 4 + 3] = 1.0f / sc;     // k scale
    }
}

__global__ void k_cls(const float* __restrict__ cls, float* __restrict__ xa) {
    int idx = blockIdx.x * 256 + threadIdx.x;
    int b = idx >> 9, d = idx & 511;
    xa[(size_t)(b * 257) * 512 + d] = cls[d];
}

// fp32 [K][N] -> bf16 [N][K] transpose-convert
__global__ __launch_bounds__(256) void k_wcvtT(const float* __restrict__ src,
                                               u16* __restrict__ dst, int K, int N) {
    __shared__ float s[32][33];
    int z = blockIdx.z;
    src += (size_t)z * K * N;
    dst += (size_t)z * K * N;
    int k0 = blockIdx.y * 32, n0 = blockIdx.x * 32;
    int t = threadIdx.x, r = t >> 3, c4 = (t & 7) * 4;
    float4 v = *(const float4*)&src[(size_t)(k0 + r) * N + n0 + c4];
    s[r][c4 + 0] = v.x; s[r][c4 + 1] = v.y; s[r][c4 + 2] = v.z; s[r][c4 + 3] = v.w;
    __syncthreads();
    ushort4 o;
    o.x = to_bf(s[c4 + 0][r]); o.y = to_bf(s[c4 + 1][r]);
    o.z = to_bf(s[c4 + 2][r]); o.w = to_bf(s[c4 + 3][r]);
    *(ushort4*)&dst[(size_t)(n0 + r) * K + k0 + c4] = o;
}

// dual-source transpose-convert: z selects src (s1|s2), dst offset z*K*N
__global__ __launch_bounds__(256) void k_wcvtT2(const float* __restrict__ s1,
                                                const float* __restrict__ s2,
                                                u16* __restrict__ dst, int K, int N) {
    __shared__ float s[32][33];
    int z = blockIdx.z;
    const float* src = z ? s2 : s1;
    dst += (size_t)z * K * N;
    int k0 = blockIdx.y * 32, n0 = blockIdx.x * 32;
    int t = threadIdx.x, r = t >> 3, c4 = (t & 7) * 4;
    float4 v = *(const float4*)&src[(size_t)(k0 + r) * N + n0 + c4];
    s[r][c4 + 0] = v.x; s[r][c4 + 1] = v.y; s[r][c4 + 2] = v.z; s[r][c4 + 3] = v.w;
    __syncthreads();
    ushort4 o;
    o.x = to_bf(s[c4 + 0][r]); o.y = to_bf(s[c4 + 1][r]);
    o.z = to_bf(s[c4 + 2][r]); o.w = to_bf(s[c4 + 3][r]);
    *(ushort4*)&dst[(size_t)(n0 + r) * K + k0 + c4] = o;
}

// ---------------- conv1: fp32 direct, bf16 NHWC out + GN partial sums ----------------
__global__ __launch_bounds__(256) void k_conv1(const float* __restrict__ in,
                                               const float* __restrict__ wt,   // [27][32]
                                               const float* __restrict__ bias,
                                               u16* __restrict__ f1n,
                                               float* __restrict__ sacc) {
    __shared__ float s_in[3][18][18];
    __shared__ float rs[4][4], rq[4][4];
    int b = blockIdx.y;
    int tile = blockIdx.x;
    int y0 = (tile >> 3) << 4;
    int x0 = (tile & 7) << 4;
    int tid = threadIdx.x;
    for (int idx = tid; idx < 972; idx += 256) {
        int ci = idx / 324, r = idx % 324;
        int ly = r / 18, lx = r % 18;
        int gy = y0 + ly - 1, gx = x0 + lx - 1;
        float v = 0.0f;
        if (gy >= 0 && gy < 128 && gx >= 0 && gx < 128)
            v = in[((size_t)(b * 3 + ci) * 128 + gy) * 128 + gx];
        s_in[ci][ly][lx] = v;
    }
    __syncthreads();
    int py = tid >> 4, px = tid & 15;
    float acc[32];
#pragma unroll
    for (int co = 0; co < 32; co++) acc[co] = bias[co];
#pragma unroll
    for (int ci = 0; ci < 3; ci++)
#pragma unroll
        for (int dy = 0; dy < 3; dy++)
#pragma unroll
            for (int dx = 0; dx < 3; dx++) {
                float v = s_in[ci][py + dy][px + dx];
                const float* wr = &wt[(ci * 9 + dy * 3 + dx) * 32];
#pragma unroll
                for (int co = 0; co < 32; co++)
                    acc[co] = fmaf(wr[co], v, acc[co]);
            }
    float s[4] = {0.f, 0.f, 0.f, 0.f}, q[4] = {0.f, 0.f, 0.f, 0.f};
    u16 ob[32];
#pragma unroll
    for (int co = 0; co < 32; co++) {
        u16 hv = to_bf(acc[co]);
        ob[co] = hv;
        float v = to_f(hv);
        s[co >> 3] += v;
        q[co >> 3] += v * v;
    }
    int oy = y0 + py, ox = x0 + px;
    u16* dst = f1n + ((size_t)(b * 16384 + oy * 128 + ox) << 5);
#pragma unroll
    for (int i = 0; i < 8; i++)
        *(ushort4*)(dst + i * 4) = make_ushort4(ob[i * 4], ob[i * 4 + 1], ob[i * 4 + 2], ob[i * 4 + 3]);
#pragma unroll
    for (int g = 0; g < 4; g++) {
#pragma unroll
        for (int off = 1; off < 64; off <<= 1) {
            s[g] += __shfl_xor(s[g], off);
            q[g] += __shfl_xor(q[g], off);
        }
    }
    int w = tid >> 6, lane = tid & 63;
    if (lane == 0)
#pragma unroll
        for (int g = 0; g < 4; g++) { rs[g][w] = s[g]; rq[g][w] = q[g]; }
    __syncthreads();
    if (tid < 4) {
        int g = tid;
        float S = rs[g][0] + rs[g][1] + rs[g][2] + rs[g][3];
        float Q = rq[g][0] + rq[g][1] + rq[g][2] + rq[g][3];
        atomicAdd(&sacc[(b * 4 + g) * 2], S);
        atomicAdd(&sacc[(b * 4 + g) * 2 + 1], Q);
    }
}

// finalize GN stats
__global__ void k_gnfin(const float* __restrict__ sacc, float* __restrict__ st, int entries) {
    int i = blockIdx.x * 256 + threadIdx.x;
    if (i < entries) {
        float m = sacc[2 * i] * (1.0f / 131072.0f);
        float var = sacc[2 * i + 1] * (1.0f / 131072.0f) - m * m;
        st[2 * i] = m;
        st[2 * i + 1] = rsqrtf(var + 1e-5f);
    }
}

// GN apply + GELU, bf16 NHWC in-place
__global__ void k_gnap(u16* __restrict__ xio, const float* __restrict__ st,
                       const float* __restrict__ gg, const float* __restrict__ bb,
                       int cm, int sh, int gmul) {
    int idx = blockIdx.x * 256 + threadIdx.x;
    long e = (long)idx * 4;
    int c0 = (int)(e & cm);
    int b = (int)(e >> sh);
    int sid = b * gmul + (c0 >> 3);
    float m = st[2 * sid], r = st[2 * sid + 1];
    ushort4 a = *(ushort4*)&xio[e];
    ushort4 o;
    o.x = to_bf(gelu_exact((to_f(a.x) - m) * r * gg[c0 + 0] + bb[c0 + 0]));
    o.y = to_bf(gelu_exact((to_f(a.y) - m) * r * gg[c0 + 1] + bb[c0 + 1]));
    o.z = to_bf(gelu_exact((to_f(a.z) - m) * r * gg[c0 + 2] + bb[c0 + 2]));
    o.w = to_bf(gelu_exact((to_f(a.w) - m) * r * gg[c0 + 3] + bb[c0 + 3]));
    *(ushort4*)&xio[e] = o;
}

// ---------------- conv2 as MFMA implicit GEMM, ZERO LDS (L1-resident tile, L2 weights) ----------------
__global__ __launch_bounds__(256) void k_conv2m(const u16* __restrict__ f1b,
                                                const u16* __restrict__ wp,   // [9][64][32]
                                                const float* __restrict__ bias,
                                                u16* __restrict__ f2n,
                                                float* __restrict__ sacc) {
    int b = blockIdx.y;
    int tile = blockIdx.x;
    int y0 = (tile >> 3) << 4;
    int x0 = (tile & 7) << 4;
    int tid = threadIdx.x;
    int w = tid >> 6, lane = tid & 63;
    int l15 = lane & 15, l16 = lane >> 4;

    const u16* base = f1b + ((size_t)b << 19);   // b * 16384 * 32

    f32x4 acc[4][4];
    f32x4 zf = {0.f, 0.f, 0.f, 0.f};
#pragma unroll
    for (int m = 0; m < 4; m++)
#pragma unroll
        for (int n = 0; n < 4; n++) acc[m][n] = zf;
    bf16x8 zb = {0, 0, 0, 0, 0, 0, 0, 0};

#pragma unroll
    for (int tap = 0; tap < 9; tap++) {
        int dy = tap / 3, dx = tap % 3;
        int gx = x0 + l15 + dx - 1;
        bf16x8 af[4], bk[4];
#pragma unroll
        for (int m = 0; m < 4; m++) {
            int gy = y0 + w * 4 + m + dy - 1;
            bool ok = (gy >= 0) && (gy < 128) && (gx >= 0) && (gx < 128);
            int pix = ok ? (gy * 128 + gx) : 0;
            bf16x8 v = *(const bf16x8*)(base + ((size_t)pix << 5) + l16 * 8);
            af[m] = ok ? v : zb;
        }
#pragma unroll
        for (int n = 0; n < 4; n++)
            bk[n] = *(const bf16x8*)&wp[(tap * 64 + n * 16 + l15) * 32 + l16 * 8];
#pragma unroll
        for (int m = 0; m < 4; m++)
#pragma unroll
            for (int n = 0; n < 4; n++)
                acc[m][n] = __builtin_amdgcn_mfma_f32_16x16x32_bf16(af[m], bk[n], acc[m][n], 0, 0, 0);
    }

    __shared__ float rs2[1];  // (unused; keeps no-LDS kernels uniform) 
    (void)rs2;

    // epilogue: write NHWC bf16 + GN partial sums (8 groups)
#pragma unroll
    for (int n = 0; n < 4; n++) {
        int gco = n * 16 + l15;
        float bv = bias[gco];
        float sn = 0.0f, qn = 0.0f;
#pragma unroll
        for (int m = 0; m < 4; m++) {
            int py = w * 4 + m;
#pragma unroll
            for (int r = 0; r < 4; r++) {
                int px = l16 * 4 + r;
                float v = acc[m][n][r] + bv;
                u16 hv = to_bf(v);
                f2n[((size_t)(b * 16384 + (y0 + py) * 128 + x0 + px) << 6) + gco] = hv;
                float vf = to_f(hv);
                sn += vf;
                qn += vf * vf;
            }
        }
#pragma unroll
        for (int off = 1; off <= 4; off <<= 1) { sn += __shfl_xor(sn, off); qn += __shfl_xor(qn, off); }
        sn += __shfl_xor(sn, 16); qn += __shfl_xor(qn, 16);
        sn += __shfl_xor(sn, 32); qn += __shfl_xor(qn, 32);
        if (lane == 0 || lane == 8) {
            int g = n * 2 + (lane >> 3);
            atomicAdd(&sacc[(b * 8 + g) * 2], sn);
            atomicAdd(&sacc[(b * 8 + g) * 2 + 1], qn);
        }
    }
}

// ---------------- bf16 MFMA GEMM ----------------
// MODE 0: A [M,K] row-major. MODE 1: implicit im2col of f2n NHWC (k = tap*64+ci).
// EPI 1: fp32 C = acc+bias. EPI 2: fp32 C += acc+bias. EPI 3: patch scatter + postab.
// EPI 4: bf16 C = acc+bias.
template <int MODE, int EPI>
__global__ __launch_bounds__(256) void k_bgemm(const u16* __restrict__ A,
                                               const u16* __restrict__ Bt,
                                               const float* __restrict__ bias,
                                               void* __restrict__ Cp,
                                               const float* __restrict__ postab,
                                               int M, int N, int K) {
    __shared__ u16 ldsA[8192];   // [kg 8][row 128][8]
    __shared__ u16 ldsB[8192];   // [col 128][kg^swz 8][8]
    int tid = threadIdx.x;
    int w = tid >> 6, lane = tid & 63;
    int bm = blockIdx.y * 128, bn = blockIdx.x * 128;
    int wr = w >> 1, wc = w & 1;
    int l15 = lane & 15, l16 = lane >> 4;

    f32x4 acc[4][4];
    f32x4 zf = {0.f, 0.f, 0.f, 0.f};
#pragma unroll
    for (int m = 0; m < 4; m++)
#pragma unroll
        for (int n = 0; n < 4; n++) acc[m][n] = zf;

    for (int k0 = 0; k0 < K; k0 += 64) {
#pragma unroll
        for (int i = 0; i < 4; i++) {
            int chunk = (w * 4 + i) * 64 + lane;
            int kg = chunk >> 7, row = chunk & 127;
            const u16* src;
            if (MODE == 0) {
                int grow = bm + row;
                if (grow > M - 1) grow = M - 1;
                src = A + (size_t)grow * K + k0 + kg * 8;
            } else {
                int grow = bm + row;
                int bimg = grow >> 8, p = grow & 255;
                int kga = (k0 >> 3) + kg;
                int tap = kga >> 3, cq = kga & 7;
                int ky = tap >> 3, kx = tap & 7;
                int gy = ((p >> 4) << 3) + ky, gx = ((p & 15) << 3) + kx;
                src = A + (((size_t)(bimg * 16384 + gy * 128 + gx)) << 6) + cq * 8;
            }
            gload_lds16(src, &ldsA[(w * 4 + i) * 512]);
        }
#pragma unroll
        for (int i = 0; i < 4; i++) {
            int chunk = (w * 4 + i) * 64 + lane;
            int col = chunk >> 3, kgs = chunk & 7;
            int kg_src = kgs ^ (col & 7);
            const u16* src = Bt + (size_t)(bn + col) * K + k0 + kg_src * 8;
            gload_lds16(src, &ldsB[(w * 4 + i) * 512]);
        }
        __syncthreads();

        bf16x8 af[4][2], bfr[4][2];
#pragma unroll
        for (int kk = 0; kk < 2; kk++) {
            int kga = kk * 4 + l16;
#pragma unroll
            for (int m = 0; m < 4; m++) {
                int row_l = wr * 64 + m * 16 + l15;
                af[m][kk] = *(const bf16x8*)&ldsA[(kga * 128 + row_l) * 8];
            }
#pragma unroll
            for (int n = 0; n < 4; n++) {
                int col_l = wc * 64 + n * 16 + l15;
                bfr[n][kk] = *(const bf16x8*)&ldsB[(col_l * 8 + (kga ^ (col_l & 7))) * 8];
            }
        }
#pragma unroll
        for (int m = 0; m < 4; m++)
#pragma unroll
            for (int n = 0; n < 4; n++) {
                acc[m][n] = __builtin_amdgcn_mfma_f32_16x16x32_bf16(af[m][0], bfr[n][0], acc[m][n], 0, 0, 0);
                acc[m][n] = __builtin_amdgcn_mfma_f32_16x16x32_bf16(af[m][1], bfr[n][1], acc[m][n], 0, 0, 0);
            }
        __syncthreads();
    }

#pragma unroll
    for (int n = 0; n < 4; n++) {
        int gcol = bn + wc * 64 + n * 16 + l15;
        float bv = bias[gcol];
#pragma unroll
        for (int m = 0; m < 4; m++) {
#pragma unroll
            for (int r = 0; r < 4; r++) {
                int grow = bm + wr * 64 + m * 16 + l16 * 4 + r;
                float v = acc[m][n][r] + bv;
                if (EPI == 1) {
                    if (grow < M) ((float*)Cp)[(size_t)grow * N + gcol] = v;
                } else if (EPI == 2) {
                    if (grow < M) ((float*)Cp)[(size_t)grow * N + gcol] += v;
                } else if (EPI == 4) {
                    if (grow < M) ((u16*)Cp)[(size_t)grow * N + gcol] = to_bf(v);
                } else {
                    int bimg = grow >> 8, p = grow & 255;
                    v += postab[p * 512 + gcol];
                    ((float*)Cp)[((size_t)(bimg * 257) + 1 + p) * 512 + gcol] = v;
                }
            }
        }
    }
}

// ---------------- LayerNorm, wave-per-row (4 rows/block), bf16 out ----------------
__global__ __launch_bounds__(256) void k_lnb(const float* __restrict__ x,
                                             const float* __restrict__ g,
                                             const float* __restrict__ bta,
                                             u16* __restrict__ o) {
    int row = blockIdx.x * 4 + (threadIdx.x >> 6);
    int lane = threadIdx.x & 63;
    const float4* xr = (const float4*)(x + (size_t)row * 512);
    float4 a = xr[lane * 2], b = xr[lane * 2 + 1];
    float s = a.x + a.y + a.z + a.w + b.x + b.y + b.z + b.w;
#pragma unroll
    for (int off = 1; off < 64; off <<= 1) s += __shfl_xor(s, off);
    float mean = s * (1.0f / 512.0f);
    float d[8] = {a.x - mean, a.y - mean, a.z - mean, a.w - mean,
                  b.x - mean, b.y - mean, b.z - mean, b.w - mean};
    float q = 0.0f;
#pragma unroll
    for (int i = 0; i < 8; i++) q += d[i] * d[i];
#pragma unroll
    for (int off = 1; off < 64; off <<= 1) q += __shfl_xor(q, off);
    float rstd = rsqrtf(q * (1.0f / 512.0f) + EPSV);
    int c0 = lane * 8;
    float4 g0 = *(const float4*)&g[c0], g1 = *(const float4*)&g[c0 + 4];
    float4 b0 = *(const float4*)&bta[c0], b1 = *(const float4*)&bta[c0 + 4];
    u16* orow = o + (size_t)row * 512 + c0;
    *(ushort4*)orow = make_ushort4(to_bf(d[0] * rstd * g0.x + b0.x), to_bf(d[1] * rstd * g0.y + b0.y),
                                   to_bf(d[2] * rstd * g0.z + b0.z), to_bf(d[3] * rstd * g0.w + b0.w));
    *(ushort4*)(orow + 4) = make_ushort4(to_bf(d[4] * rstd * g1.x + b1.x), to_bf(d[5] * rstd * g1.y + b1.y),
                                         to_bf(d[6] * rstd * g1.z + b1.z), to_bf(d[7] * rstd * g1.w + b1.w));
}

// final LN, wave-per-row, output remap (fp32 out)
__global__ __launch_bounds__(256) void k_ln_out(const float* __restrict__ x,
                                                const float* __restrict__ g,
                                                const float* __restrict__ bta,
                                                float* __restrict__ out) {
    int row = blockIdx.x * 4 + (threadIdx.x >> 6);
    int lane = threadIdx.x & 63;
    const float4* xr = (const float4*)(x + (size_t)row * 512);
    float4 a = xr[lane * 2], b = xr[lane * 2 + 1];
    float s = a.x + a.y + a.z + a.w + b.x + b.y + b.z + b.w;
#pragma unroll
    for (int off = 1; off < 64; off <<= 1) s += __shfl_xor(s, off);
    float mean = s * (1.0f / 512.0f);
    float d[8] = {a.x - mean, a.y - mean, a.z - mean, a.w - mean,
                  b.x - mean, b.y - mean, b.z - mean, b.w - mean};
    float q = 0.0f;
#pragma unroll
    for (int i = 0; i < 8; i++) q += d[i] * d[i];
#pragma unroll
    for (int off = 1; off < 64; off <<= 1) q += __shfl_xor(q, off);
    float rstd = rsqrtf(q * (1.0f / 512.0f) + EPSV);
    int bb = row / 257, t = row % 257;
    float* dst = (t == 0) ? out + (size_t)bb * 512
                          : out + 16384 + (size_t)(bb * 256 + (t - 1)) * 512;
    int c0 = lane * 8;
    float4 g0 = *(const float4*)&g[c0], g1 = *(const float4*)&g[c0 + 4];
    float4 b0 = *(const float4*)&bta[c0], b1 = *(const float4*)&bta[c0 + 4];
    *(float4*)(dst + c0) = make_float4(d[0] * rstd * g0.x + b0.x, d[1] * rstd * g0.y + b0.y,
                                       d[2] * rstd * g0.z + b0.z, d[3] * rstd * g0.w + b0.w);
    *(float4*)(dst + c0 + 4) = make_float4(d[4] * rstd * g1.x + b1.x, d[5] * rstd * g1.y + b1.y,
                                           d[6] * rstd * g1.z + b1.z, d[7] * rstd * g1.w + b1.w);
}

// ---------------- rope in-place on bf16 qkv (q and k halves) ----------------
__global__ void k_ropeb(u16* __restrict__ qkv, const float* __restrict__ rt) {
    int idx = blockIdx.x * 256 + threadIdx.x;   // 8224*256 exact
    int row = idx >> 8, sub = idx & 255;
    int qk = sub >> 7;             // 0 = q, 1 = k
    int d0 = (sub & 127) * 4;      // 0..508, pairs (d0,d0+1),(d0+2,d0+3)
    u16* p = qkv + (size_t)row * 1536 + qk * 512 + d0;
    const float* rb = rt + d0 * 4;
    ushort4 a = *(ushort4*)p;
    float c0 = rb[0], s0 = rb[1];
    float c2 = rb[8], s2 = rb[9];
    float sc0 = rb[2 + qk], sc1 = rb[6 + qk], sc2 = rb[10 + qk], sc3 = rb[14 + qk];
    float f0 = to_f(a.x), f1 = to_f(a.y), f2 = to_f(a.z), f3 = to_f(a.w);
    ushort4 o;
    o.x = to_bf((f0 * c0 - f1 * s0) * sc0);
    o.y = to_bf((f1 * c0 + f0 * s0) * sc1);
    o.z = to_bf((f2 * c2 - f3 * s2) * sc2);
    o.w = to_bf((f3 * c2 + f2 * s2) * sc3);
    *(ushort4*)p = o;
}

// ---------------- MFMA attention: pre-roped qkv, direct-global Q/K fragments ----------------
__global__ __launch_bounds__(256) void k_attn_mfma(const u16* __restrict__ qkv,
                                                   u16* __restrict__ y) {
    __shared__ u16 KV[64][72];        // V^T tile
    __shared__ float sc[32][260];
    __shared__ u16 Pb[32][328];
    __shared__ float red1[32][8];
    __shared__ float red2[32][8];
    __shared__ float invr[32];

    int bid = blockIdx.x;                 // ((b*8+h)*9 + qt)
    int qt = bid % 9, bh = bid / 9;
    int h = bh & 7, b = bh >> 3;
    int q0 = qt * 32;
    int tid = threadIdx.x;
    int w = tid >> 6, lane = tid & 63;
    int l15 = lane & 15, l16 = lane >> 4;

    // Q fragments direct from global (pre-roped, pre-scaled)
    bf16x8 aq[2][2];
#pragma unroll
    for (int m = 0; m < 2; m++) {
        int grow = q0 + m * 16 + l15; if (grow > 256) grow = 256;
        const u16* qp = qkv + (size_t)(b * 257 + grow) * 1536 + h * 64 + l16 * 8;
        aq[m][0] = *(const bf16x8*)qp;
        aq[m][1] = *(const bf16x8*)(qp + 32);
    }

    // ---- pass 1: scores, K fragments direct from global ----
    for (int t = 0; t < 5; t++) {
        int j0 = t * 64;
        int gk = j0 + w * 16 + l15; if (gk > 256) gk = 256;
        const u16* kp = qkv + (size_t)(b * 257 + gk) * 1536 + 512 + h * 64 + l16 * 8;
        bf16x8 bk0 = *(const bf16x8*)kp;
        bf16x8 bk1 = *(const bf16x8*)(kp + 32);
        f32x4 a2[2];
        f32x4 zf = {0.f, 0.f, 0.f, 0.f};
#pragma unroll
        for (int m = 0; m < 2; m++) {
            a2[m] = zf;
            a2[m] = __builtin_amdgcn_mfma_f32_16x16x32_bf16(aq[m][0], bk0, a2[m], 0, 0, 0);
            a2[m] = __builtin_amdgcn_mfma_f32_16x16x32_bf16(aq[m][1], bk1, a2[m], 0, 0, 0);
        }
        int col = j0 + w * 16 + l15;
        if (col < 257) {
#pragma unroll
            for (int m = 0; m < 2; m++)
#pragma unroll
                for (int r = 0; r < 4; r++)
                    sc[m * 16 + l16 * 4 + r][col] = a2[m][r];
        }
    }
    __syncthreads();

    // ---- softmax: 8 threads per row ----
    {
        int r = tid >> 3, sub = tid & 7;
        float mx = -1e30f;
        for (int j = sub; j < 257; j += 8) mx = fmaxf(mx, sc[r][j]);
        red1[r][sub] = mx;
        __syncthreads();
        mx = red1[r][0];
#pragma unroll
        for (int i = 1; i < 8; i++) mx = fmaxf(mx, red1[r][i]);
        float sm = 0.0f;
        for (int j = sub; j < 257; j += 8) {
            float e = __expf(sc[r][j] - mx);
            Pb[r][j] = to_bf(e);
            sm += e;
        }
        for (int j = 257 + sub; j < 320; j += 8) Pb[r][j] = 0;
        red2[r][sub] = sm;
        __syncthreads();
        if (sub == 0) {
            float t = red2[r][0];
#pragma unroll
            for (int i = 1; i < 8; i++) t += red2[r][i];
            invr[r] = 1.0f / t;
        }
        __syncthreads();
    }

    // ---- pass 2: PV over 5 V-tiles (V transposed to [d][key]) ----
    f32x4 oacc[2];
    {
        f32x4 zf = {0.f, 0.f, 0.f, 0.f};
        oacc[0] = zf; oacc[1] = zf;
    }
    for (int t = 0; t < 5; t++) {
        int j0 = t * 64;
        {
            int vk = tid & 63, vd0 = (tid >> 6) * 16;
            int gk = j0 + vk;
            u16 o[16];
            if (gk <= 256) {
                const u16* vp = qkv + (size_t)(b * 257 + gk) * 1536 + 1024 + h * 64 + vd0;
                ushort4 a0 = *(const ushort4*)vp, a1 = *(const ushort4*)(vp + 4);
                ushort4 a2v = *(const ushort4*)(vp + 8), a3 = *(const ushort4*)(vp + 12);
                o[0] = a0.x; o[1] = a0.y; o[2] = a0.z; o[3] = a0.w;
                o[4] = a1.x; o[5] = a1.y; o[6] = a1.z; o[7] = a1.w;
                o[8] = a2v.x; o[9] = a2v.y; o[10] = a2v.z; o[11] = a2v.w;
                o[12] = a3.x; o[13] = a3.y; o[14] = a3.z; o[15] = a3.w;
            } else {
#pragma unroll
                for (int i = 0; i < 16; i++) o[i] = 0;
            }
#pragma unroll
            for (int i = 0; i < 16; i++) KV[vd0 + i][vk] = o[i];
        }
        __syncthreads();

        bf16x8 ap[2][2], bv[2];
#pragma unroll
        for (int m = 0; m < 2; m++)
#pragma unroll
            for (int kk = 0; kk < 2; kk++)
                ap[m][kk] = *(const bf16x8*)&Pb[m * 16 + l15][j0 + kk * 32 + l16 * 8];
#pragma unroll
        for (int kk = 0; kk < 2; kk++)
            bv[kk] = *(const bf16x8*)&KV[w * 16 + l15][kk * 32 + l16 * 8];
#pragma unroll
        for (int m = 0; m < 2; m++) {
            oacc[m] = __builtin_amdgcn_mfma_f32_16x16x32_bf16(ap[m][0], bv[0], oacc[m], 0, 0, 0);
            oacc[m] = __builtin_amdgcn_mfma_f32_16x16x32_bf16(ap[m][1], bv[1], oacc[m], 0, 0, 0);
        }
        __syncthreads();
    }

#pragma unroll
    for (int m = 0; m < 2; m++)
#pragma unroll
        for (int r = 0; r < 4; r++) {
            int lr = m * 16 + l16 * 4 + r;
            int grow = q0 + lr;
            if (grow < 257)
                y[(size_t)(b * 257 + grow) * 512 + h * 64 + w * 16 + l15] =
                    to_bf(oacc[m][r] * invr[lr]);
        }
}

// ---------------- SwiGLU on merged h12: hb = silu(h12[:, :2048]) * h12[:, 2048:] ----------------
__global__ void k_swiglu2(const u16* __restrict__ h12, u16* __restrict__ hb) {
    int idx = blockIdx.x * 256 + threadIdx.x;
    long e = (long)idx * 4;
    long row = e >> 11;
    int c = (int)(e & 2047);
    const u16* p1 = h12 + row * 4096 + c;
    ushort4 a = *(const ushort4*)p1;
    ushort4 b = *(const ushort4*)(p1 + 2048);
    ushort4 o;
    float x;
    x = to_f(a.x); o.x = to_bf(x / (1.0f + __expf(-x)) * to_f(b.x));
    x = to_f(a.y); o.y = to_bf(x / (1.0f + __expf(-x)) * to_f(b.y));
    x = to_f(a.z); o.z = to_bf(x / (1.0f + __expf(-x)) * to_f(b.z));
    x = to_f(a.w); o.w = to_bf(x / (1.0f + __expf(-x)) * to_f(b.w));
    *(ushort4*)&hb[row * 2048 + c] = o;
}

// ---------------- host launch ----------------
extern "C" void kernel_launch(void* const* d_in, const int* in_sizes, int n_in,
                              void* d_out, int out_size, void* d_ws, size_t ws_size,
                              hipStream_t stream) {
    const float* x       = (const float*)d_in[0];
    const float* conv1_w = (const float*)d_in[1];
    const float* conv1_b = (const float*)d_in[2];
    const float* gn1_g   = (const float*)d_in[3];
    const float* gn1_b   = (const float*)d_in[4];
    const float* conv2_w = (const float*)d_in[5];
    const float* conv2_b = (const float*)d_in[6];
    const float* gn2_g   = (const float*)d_in[7];
    const float* gn2_b   = (const float*)d_in[8];
    const float* patch_w = (const float*)d_in[9];
    const float* patch_b = (const float*)d_in[10];
    const float* cls_tok = (const float*)d_in[11];
    const float* ln1_g   = (const float*)d_in[12];
    const float* ln1_b   = (const float*)d_in[13];
    const float* qkv_w   = (const float*)d_in[14];
    const float* qkv_b   = (const float*)d_in[15];
    const float* out_w   = (const float*)d_in[16];
    const float* out_b   = (const float*)d_in[17];
    const float* ln2_g   = (const float*)d_in[18];
    const float* ln2_b   = (const float*)d_in[19];
    const float* w1_w    = (const float*)d_in[20];
    const float* w1_b    = (const float*)d_in[21];
    const float* w2_w    = (const float*)d_in[22];
    const float* w2_b    = (const float*)d_in[23];
    const float* w3_w    = (const float*)d_in[24];
    const float* w3_b    = (const float*)d_in[25];
    const float* fn_g    = (const float*)d_in[26];
    const float* fn_b    = (const float*)d_in[27];
    float* out = (float*)d_out;
    char* wsb  = (char*)d_ws;

    // arena (bytes), lifetime-aliased. Total 246,181,888 < 252,991,488 proven avail.
    const size_t O_R1    = 0;
    const size_t O_H12   = O_R1 + 0;          // 67,371,008
    const size_t O_HB    = O_R1 + 67371008;   // 33,685,504
    const size_t O_NB    = O_R1 + 101056512;  // 8,421,376
    const size_t O_Y     = O_R1 + 109477888;  // 8,421,376
    const size_t O_R2    = 134217728;         // f1n bf16 33.5MB | qkvb bf16 25.3MB
    const size_t O_XA    = 201326592;
    const size_t O_PWT   = 218169344;
    const size_t O_QKVT  = 222363648;
    const size_t O_OUTT  = 234946560;
    const size_t O_WL    = 239140864;         // w12Tl 4,194,304 + w3Tl 2,097,152
    const size_t O_PT    = 245432320;
    const size_t O_RT    = 245956608;
    const size_t O_CW1   = 245964800;
    const size_t O_CW2   = 245968896;
    const size_t O_ST    = 246042624;
    const size_t O_SA    = 246046720;
    const size_t O_B12   = 246050816;
    const size_t NEED    = 246181888;
    if (ws_size < NEED) {
        k_wsfail<<<1, 1, 0, stream>>>(out);
        return;
    }
    u16*   f2n    = (u16*)(wsb + O_R1);
    u16*   h12b   = (u16*)(wsb + O_H12);
    u16*   hb     = (u16*)(wsb + O_HB);
    u16*   nb     = (u16*)(wsb + O_NB);
    u16*   yb     = (u16*)(wsb + O_Y);
    u16*   f1n    = (u16*)(wsb + O_R2);
    u16*   qkvb   = (u16*)(wsb + O_R2);
    float* xa     = (float*)(wsb + O_XA);
    u16*   patchT = (u16*)(wsb + O_PWT);
    u16*   qkvT   = (u16*)(wsb + O_QKVT);
    u16*   outT   = (u16*)(wsb + O_OUTT);
    u16*   w12Tl  = (u16*)(wsb + O_WL);
    u16*   w3Tl   = (u16*)(wsb + O_WL + 4194304);
    float* postab = (float*)(wsb + O_PT);
    float* ropet  = (float*)(wsb + O_RT);
    float* w1t    = (float*)(wsb + O_CW1);
    u16*   wpack  = (u16*)(wsb + O_CW2);
    float* stat   = (float*)(wsb + O_ST);
    float* sacc   = (float*)(wsb + O_SA);
    float* bias12 = (float*)(wsb + O_B12);

    // setup
    k_zero<<<3, 256, 0, stream>>>(sacc, 768);
    k_wt<<<4, 256, 0, stream>>>(conv1_w, w1t, 32, 27);
    k_wpack<<<72, 256, 0, stream>>>(conv2_w, wpack);
    k_tables<<<512, 256, 0, stream>>>(postab, ropet);
    k_pperm<<<8192, 256, 0, stream>>>(patch_w, patchT);
    k_biascat<<<128, 256, 0, stream>>>(w1_b, w2_b, bias12);
    k_wcvtT<<<dim3(48, 16, 8), 256, 0, stream>>>(qkv_w, qkvT, 512, 1536);
    k_wcvtT<<<dim3(16, 16, 8), 256, 0, stream>>>(out_w, outT, 512, 512);

    // conv stem (NHWC bf16, fused GN stats)
    k_conv1<<<dim3(64, 32), 256, 0, stream>>>(x, w1t, conv1_b, f1n, sacc);
    k_gnfin<<<1, 256, 0, stream>>>(sacc, stat, 128);
    k_gnap<<<16384, 256, 0, stream>>>(f1n, stat, gn1_g, gn1_b, 31, 19, 4);
    k_conv2m<<<dim3(64, 32), 256, 0, stream>>>(f1n, wpack, conv2_b, f2n, sacc + 256);
    k_gnfin<<<1, 256, 0, stream>>>(sacc + 256, stat + 256, 256);
    k_gnap<<<32768, 256, 0, stream>>>(f2n, stat + 256, gn2_g, gn2_b, 63, 20, 8);

    // patch embed + cls
    k_bgemm<1, 3><<<dim3(4, 64), 256, 0, stream>>>(f2n, patchT, patch_b, xa, postab, 8192, 512, 4096);
    k_cls<<<64, 256, 0, stream>>>(cls_tok, xa);

    // transformer
    for (int l = 0; l < 8; l++) {
        k_wcvtT2<<<dim3(64, 16, 2), 256, 0, stream>>>(w1_w + (size_t)l * 1048576,
                                                      w2_w + (size_t)l * 1048576, w12Tl, 512, 2048);
        k_wcvtT<<<dim3(16, 64, 1), 256, 0, stream>>>(w3_w + (size_t)l * 1048576, w3Tl, 2048, 512);

        k_lnb<<<2056, 256, 0, stream>>>(xa, ln1_g + l * 512, ln1_b + l * 512, nb);
        k_bgemm<0, 4><<<dim3(12, 65), 256, 0, stream>>>(nb, qkvT + (size_t)l * 786432,
                                                        qkv_b + l * 1536, qkvb, nullptr, 8224, 1536, 512);
        k_ropeb<<<8224, 256, 0, stream>>>(qkvb, ropet);
        k_attn_mfma<<<2304, 256, 0, stream>>>(qkvb, yb);
        k_bgemm<0, 2><<<dim3(4, 65), 256, 0, stream>>>(yb, outT + (size_t)l * 262144,
                                                       out_b + l * 512, xa, nullptr, 8224, 512, 512);
        k_lnb<<<2056, 256, 0, stream>>>(xa, ln2_g + l * 512, ln2_b + l * 512, nb);
        k_bgemm<0, 4><<<dim3(32, 65), 256, 0, stream>>>(nb, w12Tl,
                                                        bias12 + l * 4096, h12b, nullptr, 8224, 4096, 512);
        k_swiglu2<<<16448, 256, 0, stream>>>(h12b, hb);
        k_bgemm<0, 2><<<dim3(4, 65), 256, 0, stream>>>(hb, w3Tl,
                                                       w3_b + l * 512, xa, nullptr, 8224, 512, 2048);
    }
    k_ln_out<<<2056, 256, 0, stream>>>(xa, fn_g, fn_b, out);
}

// Round 9
// 2596.329 us; speedup vs baseline: 6.8442x; 1.1632x over previous
//
#include <hip/hip_runtime.h>

#define EPSV 1e-5f
typedef unsigned short u16;
typedef short bf16x8 __attribute__((ext_vector_type(8)));
typedef float f32x4 __attribute__((ext_vector_type(4)));

__device__ __forceinline__ float gelu_exact(float x) {
    return 0.5f * x * (1.0f + erff(x * 0.7071067811865475f));
}
__device__ __forceinline__ u16 to_bf(float x) {
    union { float f; unsigned u; } c; c.f = x;
    unsigned r = c.u + 0x7fffu + ((c.u >> 16) & 1u);
    return (u16)(r >> 16);
}
__device__ __forceinline__ float to_f(u16 h) {
    union { unsigned u; float f; } c; c.u = ((unsigned)h) << 16;
    return c.f;
}
__device__ __forceinline__ void gload_lds16(const void* g, void* l) {
    __builtin_amdgcn_global_load_lds((const __attribute__((address_space(1))) unsigned int*)g,
                                     (__attribute__((address_space(3))) unsigned int*)l, 16, 0, 0);
}

// ---------------- tiny setup kernels ----------------
__global__ void k_wsfail(float* out) { out[0] = 1.0e9f; }

__global__ void k_zero(float* p, int n) {
    int i = blockIdx.x * 256 + threadIdx.x;
    if (i < n) p[i] = 0.0f;
}

__global__ void k_wt(const float* __restrict__ w, float* __restrict__ wt, int cout, int cin9) {
    int idx = blockIdx.x * 256 + threadIdx.x;
    if (idx < cout * cin9) {
        int co = idx / cin9, k = idx % cin9;
        wt[k * cout + co] = w[idx];
    }
}

// conv2 weights [64][32][3][3] -> bf16 [tap 9][cout 64][ci 32]
__global__ void k_wpack(const float* __restrict__ w, u16* __restrict__ wp) {
    int idx = blockIdx.x * 256 + threadIdx.x;
    if (idx < 18432) {
        int ci = idx & 31, tc = idx >> 5;
        int tap = tc >> 6, co = tc & 63;
        wp[idx] = to_bf(w[co * 288 + ci * 9 + tap]);
    }
}

// patch_w [512][64][8][8] ([cout][ci][ky][kx]) -> bf16 [cout][tap*64+ci] (tap=ky*8+kx)
__global__ void k_pperm(const float* __restrict__ w, u16* __restrict__ wp) {
    int idx = blockIdx.x * 256 + threadIdx.x;
    int cout = idx >> 12, rem = idx & 4095;
    int tap = rem >> 6, ci = rem & 63;
    wp[idx] = to_bf(w[cout * 4096 + ci * 64 + tap]);
}

// packed bias12: col pc: chunk=pc>>4 even->w1, odd->w2, srccol=(chunk>>1)*16+(pc&15)
__global__ void k_biascat(const float* __restrict__ b1, const float* __restrict__ b2,
                          float* __restrict__ o) {
    int idx = blockIdx.x * 256 + threadIdx.x;
    if (idx < 32768) {
        int l = idx >> 12, pc = idx & 4095;
        int chunk = pc >> 4, within = pc & 15;
        int srccol = (chunk >> 1) * 16 + within;
        o[idx] = (chunk & 1) ? b2[l * 2048 + srccol] : b1[l * 2048 + srccol];
    }
}

__global__ void k_tables(float* __restrict__ postab, float* __restrict__ ropetab) {
    int idx = blockIdx.x * 256 + threadIdx.x;
    if (idx < 256 * 512) {
        int p = idx >> 9, j = idx & 511;
        float coord = (j < 256) ? (float)(p >> 4) : (float)(p & 15);
        int jm = j & 127;
        float om = powf(10000.0f, -(float)jm / 128.0f);
        float arg = coord * om;
        postab[idx] = ((j >> 7) & 1) ? cosf(arg) : sinf(arg);
    }
    if (idx < 512) {
        // xpos tables indexed by HEAD h (reference quirk): n_pos = H = 8
        int h = idx >> 6, d = idx & 63;
        float freq = (float)h * powf(10000.0f, -(float)(d >> 1) / 32.0f);
        float sv = (2.0f * (float)(d & 31) + 25.6f) / 89.6f;
        float pw = ((float)h - 4.0f) / 512.0f;
        float sc = powf(sv, pw);
        ropetab[idx * 4 + 0] = cosf(freq);
        ropetab[idx * 4 + 1] = sinf(freq);
        ropetab[idx * 4 + 2] = sc * 0.125f;   // q scale, HD^-0.5 folded
        ropetab[idx * 4 + 3] = 1.0f / sc;     // k scale
    }
}

__global__ void k_cls(const float* __restrict__ cls, float* __restrict__ xa) {
    int idx = blockIdx.x * 256 + threadIdx.x;
    int b = idx >> 9, d = idx & 511;
    xa[(size_t)(b * 257) * 512 + d] = cls[d];
}

// fp32 [K][N] -> bf16 [N][K] transpose-convert
__global__ __launch_bounds__(256) void k_wcvtT(const float* __restrict__ src,
                                               u16* __restrict__ dst, int K, int N) {
    __shared__ float s[32][33];
    int z = blockIdx.z;
    src += (size_t)z * K * N;
    dst += (size_t)z * K * N;
    int k0 = blockIdx.y * 32, n0 = blockIdx.x * 32;
    int t = threadIdx.x, r = t >> 3, c4 = (t & 7) * 4;
    float4 v = *(const float4*)&src[(size_t)(k0 + r) * N + n0 + c4];
    s[r][c4 + 0] = v.x; s[r][c4 + 1] = v.y; s[r][c4 + 2] = v.z; s[r][c4 + 3] = v.w;
    __syncthreads();
    ushort4 o;
    o.x = to_bf(s[c4 + 0][r]); o.y = to_bf(s[c4 + 1][r]);
    o.z = to_bf(s[c4 + 2][r]); o.w = to_bf(s[c4 + 3][r]);
    *(ushort4*)&dst[(size_t)(n0 + r) * K + k0 + c4] = o;
}

// dual-source transpose-convert with 16-col interleaved packing:
// dest col for src col nsrc of source z: ((nsrc>>4)<<5) + (z<<4) + (nsrc&15)
__global__ __launch_bounds__(256) void k_wcvtT12(const float* __restrict__ s1,
                                                 const float* __restrict__ s2,
                                                 u16* __restrict__ dst, int K, int N) {
    __shared__ float s[32][33];
    int z = blockIdx.z;
    const float* src = z ? s2 : s1;
    int k0 = blockIdx.y * 32, n0 = blockIdx.x * 32;
    int t = threadIdx.x, r = t >> 3, c4 = (t & 7) * 4;
    float4 v = *(const float4*)&src[(size_t)(k0 + r) * N + n0 + c4];
    s[r][c4 + 0] = v.x; s[r][c4 + 1] = v.y; s[r][c4 + 2] = v.z; s[r][c4 + 3] = v.w;
    __syncthreads();
    ushort4 o;
    o.x = to_bf(s[c4 + 0][r]); o.y = to_bf(s[c4 + 1][r]);
    o.z = to_bf(s[c4 + 2][r]); o.w = to_bf(s[c4 + 3][r]);
    int nsrc = n0 + r;
    int p = ((nsrc >> 4) << 5) + (z << 4) + (nsrc & 15);
    *(ushort4*)&dst[(size_t)p * K + k0 + c4] = o;
}

// ---------------- conv1: fp32 direct, bf16 NHWC out + GN partial sums ----------------
__global__ __launch_bounds__(256) void k_conv1(const float* __restrict__ in,
                                               const float* __restrict__ wt,   // [27][32]
                                               const float* __restrict__ bias,
                                               u16* __restrict__ f1n,
                                               float* __restrict__ sacc) {
    __shared__ float s_in[3][18][18];
    __shared__ float rs[4][4], rq[4][4];
    int b = blockIdx.y;
    int tile = blockIdx.x;
    int y0 = (tile >> 3) << 4;
    int x0 = (tile & 7) << 4;
    int tid = threadIdx.x;
    for (int idx = tid; idx < 972; idx += 256) {
        int ci = idx / 324, r = idx % 324;
        int ly = r / 18, lx = r % 18;
        int gy = y0 + ly - 1, gx = x0 + lx - 1;
        float v = 0.0f;
        if (gy >= 0 && gy < 128 && gx >= 0 && gx < 128)
            v = in[((size_t)(b * 3 + ci) * 128 + gy) * 128 + gx];
        s_in[ci][ly][lx] = v;
    }
    __syncthreads();
    int py = tid >> 4, px = tid & 15;
    float acc[32];
#pragma unroll
    for (int co = 0; co < 32; co++) acc[co] = bias[co];
#pragma unroll
    for (int ci = 0; ci < 3; ci++)
#pragma unroll
        for (int dy = 0; dy < 3; dy++)
#pragma unroll
            for (int dx = 0; dx < 3; dx++) {
                float v = s_in[ci][py + dy][px + dx];
                const float* wr = &wt[(ci * 9 + dy * 3 + dx) * 32];
#pragma unroll
                for (int co = 0; co < 32; co++)
                    acc[co] = fmaf(wr[co], v, acc[co]);
            }
    float s[4] = {0.f, 0.f, 0.f, 0.f}, q[4] = {0.f, 0.f, 0.f, 0.f};
    u16 ob[32];
#pragma unroll
    for (int co = 0; co < 32; co++) {
        u16 hv = to_bf(acc[co]);
        ob[co] = hv;
        float v = to_f(hv);
        s[co >> 3] += v;
        q[co >> 3] += v * v;
    }
    int oy = y0 + py, ox = x0 + px;
    u16* dst = f1n + ((size_t)(b * 16384 + oy * 128 + ox) << 5);
#pragma unroll
    for (int i = 0; i < 8; i++)
        *(ushort4*)(dst + i * 4) = make_ushort4(ob[i * 4], ob[i * 4 + 1], ob[i * 4 + 2], ob[i * 4 + 3]);
#pragma unroll
    for (int g = 0; g < 4; g++) {
#pragma unroll
        for (int off = 1; off < 64; off <<= 1) {
            s[g] += __shfl_xor(s[g], off);
            q[g] += __shfl_xor(q[g], off);
        }
    }
    int w = tid >> 6, lane = tid & 63;
    if (lane == 0)
#pragma unroll
        for (int g = 0; g < 4; g++) { rs[g][w] = s[g]; rq[g][w] = q[g]; }
    __syncthreads();
    if (tid < 4) {
        int g = tid;
        float S = rs[g][0] + rs[g][1] + rs[g][2] + rs[g][3];
        float Q = rq[g][0] + rq[g][1] + rq[g][2] + rq[g][3];
        atomicAdd(&sacc[(b * 4 + g) * 2], S);
        atomicAdd(&sacc[(b * 4 + g) * 2 + 1], Q);
    }
}

// finalize GN stats
__global__ void k_gnfin(const float* __restrict__ sacc, float* __restrict__ st, int entries) {
    int i = blockIdx.x * 256 + threadIdx.x;
    if (i < entries) {
        float m = sacc[2 * i] * (1.0f / 131072.0f);
        float var = sacc[2 * i + 1] * (1.0f / 131072.0f) - m * m;
        st[2 * i] = m;
        st[2 * i + 1] = rsqrtf(var + 1e-5f);
    }
}

// GN apply + GELU, bf16 NHWC in-place
__global__ void k_gnap(u16* __restrict__ xio, const float* __restrict__ st,
                       const float* __restrict__ gg, const float* __restrict__ bb,
                       int cm, int sh, int gmul) {
    int idx = blockIdx.x * 256 + threadIdx.x;
    long e = (long)idx * 4;
    int c0 = (int)(e & cm);
    int b = (int)(e >> sh);
    int sid = b * gmul + (c0 >> 3);
    float m = st[2 * sid], r = st[2 * sid + 1];
    ushort4 a = *(ushort4*)&xio[e];
    ushort4 o;
    o.x = to_bf(gelu_exact((to_f(a.x) - m) * r * gg[c0 + 0] + bb[c0 + 0]));
    o.y = to_bf(gelu_exact((to_f(a.y) - m) * r * gg[c0 + 1] + bb[c0 + 1]));
    o.z = to_bf(gelu_exact((to_f(a.z) - m) * r * gg[c0 + 2] + bb[c0 + 2]));
    o.w = to_bf(gelu_exact((to_f(a.w) - m) * r * gg[c0 + 3] + bb[c0 + 3]));
    *(ushort4*)&xio[e] = o;
}

// ---------------- conv2 as MFMA implicit GEMM, zero-LDS ----------------
__global__ __launch_bounds__(256) void k_conv2m(const u16* __restrict__ f1b,
                                                const u16* __restrict__ wp,   // [9][64][32]
                                                const float* __restrict__ bias,
                                                u16* __restrict__ f2n,
                                                float* __restrict__ sacc) {
    int b = blockIdx.y;
    int tile = blockIdx.x;
    int y0 = (tile >> 3) << 4;
    int x0 = (tile & 7) << 4;
    int tid = threadIdx.x;
    int w = tid >> 6, lane = tid & 63;
    int l15 = lane & 15, l16 = lane >> 4;

    const u16* base = f1b + ((size_t)b << 19);

    f32x4 acc[4][4];
    f32x4 zf = {0.f, 0.f, 0.f, 0.f};
#pragma unroll
    for (int m = 0; m < 4; m++)
#pragma unroll
        for (int n = 0; n < 4; n++) acc[m][n] = zf;
    bf16x8 zb = {0, 0, 0, 0, 0, 0, 0, 0};

#pragma unroll
    for (int tap = 0; tap < 9; tap++) {
        int dy = tap / 3, dx = tap % 3;
        int gx = x0 + l15 + dx - 1;
        bf16x8 af[4], bk[4];
#pragma unroll
        for (int m = 0; m < 4; m++) {
            int gy = y0 + w * 4 + m + dy - 1;
            bool ok = (gy >= 0) && (gy < 128) && (gx >= 0) && (gx < 128);
            int pix = ok ? (gy * 128 + gx) : 0;
            bf16x8 v = *(const bf16x8*)(base + ((size_t)pix << 5) + l16 * 8);
            af[m] = ok ? v : zb;
        }
#pragma unroll
        for (int n = 0; n < 4; n++)
            bk[n] = *(const bf16x8*)&wp[(tap * 64 + n * 16 + l15) * 32 + l16 * 8];
#pragma unroll
        for (int m = 0; m < 4; m++)
#pragma unroll
            for (int n = 0; n < 4; n++)
                acc[m][n] = __builtin_amdgcn_mfma_f32_16x16x32_bf16(af[m], bk[n], acc[m][n], 0, 0, 0);
    }

#pragma unroll
    for (int n = 0; n < 4; n++) {
        int gco = n * 16 + l15;
        float bv = bias[gco];
        float sn = 0.0f, qn = 0.0f;
#pragma unroll
        for (int m = 0; m < 4; m++) {
            int py = w * 4 + m;
#pragma unroll
            for (int r = 0; r < 4; r++) {
                int px = l16 * 4 + r;
                float v = acc[m][n][r] + bv;
                u16 hv = to_bf(v);
                f2n[((size_t)(b * 16384 + (y0 + py) * 128 + x0 + px) << 6) + gco] = hv;
                float vf = to_f(hv);
                sn += vf;
                qn += vf * vf;
            }
        }
#pragma unroll
        for (int off = 1; off <= 4; off <<= 1) { sn += __shfl_xor(sn, off); qn += __shfl_xor(qn, off); }
        sn += __shfl_xor(sn, 16); qn += __shfl_xor(qn, 16);
        sn += __shfl_xor(sn, 32); qn += __shfl_xor(qn, 32);
        if (lane == 0 || lane == 8) {
            int g = n * 2 + (lane >> 3);
            atomicAdd(&sacc[(b * 8 + g) * 2], sn);
            atomicAdd(&sacc[(b * 8 + g) * 2 + 1], qn);
        }
    }
}

// ---------------- bf16 MFMA GEMM ----------------
// MODE 0: A [M,K] row-major. MODE 1: implicit im2col of f2n NHWC (k = tap*64+ci).
// EPI 1: fp32 C = acc+bias. EPI 2: fp32 C += acc+bias. EPI 3: patch scatter + postab.
// EPI 6: interleaved w12 -> bf16 hb = silu(h1)*h2, out stride N/2.
// EPI 7: bf16 C = rope(acc+bias) for cols<1024 (aux = rope table), else acc+bias.
template <int MODE, int EPI>
__global__ __launch_bounds__(256) void k_bgemm(const u16* __restrict__ A,
                                               const u16* __restrict__ Bt,
                                               const float* __restrict__ bias,
                                               void* __restrict__ Cp,
                                               const float* __restrict__ aux,
                                               int M, int N, int K) {
    __shared__ u16 ldsA[8192];   // [kg 8][row 128][8]
    __shared__ u16 ldsB[8192];   // [col 128][kg^swz 8][8]
    int tid = threadIdx.x;
    int w = tid >> 6, lane = tid & 63;
    int bm = blockIdx.y * 128, bn = blockIdx.x * 128;
    int wr = w >> 1, wc = w & 1;
    int l15 = lane & 15, l16 = lane >> 4;

    f32x4 acc[4][4];
    f32x4 zf = {0.f, 0.f, 0.f, 0.f};
#pragma unroll
    for (int m = 0; m < 4; m++)
#pragma unroll
        for (int n = 0; n < 4; n++) acc[m][n] = zf;

    for (int k0 = 0; k0 < K; k0 += 64) {
#pragma unroll
        for (int i = 0; i < 4; i++) {
            int chunk = (w * 4 + i) * 64 + lane;
            int kg = chunk >> 7, row = chunk & 127;
            const u16* src;
            if (MODE == 0) {
                int grow = bm + row;
                if (grow > M - 1) grow = M - 1;
                src = A + (size_t)grow * K + k0 + kg * 8;
            } else {
                int grow = bm + row;
                int bimg = grow >> 8, p = grow & 255;
                int kga = (k0 >> 3) + kg;
                int tap = kga >> 3, cq = kga & 7;
                int ky = tap >> 3, kx = tap & 7;
                int gy = ((p >> 4) << 3) + ky, gx = ((p & 15) << 3) + kx;
                src = A + (((size_t)(bimg * 16384 + gy * 128 + gx)) << 6) + cq * 8;
            }
            gload_lds16(src, &ldsA[(w * 4 + i) * 512]);
        }
#pragma unroll
        for (int i = 0; i < 4; i++) {
            int chunk = (w * 4 + i) * 64 + lane;
            int col = chunk >> 3, kgs = chunk & 7;
            int kg_src = kgs ^ (col & 7);
            const u16* src = Bt + (size_t)(bn + col) * K + k0 + kg_src * 8;
            gload_lds16(src, &ldsB[(w * 4 + i) * 512]);
        }
        __syncthreads();

        bf16x8 af[4][2], bfr[4][2];
#pragma unroll
        for (int kk = 0; kk < 2; kk++) {
            int kga = kk * 4 + l16;
#pragma unroll
            for (int m = 0; m < 4; m++) {
                int row_l = wr * 64 + m * 16 + l15;
                af[m][kk] = *(const bf16x8*)&ldsA[(kga * 128 + row_l) * 8];
            }
#pragma unroll
            for (int n = 0; n < 4; n++) {
                int col_l = wc * 64 + n * 16 + l15;
                bfr[n][kk] = *(const bf16x8*)&ldsB[(col_l * 8 + (kga ^ (col_l & 7))) * 8];
            }
        }
#pragma unroll
        for (int m = 0; m < 4; m++)
#pragma unroll
            for (int n = 0; n < 4; n++) {
                acc[m][n] = __builtin_amdgcn_mfma_f32_16x16x32_bf16(af[m][0], bfr[n][0], acc[m][n], 0, 0, 0);
                acc[m][n] = __builtin_amdgcn_mfma_f32_16x16x32_bf16(af[m][1], bfr[n][1], acc[m][n], 0, 0, 0);
            }
        __syncthreads();
    }

    if (EPI == 6) {
        // pairs (n, n+1) share the same output column chunk
#pragma unroll
        for (int np = 0; np < 2; np++) {
            int n_a = np * 2, n_b = np * 2 + 1;
            float bva = bias[bn + wc * 64 + n_a * 16 + l15];
            float bvb = bias[bn + wc * 64 + n_b * 16 + l15];
            int ocol = (bn >> 1) + wc * 32 + np * 16 + l15;
#pragma unroll
            for (int m = 0; m < 4; m++) {
#pragma unroll
                for (int r = 0; r < 4; r++) {
                    int grow = bm + wr * 64 + m * 16 + l16 * 4 + r;
                    if (grow < M) {
                        float h1v = to_f(to_bf(acc[m][n_a][r] + bva));
                        float h2v = to_f(to_bf(acc[m][n_b][r] + bvb));
                        float sl = h1v / (1.0f + __expf(-h1v));
                        ((u16*)Cp)[(size_t)grow * (N >> 1) + ocol] = to_bf(sl * h2v);
                    }
                }
            }
        }
    } else {
#pragma unroll
        for (int n = 0; n < 4; n++) {
            int gcol = bn + wc * 64 + n * 16 + l15;
            float bv = bias[gcol];
            float rc = 0.f, rsn = 0.f, rsc = 1.f;
            bool isqk = false, odd = false;
            if (EPI == 7) {
                isqk = gcol < 1024;
                odd = (l15 & 1) != 0;
                const float* rb = &aux[(gcol & 511) * 4];
                if (isqk) {
                    rc = rb[0]; rsn = rb[1];
                    rsc = (gcol < 512) ? rb[2] : rb[3];
                }
            }
#pragma unroll
            for (int m = 0; m < 4; m++) {
#pragma unroll
                for (int r = 0; r < 4; r++) {
                    int grow = bm + wr * 64 + m * 16 + l16 * 4 + r;
                    float v = acc[m][n][r] + bv;
                    if (EPI == 7) {
                        float p = __shfl_xor(v, 1);
                        float vr = isqk ? ((odd ? (v * rc + p * rsn) : (v * rc - p * rsn)) * rsc) : v;
                        if (grow < M) ((u16*)Cp)[(size_t)grow * N + gcol] = to_bf(vr);
                    } else if (EPI == 1) {
                        if (grow < M) ((float*)Cp)[(size_t)grow * N + gcol] = v;
                    } else if (EPI == 2) {
                        if (grow < M) ((float*)Cp)[(size_t)grow * N + gcol] += v;
                    } else {
                        int bimg = grow >> 8, p2 = grow & 255;
                        v += aux[p2 * 512 + gcol];
                        ((float*)Cp)[((size_t)(bimg * 257) + 1 + p2) * 512 + gcol] = v;
                    }
                }
            }
        }
    }
}

// ---------------- LayerNorm, wave-per-row (4 rows/block), bf16 out ----------------
__global__ __launch_bounds__(256) void k_lnb(const float* __restrict__ x,
                                             const float* __restrict__ g,
                                             const float* __restrict__ bta,
                                             u16* __restrict__ o) {
    int row = blockIdx.x * 4 + (threadIdx.x >> 6);
    int lane = threadIdx.x & 63;
    const float4* xr = (const float4*)(x + (size_t)row * 512);
    float4 a = xr[lane * 2], b = xr[lane * 2 + 1];
    float s = a.x + a.y + a.z + a.w + b.x + b.y + b.z + b.w;
#pragma unroll
    for (int off = 1; off < 64; off <<= 1) s += __shfl_xor(s, off);
    float mean = s * (1.0f / 512.0f);
    float d[8] = {a.x - mean, a.y - mean, a.z - mean, a.w - mean,
                  b.x - mean, b.y - mean, b.z - mean, b.w - mean};
    float q = 0.0f;
#pragma unroll
    for (int i = 0; i < 8; i++) q += d[i] * d[i];
#pragma unroll
    for (int off = 1; off < 64; off <<= 1) q += __shfl_xor(q, off);
    float rstd = rsqrtf(q * (1.0f / 512.0f) + EPSV);
    int c0 = lane * 8;
    float4 g0 = *(const float4*)&g[c0], g1 = *(const float4*)&g[c0 + 4];
    float4 b0 = *(const float4*)&bta[c0], b1 = *(const float4*)&bta[c0 + 4];
    u16* orow = o + (size_t)row * 512 + c0;
    *(ushort4*)orow = make_ushort4(to_bf(d[0] * rstd * g0.x + b0.x), to_bf(d[1] * rstd * g0.y + b0.y),
                                   to_bf(d[2] * rstd * g0.z + b0.z), to_bf(d[3] * rstd * g0.w + b0.w));
    *(ushort4*)(orow + 4) = make_ushort4(to_bf(d[4] * rstd * g1.x + b1.x), to_bf(d[5] * rstd * g1.y + b1.y),
                                         to_bf(d[6] * rstd * g1.z + b1.z), to_bf(d[7] * rstd * g1.w + b1.w));
}

// final LN, wave-per-row, output remap (fp32 out)
__global__ __launch_bounds__(256) void k_ln_out(const float* __restrict__ x,
                                                const float* __restrict__ g,
                                                const float* __restrict__ bta,
                                                float* __restrict__ out) {
    int row = blockIdx.x * 4 + (threadIdx.x >> 6);
    int lane = threadIdx.x & 63;
    const float4* xr = (const float4*)(x + (size_t)row * 512);
    float4 a = xr[lane * 2], b = xr[lane * 2 + 1];
    float s = a.x + a.y + a.z + a.w + b.x + b.y + b.z + b.w;
#pragma unroll
    for (int off = 1; off < 64; off <<= 1) s += __shfl_xor(s, off);
    float mean = s * (1.0f / 512.0f);
    float d[8] = {a.x - mean, a.y - mean, a.z - mean, a.w - mean,
                  b.x - mean, b.y - mean, b.z - mean, b.w - mean};
    float q = 0.0f;
#pragma unroll
    for (int i = 0; i < 8; i++) q += d[i] * d[i];
#pragma unroll
    for (int off = 1; off < 64; off <<= 1) q += __shfl_xor(q, off);
    float rstd = rsqrtf(q * (1.0f / 512.0f) + EPSV);
    int bb = row / 257, t = row % 257;
    float* dst = (t == 0) ? out + (size_t)bb * 512
                          : out + 16384 + (size_t)(bb * 256 + (t - 1)) * 512;
    int c0 = lane * 8;
    float4 g0 = *(const float4*)&g[c0], g1 = *(const float4*)&g[c0 + 4];
    float4 b0 = *(const float4*)&bta[c0], b1 = *(const float4*)&bta[c0 + 4];
    *(float4*)(dst + c0) = make_float4(d[0] * rstd * g0.x + b0.x, d[1] * rstd * g0.y + b0.y,
                                       d[2] * rstd * g0.z + b0.z, d[3] * rstd * g0.w + b0.w);
    *(float4*)(dst + c0 + 4) = make_float4(d[4] * rstd * g1.x + b1.x, d[5] * rstd * g1.y + b1.y,
                                           d[6] * rstd * g1.z + b1.z, d[7] * rstd * g1.w + b1.w);
}

// ---------------- MFMA attention: pre-roped qkv, direct-global Q/K fragments ----------------
__global__ __launch_bounds__(256) void k_attn_mfma(const u16* __restrict__ qkv,
                                                   u16* __restrict__ y) {
    __shared__ u16 KV[64][72];        // V^T tile
    __shared__ float sc[32][260];
    __shared__ u16 Pb[32][328];
    __shared__ float red1[32][8];
    __shared__ float red2[32][8];
    __shared__ float invr[32];

    int bid = blockIdx.x;                 // ((b*8+h)*9 + qt)
    int qt = bid % 9, bh = bid / 9;
    int h = bh & 7, b = bh >> 3;
    int q0 = qt * 32;
    int tid = threadIdx.x;
    int w = tid >> 6, lane = tid & 63;
    int l15 = lane & 15, l16 = lane >> 4;

    bf16x8 aq[2][2];
#pragma unroll
    for (int m = 0; m < 2; m++) {
        int grow = q0 + m * 16 + l15; if (grow > 256) grow = 256;
        const u16* qp = qkv + (size_t)(b * 257 + grow) * 1536 + h * 64 + l16 * 8;
        aq[m][0] = *(const bf16x8*)qp;
        aq[m][1] = *(const bf16x8*)(qp + 32);
    }

    for (int t = 0; t < 5; t++) {
        int j0 = t * 64;
        int gk = j0 + w * 16 + l15; if (gk > 256) gk = 256;
        const u16* kp = qkv + (size_t)(b * 257 + gk) * 1536 + 512 + h * 64 + l16 * 8;
        bf16x8 bk0 = *(const bf16x8*)kp;
        bf16x8 bk1 = *(const bf16x8*)(kp + 32);
        f32x4 a2[2];
        f32x4 zf = {0.f, 0.f, 0.f, 0.f};
#pragma unroll
        for (int m = 0; m < 2; m++) {
            a2[m] = zf;
            a2[m] = __builtin_amdgcn_mfma_f32_16x16x32_bf16(aq[m][0], bk0, a2[m], 0, 0, 0);
            a2[m] = __builtin_amdgcn_mfma_f32_16x16x32_bf16(aq[m][1], bk1, a2[m], 0, 0, 0);
        }
        int col = j0 + w * 16 + l15;
        if (col < 257) {
#pragma unroll
            for (int m = 0; m < 2; m++)
#pragma unroll
                for (int r = 0; r < 4; r++)
                    sc[m * 16 + l16 * 4 + r][col] = a2[m][r];
        }
    }
    __syncthreads();

    {
        int r = tid >> 3, sub = tid & 7;
        float mx = -1e30f;
        for (int j = sub; j < 257; j += 8) mx = fmaxf(mx, sc[r][j]);
        red1[r][sub] = mx;
        __syncthreads();
        mx = red1[r][0];
#pragma unroll
        for (int i = 1; i < 8; i++) mx = fmaxf(mx, red1[r][i]);
        float sm = 0.0f;
        for (int j = sub; j < 257; j += 8) {
            float e = __expf(sc[r][j] - mx);
            Pb[r][j] = to_bf(e);
            sm += e;
        }
        for (int j = 257 + sub; j < 320; j += 8) Pb[r][j] = 0;
        red2[r][sub] = sm;
        __syncthreads();
        if (sub == 0) {
            float t = red2[r][0];
#pragma unroll
            for (int i = 1; i < 8; i++) t += red2[r][i];
            invr[r] = 1.0f / t;
        }
        __syncthreads();
    }

    f32x4 oacc[2];
    {
        f32x4 zf = {0.f, 0.f, 0.f, 0.f};
        oacc[0] = zf; oacc[1] = zf;
    }
    for (int t = 0; t < 5; t++) {
        int j0 = t * 64;
        {
            int vk = tid & 63, vd0 = (tid >> 6) * 16;
            int gk = j0 + vk;
            u16 o[16];
            if (gk <= 256) {
                const u16* vp = qkv + (size_t)(b * 257 + gk) * 1536 + 1024 + h * 64 + vd0;
                ushort4 a0 = *(const ushort4*)vp, a1 = *(const ushort4*)(vp + 4);
                ushort4 a2v = *(const ushort4*)(vp + 8), a3 = *(const ushort4*)(vp + 12);
                o[0] = a0.x; o[1] = a0.y; o[2] = a0.z; o[3] = a0.w;
                o[4] = a1.x; o[5] = a1.y; o[6] = a1.z; o[7] = a1.w;
                o[8] = a2v.x; o[9] = a2v.y; o[10] = a2v.z; o[11] = a2v.w;
                o[12] = a3.x; o[13] = a3.y; o[14] = a3.z; o[15] = a3.w;
            } else {
#pragma unroll
                for (int i = 0; i < 16; i++) o[i] = 0;
            }
#pragma unroll
            for (int i = 0; i < 16; i++) KV[vd0 + i][vk] = o[i];
        }
        __syncthreads();

        bf16x8 ap[2][2], bv[2];
#pragma unroll
        for (int m = 0; m < 2; m++)
#pragma unroll
            for (int kk = 0; kk < 2; kk++)
                ap[m][kk] = *(const bf16x8*)&Pb[m * 16 + l15][j0 + kk * 32 + l16 * 8];
#pragma unroll
        for (int kk = 0; kk < 2; kk++)
            bv[kk] = *(const bf16x8*)&KV[w * 16 + l15][kk * 32 + l16 * 8];
#pragma unroll
        for (int m = 0; m < 2; m++) {
            oacc[m] = __builtin_amdgcn_mfma_f32_16x16x32_bf16(ap[m][0], bv[0], oacc[m], 0, 0, 0);
            oacc[m] = __builtin_amdgcn_mfma_f32_16x16x32_bf16(ap[m][1], bv[1], oacc[m], 0, 0, 0);
        }
        __syncthreads();
    }

#pragma unroll
    for (int m = 0; m < 2; m++)
#pragma unroll
        for (int r = 0; r < 4; r++) {
            int lr = m * 16 + l16 * 4 + r;
            int grow = q0 + lr;
            if (grow < 257)
                y[(size_t)(b * 257 + grow) * 512 + h * 64 + w * 16 + l15] =
                    to_bf(oacc[m][r] * invr[lr]);
        }
}

// ---------------- host launch ----------------
extern "C" void kernel_launch(void* const* d_in, const int* in_sizes, int n_in,
                              void* d_out, int out_size, void* d_ws, size_t ws_size,
                              hipStream_t stream) {
    const float* x       = (const float*)d_in[0];
    const float* conv1_w = (const float*)d_in[1];
    const float* conv1_b = (const float*)d_in[2];
    const float* gn1_g   = (const float*)d_in[3];
    const float* gn1_b   = (const float*)d_in[4];
    const float* conv2_w = (const float*)d_in[5];
    const float* conv2_b = (const float*)d_in[6];
    const float* gn2_g   = (const float*)d_in[7];
    const float* gn2_b   = (const float*)d_in[8];
    const float* patch_w = (const float*)d_in[9];
    const float* patch_b = (const float*)d_in[10];
    const float* cls_tok = (const float*)d_in[11];
    const float* ln1_g   = (const float*)d_in[12];
    const float* ln1_b   = (const float*)d_in[13];
    const float* qkv_w   = (const float*)d_in[14];
    const float* qkv_b   = (const float*)d_in[15];
    const float* out_w   = (const float*)d_in[16];
    const float* out_b   = (const float*)d_in[17];
    const float* ln2_g   = (const float*)d_in[18];
    const float* ln2_b   = (const float*)d_in[19];
    const float* w1_w    = (const float*)d_in[20];
    const float* w1_b    = (const float*)d_in[21];
    const float* w2_w    = (const float*)d_in[22];
    const float* w2_b    = (const float*)d_in[23];
    const float* w3_w    = (const float*)d_in[24];
    const float* w3_b    = (const float*)d_in[25];
    const float* fn_g    = (const float*)d_in[26];
    const float* fn_b    = (const float*)d_in[27];
    float* out = (float*)d_out;
    char* wsb  = (char*)d_ws;

    const size_t O_R1    = 0;
    const size_t O_HB    = O_R1 + 67371008;   // 33,685,504
    const size_t O_NB    = O_R1 + 101056512;  // 8,421,376
    const size_t O_Y     = O_R1 + 109477888;  // 8,421,376
    const size_t O_R2    = 134217728;         // f1n bf16 | qkvb bf16
    const size_t O_XA    = 201326592;
    const size_t O_PWT   = 218169344;
    const size_t O_QKVT  = 222363648;
    const size_t O_OUTT  = 234946560;
    const size_t O_WL    = 239140864;         // w12Tl 4,194,304 + w3Tl 2,097,152
    const size_t O_PT    = 245432320;
    const size_t O_RT    = 245956608;
    const size_t O_CW1   = 245964800;
    const size_t O_CW2   = 245968896;
    const size_t O_ST    = 246042624;
    const size_t O_SA    = 246046720;
    const size_t O_B12   = 246050816;
    const size_t NEED    = 246181888;
    if (ws_size < NEED) {
        k_wsfail<<<1, 1, 0, stream>>>(out);
        return;
    }
    u16*   f2n    = (u16*)(wsb + O_R1);
    u16*   hb     = (u16*)(wsb + O_HB);
    u16*   nb     = (u16*)(wsb + O_NB);
    u16*   yb     = (u16*)(wsb + O_Y);
    u16*   f1n    = (u16*)(wsb + O_R2);
    u16*   qkvb   = (u16*)(wsb + O_R2);
    float* xa     = (float*)(wsb + O_XA);
    u16*   patchT = (u16*)(wsb + O_PWT);
    u16*   qkvT   = (u16*)(wsb + O_QKVT);
    u16*   outT   = (u16*)(wsb + O_OUTT);
    u16*   w12Tl  = (u16*)(wsb + O_WL);
    u16*   w3Tl   = (u16*)(wsb + O_WL + 4194304);
    float* postab = (float*)(wsb + O_PT);
    float* ropet  = (float*)(wsb + O_RT);
    float* w1t    = (float*)(wsb + O_CW1);
    u16*   wpack  = (u16*)(wsb + O_CW2);
    float* stat   = (float*)(wsb + O_ST);
    float* sacc   = (float*)(wsb + O_SA);
    float* bias12 = (float*)(wsb + O_B12);

    // setup
    k_zero<<<3, 256, 0, stream>>>(sacc, 768);
    k_wt<<<4, 256, 0, stream>>>(conv1_w, w1t, 32, 27);
    k_wpack<<<72, 256, 0, stream>>>(conv2_w, wpack);
    k_tables<<<512, 256, 0, stream>>>(postab, ropet);
    k_pperm<<<8192, 256, 0, stream>>>(patch_w, patchT);
    k_biascat<<<128, 256, 0, stream>>>(w1_b, w2_b, bias12);
    k_wcvtT<<<dim3(48, 16, 8), 256, 0, stream>>>(qkv_w, qkvT, 512, 1536);
    k_wcvtT<<<dim3(16, 16, 8), 256, 0, stream>>>(out_w, outT, 512, 512);

    // conv stem (NHWC bf16, fused GN stats)
    k_conv1<<<dim3(64, 32), 256, 0, stream>>>(x, w1t, conv1_b, f1n, sacc);
    k_gnfin<<<1, 256, 0, stream>>>(sacc, stat, 128);
    k_gnap<<<16384, 256, 0, stream>>>(f1n, stat, gn1_g, gn1_b, 31, 19, 4);
    k_conv2m<<<dim3(64, 32), 256, 0, stream>>>(f1n, wpack, conv2_b, f2n, sacc + 256);
    k_gnfin<<<1, 256, 0, stream>>>(sacc + 256, stat + 256, 256);
    k_gnap<<<32768, 256, 0, stream>>>(f2n, stat + 256, gn2_g, gn2_b, 63, 20, 8);

    // patch embed + cls
    k_bgemm<1, 3><<<dim3(4, 64), 256, 0, stream>>>(f2n, patchT, patch_b, xa, postab, 8192, 512, 4096);
    k_cls<<<64, 256, 0, stream>>>(cls_tok, xa);

    // transformer
    for (int l = 0; l < 8; l++) {
        k_wcvtT12<<<dim3(64, 16, 2), 256, 0, stream>>>(w1_w + (size_t)l * 1048576,
                                                       w2_w + (size_t)l * 1048576, w12Tl, 512, 2048);
        k_wcvtT<<<dim3(16, 64, 1), 256, 0, stream>>>(w3_w + (size_t)l * 1048576, w3Tl, 2048, 512);

        k_lnb<<<2056, 256, 0, stream>>>(xa, ln1_g + l * 512, ln1_b + l * 512, nb);
        k_bgemm<0, 7><<<dim3(12, 65), 256, 0, stream>>>(nb, qkvT + (size_t)l * 786432,
                                                        qkv_b + l * 1536, qkvb, ropet, 8224, 1536, 512);
        k_attn_mfma<<<2304, 256, 0, stream>>>(qkvb, yb);
        k_bgemm<0, 2><<<dim3(4, 65), 256, 0, stream>>>(yb, outT + (size_t)l * 262144,
                                                       out_b + l * 512, xa, nullptr, 8224, 512, 512);
        k_lnb<<<2056, 256, 0, stream>>>(xa, ln2_g + l * 512, ln2_b + l * 512, nb);
        k_bgemm<0, 6><<<dim3(32, 65), 256, 0, stream>>>(nb, w12Tl,
                                                        bias12 + l * 4096, hb, nullptr, 8224, 4096, 512);
        k_bgemm<0, 2><<<dim3(4, 65), 256, 0, stream>>>(hb, w3Tl,
                                                       w3_b + l * 512, xa, nullptr, 8224, 512, 2048);
    }
    k_ln_out<<<2056, 256, 0, stream>>>(xa, fn_g, fn_b, out);
}

// Round 10
// 2556.265 us; speedup vs baseline: 6.9515x; 1.0157x over previous
//
#include <hip/hip_runtime.h>

#define EPSV 1e-5f
typedef unsigned short u16;
typedef short bf16x8 __attribute__((ext_vector_type(8)));
typedef float f32x4 __attribute__((ext_vector_type(4)));

__device__ __forceinline__ float gelu_exact(float x) {
    return 0.5f * x * (1.0f + erff(x * 0.7071067811865475f));
}
__device__ __forceinline__ u16 to_bf(float x) {
    union { float f; unsigned u; } c; c.f = x;
    unsigned r = c.u + 0x7fffu + ((c.u >> 16) & 1u);
    return (u16)(r >> 16);
}
__device__ __forceinline__ float to_f(u16 h) {
    union { unsigned u; float f; } c; c.u = ((unsigned)h) << 16;
    return c.f;
}
__device__ __forceinline__ void gload_lds16(const void* g, void* l) {
    __builtin_amdgcn_global_load_lds((const __attribute__((address_space(1))) unsigned int*)g,
                                     (__attribute__((address_space(3))) unsigned int*)l, 16, 0, 0);
}

// ---------------- guard ----------------
__global__ void k_wsfail(float* out) { out[0] = 1.0e9f; }

// ---------------- combined setup: sacc-zero, conv1 wT, conv2 pack, bias12, tables, cls ----------------
__global__ void k_setup(float* __restrict__ sacc,
                        const float* __restrict__ conv1_w, float* __restrict__ w1t,
                        const float* __restrict__ conv2_w, u16* __restrict__ wpack,
                        const float* __restrict__ b1, const float* __restrict__ b2,
                        float* __restrict__ bias12,
                        float* __restrict__ postab, float* __restrict__ ropetab,
                        const float* __restrict__ cls, float* __restrict__ xa) {
    int idx = blockIdx.x * 256 + threadIdx.x;   // 512 blocks -> 131072
    if (idx < 131072) {
        int p = idx >> 9, j = idx & 511;
        float coord = (j < 256) ? (float)(p >> 4) : (float)(p & 15);
        int jm = j & 127;
        float om = powf(10000.0f, -(float)jm / 128.0f);
        float arg = coord * om;
        postab[idx] = ((j >> 7) & 1) ? cosf(arg) : sinf(arg);
    }
    if (idx < 512) {
        // xpos tables indexed by HEAD h (reference quirk): n_pos = H = 8
        int h = idx >> 6, d = idx & 63;
        float freq = (float)h * powf(10000.0f, -(float)(d >> 1) / 32.0f);
        float sv = (2.0f * (float)(d & 31) + 25.6f) / 89.6f;
        float pw = ((float)h - 4.0f) / 512.0f;
        float sc = powf(sv, pw);
        ropetab[idx * 4 + 0] = cosf(freq);
        ropetab[idx * 4 + 1] = sinf(freq);
        ropetab[idx * 4 + 2] = sc * 0.125f;   // q scale, HD^-0.5 folded
        ropetab[idx * 4 + 3] = 1.0f / sc;     // k scale
    }
    if (idx < 768) sacc[idx] = 0.0f;
    if (idx < 864) {                           // conv1 w: [32][27] -> [27][32]
        int co = idx / 27, k = idx % 27;
        w1t[k * 32 + co] = conv1_w[idx];
    }
    if (idx < 18432) {                         // conv2 w: [64][32][3][3] -> [tap][cout][ci]
        int ci = idx & 31, tc = idx >> 5;
        int tap = tc >> 6, co = tc & 63;
        wpack[idx] = to_bf(conv2_w[co * 288 + ci * 9 + tap]);
    }
    if (idx < 32768) {                         // packed bias12
        int l = idx >> 12, pc = idx & 4095;
        int chunk = pc >> 4, within = pc & 15;
        int srccol = (chunk >> 1) * 16 + within;
        bias12[idx] = (chunk & 1) ? b2[l * 2048 + srccol] : b1[l * 2048 + srccol];
    }
    if (idx < 16384) {                         // cls -> xa row 0 of each image
        int b = idx >> 9, d = idx & 511;
        xa[(size_t)(b * 257) * 512 + d] = cls[d];
    }
}

// patch_w [512][64][8][8] ([cout][ci][ky][kx]) -> bf16 [cout][tap*64+ci] (tap=ky*8+kx)
__global__ void k_pperm(const float* __restrict__ w, u16* __restrict__ wp) {
    int idx = blockIdx.x * 256 + threadIdx.x;
    int cout = idx >> 12, rem = idx & 4095;
    int tap = rem >> 6, ci = rem & 63;
    wp[idx] = to_bf(w[cout * 4096 + ci * 64 + tap]);
}

// fp32 [K][N] -> bf16 [N][K] transpose-convert (z = layer, stride K*N both sides)
__global__ __launch_bounds__(256) void k_wcvtT(const float* __restrict__ src,
                                               u16* __restrict__ dst, int K, int N) {
    __shared__ float s[32][33];
    int z = blockIdx.z;
    src += (size_t)z * K * N;
    dst += (size_t)z * K * N;
    int k0 = blockIdx.y * 32, n0 = blockIdx.x * 32;
    int t = threadIdx.x, r = t >> 3, c4 = (t & 7) * 4;
    float4 v = *(const float4*)&src[(size_t)(k0 + r) * N + n0 + c4];
    s[r][c4 + 0] = v.x; s[r][c4 + 1] = v.y; s[r][c4 + 2] = v.z; s[r][c4 + 3] = v.w;
    __syncthreads();
    ushort4 o;
    o.x = to_bf(s[c4 + 0][r]); o.y = to_bf(s[c4 + 1][r]);
    o.z = to_bf(s[c4 + 2][r]); o.w = to_bf(s[c4 + 3][r]);
    *(ushort4*)&dst[(size_t)(n0 + r) * K + k0 + c4] = o;
}

// all-layer w1/w2 transpose-convert with 16-col interleaved packing.
// z in 0..15: layer = z>>1, sel = z&1. K=512, N=2048.
__global__ __launch_bounds__(256) void k_wcvtT12L(const float* __restrict__ w1,
                                                  const float* __restrict__ w2,
                                                  u16* __restrict__ w12All) {
    __shared__ float s[32][33];
    int z = blockIdx.z;
    int layer = z >> 1, sel = z & 1;
    const float* src = (sel ? w2 : w1) + (size_t)layer * 1048576;
    u16* dst = w12All + (size_t)layer * 2097152;
    int k0 = blockIdx.y * 32, n0 = blockIdx.x * 32;
    int t = threadIdx.x, r = t >> 3, c4 = (t & 7) * 4;
    float4 v = *(const float4*)&src[(size_t)(k0 + r) * 2048 + n0 + c4];
    s[r][c4 + 0] = v.x; s[r][c4 + 1] = v.y; s[r][c4 + 2] = v.z; s[r][c4 + 3] = v.w;
    __syncthreads();
    ushort4 o;
    o.x = to_bf(s[c4 + 0][r]); o.y = to_bf(s[c4 + 1][r]);
    o.z = to_bf(s[c4 + 2][r]); o.w = to_bf(s[c4 + 3][r]);
    int nsrc = n0 + r;
    int p = ((nsrc >> 4) << 5) + (sel << 4) + (nsrc & 15);
    *(ushort4*)&dst[(size_t)p * 512 + k0 + c4] = o;
}

// ---------------- conv1: fp32 direct, bf16 NHWC out + GN partial sums ----------------
__global__ __launch_bounds__(256) void k_conv1(const float* __restrict__ in,
                                               const float* __restrict__ wt,   // [27][32]
                                               const float* __restrict__ bias,
                                               u16* __restrict__ f1n,
                                               float* __restrict__ sacc) {
    __shared__ float s_in[3][18][18];
    __shared__ float rs[4][4], rq[4][4];
    int b = blockIdx.y;
    int tile = blockIdx.x;
    int y0 = (tile >> 3) << 4;
    int x0 = (tile & 7) << 4;
    int tid = threadIdx.x;
    for (int idx = tid; idx < 972; idx += 256) {
        int ci = idx / 324, r = idx % 324;
        int ly = r / 18, lx = r % 18;
        int gy = y0 + ly - 1, gx = x0 + lx - 1;
        float v = 0.0f;
        if (gy >= 0 && gy < 128 && gx >= 0 && gx < 128)
            v = in[((size_t)(b * 3 + ci) * 128 + gy) * 128 + gx];
        s_in[ci][ly][lx] = v;
    }
    __syncthreads();
    int py = tid >> 4, px = tid & 15;
    float acc[32];
#pragma unroll
    for (int co = 0; co < 32; co++) acc[co] = bias[co];
#pragma unroll
    for (int ci = 0; ci < 3; ci++)
#pragma unroll
        for (int dy = 0; dy < 3; dy++)
#pragma unroll
            for (int dx = 0; dx < 3; dx++) {
                float v = s_in[ci][py + dy][px + dx];
                const float* wr = &wt[(ci * 9 + dy * 3 + dx) * 32];
#pragma unroll
                for (int co = 0; co < 32; co++)
                    acc[co] = fmaf(wr[co], v, acc[co]);
            }
    float s[4] = {0.f, 0.f, 0.f, 0.f}, q[4] = {0.f, 0.f, 0.f, 0.f};
    u16 ob[32];
#pragma unroll
    for (int co = 0; co < 32; co++) {
        u16 hv = to_bf(acc[co]);
        ob[co] = hv;
        float v = to_f(hv);
        s[co >> 3] += v;
        q[co >> 3] += v * v;
    }
    int oy = y0 + py, ox = x0 + px;
    u16* dst = f1n + ((size_t)(b * 16384 + oy * 128 + ox) << 5);
#pragma unroll
    for (int i = 0; i < 8; i++)
        *(ushort4*)(dst + i * 4) = make_ushort4(ob[i * 4], ob[i * 4 + 1], ob[i * 4 + 2], ob[i * 4 + 3]);
#pragma unroll
    for (int g = 0; g < 4; g++) {
#pragma unroll
        for (int off = 1; off < 64; off <<= 1) {
            s[g] += __shfl_xor(s[g], off);
            q[g] += __shfl_xor(q[g], off);
        }
    }
    int w = tid >> 6, lane = tid & 63;
    if (lane == 0)
#pragma unroll
        for (int g = 0; g < 4; g++) { rs[g][w] = s[g]; rq[g][w] = q[g]; }
    __syncthreads();
    if (tid < 4) {
        int g = tid;
        float S = rs[g][0] + rs[g][1] + rs[g][2] + rs[g][3];
        float Q = rq[g][0] + rq[g][1] + rq[g][2] + rq[g][3];
        atomicAdd(&sacc[(b * 4 + g) * 2], S);
        atomicAdd(&sacc[(b * 4 + g) * 2 + 1], Q);
    }
}

// GN apply + GELU, bf16 NHWC in-place; stats finalized inline from sacc
__global__ void k_gnap(u16* __restrict__ xio, const float* __restrict__ sacc,
                       const float* __restrict__ gg, const float* __restrict__ bb,
                       int cm, int sh, int gmul) {
    int idx = blockIdx.x * 256 + threadIdx.x;
    long e = (long)idx * 4;
    int c0 = (int)(e & cm);
    int b = (int)(e >> sh);
    int sid = b * gmul + (c0 >> 3);
    float m = sacc[2 * sid] * (1.0f / 131072.0f);
    float var = sacc[2 * sid + 1] * (1.0f / 131072.0f) - m * m;
    float r = rsqrtf(var + 1e-5f);
    ushort4 a = *(ushort4*)&xio[e];
    ushort4 o;
    o.x = to_bf(gelu_exact((to_f(a.x) - m) * r * gg[c0 + 0] + bb[c0 + 0]));
    o.y = to_bf(gelu_exact((to_f(a.y) - m) * r * gg[c0 + 1] + bb[c0 + 1]));
    o.z = to_bf(gelu_exact((to_f(a.z) - m) * r * gg[c0 + 2] + bb[c0 + 2]));
    o.w = to_bf(gelu_exact((to_f(a.w) - m) * r * gg[c0 + 3] + bb[c0 + 3]));
    *(ushort4*)&xio[e] = o;
}

// ---------------- conv2 as MFMA implicit GEMM, zero-LDS ----------------
__global__ __launch_bounds__(256) void k_conv2m(const u16* __restrict__ f1b,
                                                const u16* __restrict__ wp,   // [9][64][32]
                                                const float* __restrict__ bias,
                                                u16* __restrict__ f2n,
                                                float* __restrict__ sacc) {
    int b = blockIdx.y;
    int tile = blockIdx.x;
    int y0 = (tile >> 3) << 4;
    int x0 = (tile & 7) << 4;
    int tid = threadIdx.x;
    int w = tid >> 6, lane = tid & 63;
    int l15 = lane & 15, l16 = lane >> 4;

    const u16* base = f1b + ((size_t)b << 19);

    f32x4 acc[4][4];
    f32x4 zf = {0.f, 0.f, 0.f, 0.f};
#pragma unroll
    for (int m = 0; m < 4; m++)
#pragma unroll
        for (int n = 0; n < 4; n++) acc[m][n] = zf;
    bf16x8 zb = {0, 0, 0, 0, 0, 0, 0, 0};

#pragma unroll
    for (int tap = 0; tap < 9; tap++) {
        int dy = tap / 3, dx = tap % 3;
        int gx = x0 + l15 + dx - 1;
        bf16x8 af[4], bk[4];
#pragma unroll
        for (int m = 0; m < 4; m++) {
            int gy = y0 + w * 4 + m + dy - 1;
            bool ok = (gy >= 0) && (gy < 128) && (gx >= 0) && (gx < 128);
            int pix = ok ? (gy * 128 + gx) : 0;
            bf16x8 v = *(const bf16x8*)(base + ((size_t)pix << 5) + l16 * 8);
            af[m] = ok ? v : zb;
        }
#pragma unroll
        for (int n = 0; n < 4; n++)
            bk[n] = *(const bf16x8*)&wp[(tap * 64 + n * 16 + l15) * 32 + l16 * 8];
#pragma unroll
        for (int m = 0; m < 4; m++)
#pragma unroll
            for (int n = 0; n < 4; n++)
                acc[m][n] = __builtin_amdgcn_mfma_f32_16x16x32_bf16(af[m], bk[n], acc[m][n], 0, 0, 0);
    }

#pragma unroll
    for (int n = 0; n < 4; n++) {
        int gco = n * 16 + l15;
        float bv = bias[gco];
        float sn = 0.0f, qn = 0.0f;
#pragma unroll
        for (int m = 0; m < 4; m++) {
            int py = w * 4 + m;
#pragma unroll
            for (int r = 0; r < 4; r++) {
                int px = l16 * 4 + r;
                float v = acc[m][n][r] + bv;
                u16 hv = to_bf(v);
                f2n[((size_t)(b * 16384 + (y0 + py) * 128 + x0 + px) << 6) + gco] = hv;
                float vf = to_f(hv);
                sn += vf;
                qn += vf * vf;
            }
        }
#pragma unroll
        for (int off = 1; off <= 4; off <<= 1) { sn += __shfl_xor(sn, off); qn += __shfl_xor(qn, off); }
        sn += __shfl_xor(sn, 16); qn += __shfl_xor(qn, 16);
        sn += __shfl_xor(sn, 32); qn += __shfl_xor(qn, 32);
        if (lane == 0 || lane == 8) {
            int g = n * 2 + (lane >> 3);
            atomicAdd(&sacc[(b * 8 + g) * 2], sn);
            atomicAdd(&sacc[(b * 8 + g) * 2 + 1], qn);
        }
    }
}

// ---------------- bf16 MFMA GEMM ----------------
// MODE 0: A [M,K] row-major. MODE 1: implicit im2col of f2n NHWC (k = tap*64+ci).
// EPI 1: fp32 C = acc+bias. EPI 2: fp32 C += acc+bias. EPI 3: patch scatter + postab.
// EPI 6: interleaved w12 -> bf16 hb = silu(h1)*h2, out stride N/2.
// EPI 7: bf16 C = rope(acc+bias) for cols<1024 (aux = rope table), else acc+bias.
template <int MODE, int EPI>
__global__ __launch_bounds__(256) void k_bgemm(const u16* __restrict__ A,
                                               const u16* __restrict__ Bt,
                                               const float* __restrict__ bias,
                                               void* __restrict__ Cp,
                                               const float* __restrict__ aux,
                                               int M, int N, int K) {
    __shared__ u16 ldsA[8192];   // [kg 8][row 128][8]
    __shared__ u16 ldsB[8192];   // [col 128][kg^swz 8][8]
    int tid = threadIdx.x;
    int w = tid >> 6, lane = tid & 63;
    int bm = blockIdx.y * 128, bn = blockIdx.x * 128;
    int wr = w >> 1, wc = w & 1;
    int l15 = lane & 15, l16 = lane >> 4;

    f32x4 acc[4][4];
    f32x4 zf = {0.f, 0.f, 0.f, 0.f};
#pragma unroll
    for (int m = 0; m < 4; m++)
#pragma unroll
        for (int n = 0; n < 4; n++) acc[m][n] = zf;

    for (int k0 = 0; k0 < K; k0 += 64) {
#pragma unroll
        for (int i = 0; i < 4; i++) {
            int chunk = (w * 4 + i) * 64 + lane;
            int kg = chunk >> 7, row = chunk & 127;
            const u16* src;
            if (MODE == 0) {
                int grow = bm + row;
                if (grow > M - 1) grow = M - 1;
                src = A + (size_t)grow * K + k0 + kg * 8;
            } else {
                int grow = bm + row;
                int bimg = grow >> 8, p = grow & 255;
                int kga = (k0 >> 3) + kg;
                int tap = kga >> 3, cq = kga & 7;
                int ky = tap >> 3, kx = tap & 7;
                int gy = ((p >> 4) << 3) + ky, gx = ((p & 15) << 3) + kx;
                src = A + (((size_t)(bimg * 16384 + gy * 128 + gx)) << 6) + cq * 8;
            }
            gload_lds16(src, &ldsA[(w * 4 + i) * 512]);
        }
#pragma unroll
        for (int i = 0; i < 4; i++) {
            int chunk = (w * 4 + i) * 64 + lane;
            int col = chunk >> 3, kgs = chunk & 7;
            int kg_src = kgs ^ (col & 7);
            const u16* src = Bt + (size_t)(bn + col) * K + k0 + kg_src * 8;
            gload_lds16(src, &ldsB[(w * 4 + i) * 512]);
        }
        __syncthreads();

        bf16x8 af[4][2], bfr[4][2];
#pragma unroll
        for (int kk = 0; kk < 2; kk++) {
            int kga = kk * 4 + l16;
#pragma unroll
            for (int m = 0; m < 4; m++) {
                int row_l = wr * 64 + m * 16 + l15;
                af[m][kk] = *(const bf16x8*)&ldsA[(kga * 128 + row_l) * 8];
            }
#pragma unroll
            for (int n = 0; n < 4; n++) {
                int col_l = wc * 64 + n * 16 + l15;
                bfr[n][kk] = *(const bf16x8*)&ldsB[(col_l * 8 + (kga ^ (col_l & 7))) * 8];
            }
        }
#pragma unroll
        for (int m = 0; m < 4; m++)
#pragma unroll
            for (int n = 0; n < 4; n++) {
                acc[m][n] = __builtin_amdgcn_mfma_f32_16x16x32_bf16(af[m][0], bfr[n][0], acc[m][n], 0, 0, 0);
                acc[m][n] = __builtin_amdgcn_mfma_f32_16x16x32_bf16(af[m][1], bfr[n][1], acc[m][n], 0, 0, 0);
            }
        __syncthreads();
    }

    if (EPI == 6) {
#pragma unroll
        for (int np = 0; np < 2; np++) {
            int n_a = np * 2, n_b = np * 2 + 1;
            float bva = bias[bn + wc * 64 + n_a * 16 + l15];
            float bvb = bias[bn + wc * 64 + n_b * 16 + l15];
            int ocol = (bn >> 1) + wc * 32 + np * 16 + l15;
#pragma unroll
            for (int m = 0; m < 4; m++) {
#pragma unroll
                for (int r = 0; r < 4; r++) {
                    int grow = bm + wr * 64 + m * 16 + l16 * 4 + r;
                    if (grow < M) {
                        float h1v = to_f(to_bf(acc[m][n_a][r] + bva));
                        float h2v = to_f(to_bf(acc[m][n_b][r] + bvb));
                        float sl = h1v / (1.0f + __expf(-h1v));
                        ((u16*)Cp)[(size_t)grow * (N >> 1) + ocol] = to_bf(sl * h2v);
                    }
                }
            }
        }
    } else {
#pragma unroll
        for (int n = 0; n < 4; n++) {
            int gcol = bn + wc * 64 + n * 16 + l15;
            float bv = bias[gcol];
            float rc = 0.f, rsn = 0.f, rsc = 1.f;
            bool isqk = false, odd = false;
            if (EPI == 7) {
                isqk = gcol < 1024;
                odd = (l15 & 1) != 0;
                const float* rb = &aux[(gcol & 511) * 4];
                if (isqk) {
                    rc = rb[0]; rsn = rb[1];
                    rsc = (gcol < 512) ? rb[2] : rb[3];
                }
            }
#pragma unroll
            for (int m = 0; m < 4; m++) {
#pragma unroll
                for (int r = 0; r < 4; r++) {
                    int grow = bm + wr * 64 + m * 16 + l16 * 4 + r;
                    float v = acc[m][n][r] + bv;
                    if (EPI == 7) {
                        float p = __shfl_xor(v, 1);
                        float vr = isqk ? ((odd ? (v * rc + p * rsn) : (v * rc - p * rsn)) * rsc) : v;
                        if (grow < M) ((u16*)Cp)[(size_t)grow * N + gcol] = to_bf(vr);
                    } else if (EPI == 1) {
                        if (grow < M) ((float*)Cp)[(size_t)grow * N + gcol] = v;
                    } else if (EPI == 2) {
                        if (grow < M) ((float*)Cp)[(size_t)grow * N + gcol] += v;
                    } else {
                        int bimg = grow >> 8, p2 = grow & 255;
                        v += aux[p2 * 512 + gcol];
                        ((float*)Cp)[((size_t)(bimg * 257) + 1 + p2) * 512 + gcol] = v;
                    }
                }
            }
        }
    }
}

// ---------------- LayerNorm, wave-per-row (4 rows/block), bf16 out ----------------
__global__ __launch_bounds__(256) void k_lnb(const float* __restrict__ x,
                                             const float* __restrict__ g,
                                             const float* __restrict__ bta,
                                             u16* __restrict__ o) {
    int row = blockIdx.x * 4 + (threadIdx.x >> 6);
    int lane = threadIdx.x & 63;
    const float4* xr = (const float4*)(x + (size_t)row * 512);
    float4 a = xr[lane * 2], b = xr[lane * 2 + 1];
    float s = a.x + a.y + a.z + a.w + b.x + b.y + b.z + b.w;
#pragma unroll
    for (int off = 1; off < 64; off <<= 1) s += __shfl_xor(s, off);
    float mean = s * (1.0f / 512.0f);
    float d[8] = {a.x - mean, a.y - mean, a.z - mean, a.w - mean,
                  b.x - mean, b.y - mean, b.z - mean, b.w - mean};
    float q = 0.0f;
#pragma unroll
    for (int i = 0; i < 8; i++) q += d[i] * d[i];
#pragma unroll
    for (int off = 1; off < 64; off <<= 1) q += __shfl_xor(q, off);
    float rstd = rsqrtf(q * (1.0f / 512.0f) + EPSV);
    int c0 = lane * 8;
    float4 g0 = *(const float4*)&g[c0], g1 = *(const float4*)&g[c0 + 4];
    float4 b0 = *(const float4*)&bta[c0], b1 = *(const float4*)&bta[c0 + 4];
    u16* orow = o + (size_t)row * 512 + c0;
    *(ushort4*)orow = make_ushort4(to_bf(d[0] * rstd * g0.x + b0.x), to_bf(d[1] * rstd * g0.y + b0.y),
                                   to_bf(d[2] * rstd * g0.z + b0.z), to_bf(d[3] * rstd * g0.w + b0.w));
    *(ushort4*)(orow + 4) = make_ushort4(to_bf(d[4] * rstd * g1.x + b1.x), to_bf(d[5] * rstd * g1.y + b1.y),
                                         to_bf(d[6] * rstd * g1.z + b1.z), to_bf(d[7] * rstd * g1.w + b1.w));
}

// final LN, wave-per-row, output remap (fp32 out)
__global__ __launch_bounds__(256) void k_ln_out(const float* __restrict__ x,
                                                const float* __restrict__ g,
                                                const float* __restrict__ bta,
                                                float* __restrict__ out) {
    int row = blockIdx.x * 4 + (threadIdx.x >> 6);
    int lane = threadIdx.x & 63;
    const float4* xr = (const float4*)(x + (size_t)row * 512);
    float4 a = xr[lane * 2], b = xr[lane * 2 + 1];
    float s = a.x + a.y + a.z + a.w + b.x + b.y + b.z + b.w;
#pragma unroll
    for (int off = 1; off < 64; off <<= 1) s += __shfl_xor(s, off);
    float mean = s * (1.0f / 512.0f);
    float d[8] = {a.x - mean, a.y - mean, a.z - mean, a.w - mean,
                  b.x - mean, b.y - mean, b.z - mean, b.w - mean};
    float q = 0.0f;
#pragma unroll
    for (int i = 0; i < 8; i++) q += d[i] * d[i];
#pragma unroll
    for (int off = 1; off < 64; off <<= 1) q += __shfl_xor(q, off);
    float rstd = rsqrtf(q * (1.0f / 512.0f) + EPSV);
    int bb = row / 257, t = row % 257;
    float* dst = (t == 0) ? out + (size_t)bb * 512
                          : out + 16384 + (size_t)(bb * 256 + (t - 1)) * 512;
    int c0 = lane * 8;
    float4 g0 = *(const float4*)&g[c0], g1 = *(const float4*)&g[c0 + 4];
    float4 b0 = *(const float4*)&bta[c0], b1 = *(const float4*)&bta[c0 + 4];
    *(float4*)(dst + c0) = make_float4(d[0] * rstd * g0.x + b0.x, d[1] * rstd * g0.y + b0.y,
                                       d[2] * rstd * g0.z + b0.z, d[3] * rstd * g0.w + b0.w);
    *(float4*)(dst + c0 + 4) = make_float4(d[4] * rstd * g1.x + b1.x, d[5] * rstd * g1.y + b1.y,
                                           d[6] * rstd * g1.z + b1.z, d[7] * rstd * g1.w + b1.w);
}

// ---------------- MFMA attention: pre-roped qkv, direct-global Q/K, dbuf PV ----------------
__global__ __launch_bounds__(256) void k_attn_mfma(const u16* __restrict__ qkv,
                                                   u16* __restrict__ y) {
    __shared__ u16 KV[2][64][72];     // V^T tiles, double-buffered (1 barrier per tile)
    __shared__ float sc[32][260];
    __shared__ u16 Pb[32][328];
    __shared__ float red1[32][8];
    __shared__ float red2[32][8];
    __shared__ float invr[32];

    int bid = blockIdx.x;                 // ((b*8+h)*9 + qt)
    int qt = bid % 9, bh = bid / 9;
    int h = bh & 7, b = bh >> 3;
    int q0 = qt * 32;
    int tid = threadIdx.x;
    int w = tid >> 6, lane = tid & 63;
    int l15 = lane & 15, l16 = lane >> 4;

    bf16x8 aq[2][2];
#pragma unroll
    for (int m = 0; m < 2; m++) {
        int grow = q0 + m * 16 + l15; if (grow > 256) grow = 256;
        const u16* qp = qkv + (size_t)(b * 257 + grow) * 1536 + h * 64 + l16 * 8;
        aq[m][0] = *(const bf16x8*)qp;
        aq[m][1] = *(const bf16x8*)(qp + 32);
    }

    for (int t = 0; t < 5; t++) {
        int j0 = t * 64;
        int gk = j0 + w * 16 + l15; if (gk > 256) gk = 256;
        const u16* kp = qkv + (size_t)(b * 257 + gk) * 1536 + 512 + h * 64 + l16 * 8;
        bf16x8 bk0 = *(const bf16x8*)kp;
        bf16x8 bk1 = *(const bf16x8*)(kp + 32);
        f32x4 a2[2];
        f32x4 zf = {0.f, 0.f, 0.f, 0.f};
#pragma unroll
        for (int m = 0; m < 2; m++) {
            a2[m] = zf;
            a2[m] = __builtin_amdgcn_mfma_f32_16x16x32_bf16(aq[m][0], bk0, a2[m], 0, 0, 0);
            a2[m] = __builtin_amdgcn_mfma_f32_16x16x32_bf16(aq[m][1], bk1, a2[m], 0, 0, 0);
        }
        int col = j0 + w * 16 + l15;
        if (col < 257) {
#pragma unroll
            for (int m = 0; m < 2; m++)
#pragma unroll
                for (int r = 0; r < 4; r++)
                    sc[m * 16 + l16 * 4 + r][col] = a2[m][r];
        }
    }
    __syncthreads();

    {
        int r = tid >> 3, sub = tid & 7;
        float mx = -1e30f;
        for (int j = sub; j < 257; j += 8) mx = fmaxf(mx, sc[r][j]);
        red1[r][sub] = mx;
        __syncthreads();
        mx = red1[r][0];
#pragma unroll
        for (int i = 1; i < 8; i++) mx = fmaxf(mx, red1[r][i]);
        float sm = 0.0f;
        for (int j = sub; j < 257; j += 8) {
            float e = __expf(sc[r][j] - mx);
            Pb[r][j] = to_bf(e);
            sm += e;
        }
        for (int j = 257 + sub; j < 320; j += 8) Pb[r][j] = 0;
        red2[r][sub] = sm;
        __syncthreads();
        if (sub == 0) {
            float t = red2[r][0];
#pragma unroll
            for (int i = 1; i < 8; i++) t += red2[r][i];
            invr[r] = 1.0f / t;
        }
        __syncthreads();
    }

    f32x4 oacc[2];
    {
        f32x4 zf = {0.f, 0.f, 0.f, 0.f};
        oacc[0] = zf; oacc[1] = zf;
    }
    for (int t = 0; t < 5; t++) {
        int j0 = t * 64;
        int buf = t & 1;
        {
            int vk = tid & 63, vd0 = (tid >> 6) * 16;
            int gk = j0 + vk;
            u16 o[16];
            if (gk <= 256) {
                const u16* vp = qkv + (size_t)(b * 257 + gk) * 1536 + 1024 + h * 64 + vd0;
                ushort4 a0 = *(const ushort4*)vp, a1 = *(const ushort4*)(vp + 4);
                ushort4 a2v = *(const ushort4*)(vp + 8), a3 = *(const ushort4*)(vp + 12);
                o[0] = a0.x; o[1] = a0.y; o[2] = a0.z; o[3] = a0.w;
                o[4] = a1.x; o[5] = a1.y; o[6] = a1.z; o[7] = a1.w;
                o[8] = a2v.x; o[9] = a2v.y; o[10] = a2v.z; o[11] = a2v.w;
                o[12] = a3.x; o[13] = a3.y; o[14] = a3.z; o[15] = a3.w;
            } else {
#pragma unroll
                for (int i = 0; i < 16; i++) o[i] = 0;
            }
#pragma unroll
            for (int i = 0; i < 16; i++) KV[buf][vd0 + i][vk] = o[i];
        }
        __syncthreads();   // single barrier per tile: next iter writes the OTHER buffer

        bf16x8 ap[2][2], bv[2];
#pragma unroll
        for (int m = 0; m < 2; m++)
#pragma unroll
            for (int kk = 0; kk < 2; kk++)
                ap[m][kk] = *(const bf16x8*)&Pb[m * 16 + l15][j0 + kk * 32 + l16 * 8];
#pragma unroll
        for (int kk = 0; kk < 2; kk++)
            bv[kk] = *(const bf16x8*)&KV[buf][w * 16 + l15][kk * 32 + l16 * 8];
#pragma unroll
        for (int m = 0; m < 2; m++) {
            oacc[m] = __builtin_amdgcn_mfma_f32_16x16x32_bf16(ap[m][0], bv[0], oacc[m], 0, 0, 0);
            oacc[m] = __builtin_amdgcn_mfma_f32_16x16x32_bf16(ap[m][1], bv[1], oacc[m], 0, 0, 0);
        }
    }

#pragma unroll
    for (int m = 0; m < 2; m++)
#pragma unroll
        for (int r = 0; r < 4; r++) {
            int lr = m * 16 + l16 * 4 + r;
            int grow = q0 + lr;
            if (grow < 257)
                y[(size_t)(b * 257 + grow) * 512 + h * 64 + w * 16 + l15] =
                    to_bf(oacc[m][r] * invr[lr]);
        }
}

// ---------------- host launch ----------------
extern "C" void kernel_launch(void* const* d_in, const int* in_sizes, int n_in,
                              void* d_out, int out_size, void* d_ws, size_t ws_size,
                              hipStream_t stream) {
    const float* x       = (const float*)d_in[0];
    const float* conv1_w = (const float*)d_in[1];
    const float* conv1_b = (const float*)d_in[2];
    const float* gn1_g   = (const float*)d_in[3];
    const float* gn1_b   = (const float*)d_in[4];
    const float* conv2_w = (const float*)d_in[5];
    const float* conv2_b = (const float*)d_in[6];
    const float* gn2_g   = (const float*)d_in[7];
    const float* gn2_b   = (const float*)d_in[8];
    const float* patch_w = (const float*)d_in[9];
    const float* patch_b = (const float*)d_in[10];
    const float* cls_tok = (const float*)d_in[11];
    const float* ln1_g   = (const float*)d_in[12];
    const float* ln1_b   = (const float*)d_in[13];
    const float* qkv_w   = (const float*)d_in[14];
    const float* qkv_b   = (const float*)d_in[15];
    const float* out_w   = (const float*)d_in[16];
    const float* out_b   = (const float*)d_in[17];
    const float* ln2_g   = (const float*)d_in[18];
    const float* ln2_b   = (const float*)d_in[19];
    const float* w1_w    = (const float*)d_in[20];
    const float* w1_b    = (const float*)d_in[21];
    const float* w2_w    = (const float*)d_in[22];
    const float* w2_b    = (const float*)d_in[23];
    const float* w3_w    = (const float*)d_in[24];
    const float* w3_b    = (const float*)d_in[25];
    const float* fn_g    = (const float*)d_in[26];
    const float* fn_b    = (const float*)d_in[27];
    float* out = (float*)d_out;
    char* wsb  = (char*)d_ws;

    // arena (bytes), lifetime-aliased. Total 246,181,888 < 252,991,488 proven avail.
    // Region 0..67.37MB: f2n (stem) -> {w12All 33.55MB + w3All 16.78MB} (transformer)
    const size_t O_R1    = 0;
    const size_t O_W12A  = 0;                 // 33,554,432 (after patchgemm)
    const size_t O_W3A   = 33554432;          // 16,777,216
    const size_t O_HB    = O_R1 + 67371008;   // 33,685,504
    const size_t O_NB    = O_R1 + 101056512;  // 8,421,376
    const size_t O_Y     = O_R1 + 109477888;  // 8,421,376
    const size_t O_R2    = 134217728;         // f1n bf16 | qkvb bf16
    const size_t O_XA    = 201326592;
    const size_t O_PWT   = 218169344;
    const size_t O_QKVT  = 222363648;
    const size_t O_OUTT  = 234946560;
    const size_t O_PT    = 245432320;
    const size_t O_RT    = 245956608;
    const size_t O_CW1   = 245964800;
    const size_t O_CW2   = 245968896;
    const size_t O_SA    = 246046720;
    const size_t O_B12   = 246050816;
    const size_t NEED    = 246181888;
    if (ws_size < NEED) {
        k_wsfail<<<1, 1, 0, stream>>>(out);
        return;
    }
    u16*   f2n    = (u16*)(wsb + O_R1);
    u16*   w12All = (u16*)(wsb + O_W12A);
    u16*   w3All  = (u16*)(wsb + O_W3A);
    u16*   hb     = (u16*)(wsb + O_HB);
    u16*   nb     = (u16*)(wsb + O_NB);
    u16*   yb     = (u16*)(wsb + O_Y);
    u16*   f1n    = (u16*)(wsb + O_R2);
    u16*   qkvb   = (u16*)(wsb + O_R2);
    float* xa     = (float*)(wsb + O_XA);
    u16*   patchT = (u16*)(wsb + O_PWT);
    u16*   qkvT   = (u16*)(wsb + O_QKVT);
    u16*   outT   = (u16*)(wsb + O_OUTT);
    float* postab = (float*)(wsb + O_PT);
    float* ropet  = (float*)(wsb + O_RT);
    float* w1t    = (float*)(wsb + O_CW1);
    u16*   wpack  = (u16*)(wsb + O_CW2);
    float* sacc   = (float*)(wsb + O_SA);
    float* bias12 = (float*)(wsb + O_B12);

    // setup (combined) + big weight conversions
    k_setup<<<512, 256, 0, stream>>>(sacc, conv1_w, w1t, conv2_w, wpack,
                                     w1_b, w2_b, bias12, postab, ropet, cls_tok, xa);
    k_pperm<<<8192, 256, 0, stream>>>(patch_w, patchT);
    k_wcvtT<<<dim3(48, 16, 8), 256, 0, stream>>>(qkv_w, qkvT, 512, 1536);
    k_wcvtT<<<dim3(16, 16, 8), 256, 0, stream>>>(out_w, outT, 512, 512);

    // conv stem (NHWC bf16, fused GN stats; finalize inlined in gnap)
    k_conv1<<<dim3(64, 32), 256, 0, stream>>>(x, w1t, conv1_b, f1n, sacc);
    k_gnap<<<16384, 256, 0, stream>>>(f1n, sacc, gn1_g, gn1_b, 31, 19, 4);
    k_conv2m<<<dim3(64, 32), 256, 0, stream>>>(f1n, wpack, conv2_b, f2n, sacc + 256);
    k_gnap<<<32768, 256, 0, stream>>>(f2n, sacc + 256, gn2_g, gn2_b, 63, 20, 8);

    // patch embed (reads f2n; afterwards region 0 is free for weights)
    k_bgemm<1, 3><<<dim3(4, 64), 256, 0, stream>>>(f2n, patchT, patch_b, xa, postab, 8192, 512, 4096);

    // one-time all-layer MLP weight conversion into freed region
    k_wcvtT12L<<<dim3(64, 16, 16), 256, 0, stream>>>(w1_w, w2_w, w12All);
    k_wcvtT<<<dim3(16, 64, 8), 256, 0, stream>>>(w3_w, w3All, 2048, 512);

    // transformer
    for (int l = 0; l < 8; l++) {
        k_lnb<<<2056, 256, 0, stream>>>(xa, ln1_g + l * 512, ln1_b + l * 512, nb);
        k_bgemm<0, 7><<<dim3(12, 65), 256, 0, stream>>>(nb, qkvT + (size_t)l * 786432,
                                                        qkv_b + l * 1536, qkvb, ropet, 8224, 1536, 512);
        k_attn_mfma<<<2304, 256, 0, stream>>>(qkvb, yb);
        k_bgemm<0, 2><<<dim3(4, 65), 256, 0, stream>>>(yb, outT + (size_t)l * 262144,
                                                       out_b + l * 512, xa, nullptr, 8224, 512, 512);
        k_lnb<<<2056, 256, 0, stream>>>(xa, ln2_g + l * 512, ln2_b + l * 512, nb);
        k_bgemm<0, 6><<<dim3(32, 65), 256, 0, stream>>>(nb, w12All + (size_t)l * 2097152,
                                                        bias12 + l * 4096, hb, nullptr, 8224, 4096, 512);
        k_bgemm<0, 2><<<dim3(4, 65), 256, 0, stream>>>(hb, w3All + (size_t)l * 1048576,
                                                       w3_b + l * 512, xa, nullptr, 8224, 512, 2048);
    }
    k_ln_out<<<2056, 256, 0, stream>>>(xa, fn_g, fn_b, out);
}

// Round 11
// 2266.208 us; speedup vs baseline: 7.8412x; 1.1280x over previous
//
#include <hip/hip_runtime.h>

#define EPSV 1e-5f
typedef unsigned short u16;
typedef short bf16x8 __attribute__((ext_vector_type(8)));
typedef float f32x4 __attribute__((ext_vector_type(4)));
typedef u16 u16x8 __attribute__((ext_vector_type(8)));

__device__ __forceinline__ float gelu_exact(float x) {
    return 0.5f * x * (1.0f + erff(x * 0.7071067811865475f));
}
__device__ __forceinline__ u16 to_bf(float x) {
    union { float f; unsigned u; } c; c.f = x;
    unsigned r = c.u + 0x7fffu + ((c.u >> 16) & 1u);
    return (u16)(r >> 16);
}
__device__ __forceinline__ float to_f(u16 h) {
    union { unsigned u; float f; } c; c.u = ((unsigned)h) << 16;
    return c.f;
}
__device__ __forceinline__ void gload_lds16(const void* g, void* l) {
    __builtin_amdgcn_global_load_lds((const __attribute__((address_space(1))) unsigned int*)g,
                                     (__attribute__((address_space(3))) unsigned int*)l, 16, 0, 0);
}

// ---------------- guard ----------------
__global__ void k_wsfail(float* out) { out[0] = 1.0e9f; }

// ---------------- combined setup ----------------
__global__ void k_setup(float* __restrict__ sacc,
                        const float* __restrict__ conv1_w, float* __restrict__ w1t,
                        const float* __restrict__ conv2_w, u16* __restrict__ wpack,
                        const float* __restrict__ b1, const float* __restrict__ b2,
                        float* __restrict__ bias12,
                        float* __restrict__ postab, float* __restrict__ ropetab,
                        const float* __restrict__ cls, float* __restrict__ xa) {
    int idx = blockIdx.x * 256 + threadIdx.x;   // 512 blocks -> 131072
    if (idx < 131072) {
        int p = idx >> 9, j = idx & 511;
        float coord = (j < 256) ? (float)(p >> 4) : (float)(p & 15);
        int jm = j & 127;
        float om = powf(10000.0f, -(float)jm / 128.0f);
        float arg = coord * om;
        postab[idx] = ((j >> 7) & 1) ? cosf(arg) : sinf(arg);
    }
    if (idx < 512) {
        // xpos tables indexed by HEAD h (reference quirk): n_pos = H = 8
        int h = idx >> 6, d = idx & 63;
        float freq = (float)h * powf(10000.0f, -(float)(d >> 1) / 32.0f);
        float sv = (2.0f * (float)(d & 31) + 25.6f) / 89.6f;
        float pw = ((float)h - 4.0f) / 512.0f;
        float sc = powf(sv, pw);
        ropetab[idx * 4 + 0] = cosf(freq);
        ropetab[idx * 4 + 1] = sinf(freq);
        ropetab[idx * 4 + 2] = sc * 0.125f;
        ropetab[idx * 4 + 3] = 1.0f / sc;
    }
    if (idx < 768) sacc[idx] = 0.0f;
    if (idx < 864) {
        int co = idx / 27, k = idx % 27;
        w1t[k * 32 + co] = conv1_w[idx];
    }
    if (idx < 18432) {
        int ci = idx & 31, tc = idx >> 5;
        int tap = tc >> 6, co = tc & 63;
        wpack[idx] = to_bf(conv2_w[co * 288 + ci * 9 + tap]);
    }
    if (idx < 32768) {
        int l = idx >> 12, pc = idx & 4095;
        int chunk = pc >> 4, within = pc & 15;
        int srccol = (chunk >> 1) * 16 + within;
        bias12[idx] = (chunk & 1) ? b2[l * 2048 + srccol] : b1[l * 2048 + srccol];
    }
    if (idx < 16384) {
        int b = idx >> 9, d = idx & 511;
        xa[(size_t)(b * 257) * 512 + d] = cls[d];
    }
}

// patch_w [512][64][8][8] -> bf16 [cout][tap*64+ci]
__global__ void k_pperm(const float* __restrict__ w, u16* __restrict__ wp) {
    int idx = blockIdx.x * 256 + threadIdx.x;
    int cout = idx >> 12, rem = idx & 4095;
    int tap = rem >> 6, ci = rem & 63;
    wp[idx] = to_bf(w[cout * 4096 + ci * 64 + tap]);
}

// fp32 [K][N] -> bf16 [N][K] transpose-convert (z = layer)
__global__ __launch_bounds__(256) void k_wcvtT(const float* __restrict__ src,
                                               u16* __restrict__ dst, int K, int N) {
    __shared__ float s[32][33];
    int z = blockIdx.z;
    src += (size_t)z * K * N;
    dst += (size_t)z * K * N;
    int k0 = blockIdx.y * 32, n0 = blockIdx.x * 32;
    int t = threadIdx.x, r = t >> 3, c4 = (t & 7) * 4;
    float4 v = *(const float4*)&src[(size_t)(k0 + r) * N + n0 + c4];
    s[r][c4 + 0] = v.x; s[r][c4 + 1] = v.y; s[r][c4 + 2] = v.z; s[r][c4 + 3] = v.w;
    __syncthreads();
    ushort4 o;
    o.x = to_bf(s[c4 + 0][r]); o.y = to_bf(s[c4 + 1][r]);
    o.z = to_bf(s[c4 + 2][r]); o.w = to_bf(s[c4 + 3][r]);
    *(ushort4*)&dst[(size_t)(n0 + r) * K + k0 + c4] = o;
}

// all-layer w1/w2 transpose-convert with 16-col interleaved packing
__global__ __launch_bounds__(256) void k_wcvtT12L(const float* __restrict__ w1,
                                                  const float* __restrict__ w2,
                                                  u16* __restrict__ w12All) {
    __shared__ float s[32][33];
    int z = blockIdx.z;
    int layer = z >> 1, sel = z & 1;
    const float* src = (sel ? w2 : w1) + (size_t)layer * 1048576;
    u16* dst = w12All + (size_t)layer * 2097152;
    int k0 = blockIdx.y * 32, n0 = blockIdx.x * 32;
    int t = threadIdx.x, r = t >> 3, c4 = (t & 7) * 4;
    float4 v = *(const float4*)&src[(size_t)(k0 + r) * 2048 + n0 + c4];
    s[r][c4 + 0] = v.x; s[r][c4 + 1] = v.y; s[r][c4 + 2] = v.z; s[r][c4 + 3] = v.w;
    __syncthreads();
    ushort4 o;
    o.x = to_bf(s[c4 + 0][r]); o.y = to_bf(s[c4 + 1][r]);
    o.z = to_bf(s[c4 + 2][r]); o.w = to_bf(s[c4 + 3][r]);
    int nsrc = n0 + r;
    int p = ((nsrc >> 4) << 5) + (sel << 4) + (nsrc & 15);
    *(ushort4*)&dst[(size_t)p * 512 + k0 + c4] = o;
}

// ---------------- conv1: fp32 direct, bf16 NHWC out + GN partial sums ----------------
__global__ __launch_bounds__(256) void k_conv1(const float* __restrict__ in,
                                               const float* __restrict__ wt,   // [27][32]
                                               const float* __restrict__ bias,
                                               u16* __restrict__ f1n,
                                               float* __restrict__ sacc) {
    __shared__ float s_in[3][18][18];
    __shared__ float rs[4][4], rq[4][4];
    int b = blockIdx.y;
    int tile = blockIdx.x;
    int y0 = (tile >> 3) << 4;
    int x0 = (tile & 7) << 4;
    int tid = threadIdx.x;
    for (int idx = tid; idx < 972; idx += 256) {
        int ci = idx / 324, r = idx % 324;
        int ly = r / 18, lx = r % 18;
        int gy = y0 + ly - 1, gx = x0 + lx - 1;
        float v = 0.0f;
        if (gy >= 0 && gy < 128 && gx >= 0 && gx < 128)
            v = in[((size_t)(b * 3 + ci) * 128 + gy) * 128 + gx];
        s_in[ci][ly][lx] = v;
    }
    __syncthreads();
    int py = tid >> 4, px = tid & 15;
    float acc[32];
#pragma unroll
    for (int co = 0; co < 32; co++) acc[co] = bias[co];
#pragma unroll
    for (int ci = 0; ci < 3; ci++)
#pragma unroll
        for (int dy = 0; dy < 3; dy++)
#pragma unroll
            for (int dx = 0; dx < 3; dx++) {
                float v = s_in[ci][py + dy][px + dx];
                const float* wr = &wt[(ci * 9 + dy * 3 + dx) * 32];
#pragma unroll
                for (int co = 0; co < 32; co++)
                    acc[co] = fmaf(wr[co], v, acc[co]);
            }
    float s[4] = {0.f, 0.f, 0.f, 0.f}, q[4] = {0.f, 0.f, 0.f, 0.f};
    u16 ob[32];
#pragma unroll
    for (int co = 0; co < 32; co++) {
        u16 hv = to_bf(acc[co]);
        ob[co] = hv;
        float v = to_f(hv);
        s[co >> 3] += v;
        q[co >> 3] += v * v;
    }
    int oy = y0 + py, ox = x0 + px;
    u16* dst = f1n + ((size_t)(b * 16384 + oy * 128 + ox) << 5);
#pragma unroll
    for (int i = 0; i < 8; i++)
        *(ushort4*)(dst + i * 4) = make_ushort4(ob[i * 4], ob[i * 4 + 1], ob[i * 4 + 2], ob[i * 4 + 3]);
#pragma unroll
    for (int g = 0; g < 4; g++) {
#pragma unroll
        for (int off = 1; off < 64; off <<= 1) {
            s[g] += __shfl_xor(s[g], off);
            q[g] += __shfl_xor(q[g], off);
        }
    }
    int w = tid >> 6, lane = tid & 63;
    if (lane == 0)
#pragma unroll
        for (int g = 0; g < 4; g++) { rs[g][w] = s[g]; rq[g][w] = q[g]; }
    __syncthreads();
    if (tid < 4) {
        int g = tid;
        float S = rs[g][0] + rs[g][1] + rs[g][2] + rs[g][3];
        float Q = rq[g][0] + rq[g][1] + rq[g][2] + rq[g][3];
        atomicAdd(&sacc[(b * 4 + g) * 2], S);
        atomicAdd(&sacc[(b * 4 + g) * 2 + 1], Q);
    }
}

// GN apply + GELU, bf16 NHWC in-place; stats finalized inline from sacc
__global__ void k_gnap(u16* __restrict__ xio, const float* __restrict__ sacc,
                       const float* __restrict__ gg, const float* __restrict__ bb,
                       int cm, int sh, int gmul) {
    int idx = blockIdx.x * 256 + threadIdx.x;
    long e = (long)idx * 4;
    int c0 = (int)(e & cm);
    int b = (int)(e >> sh);
    int sid = b * gmul + (c0 >> 3);
    float m = sacc[2 * sid] * (1.0f / 131072.0f);
    float var = sacc[2 * sid + 1] * (1.0f / 131072.0f) - m * m;
    float r = rsqrtf(var + 1e-5f);
    ushort4 a = *(ushort4*)&xio[e];
    ushort4 o;
    o.x = to_bf(gelu_exact((to_f(a.x) - m) * r * gg[c0 + 0] + bb[c0 + 0]));
    o.y = to_bf(gelu_exact((to_f(a.y) - m) * r * gg[c0 + 1] + bb[c0 + 1]));
    o.z = to_bf(gelu_exact((to_f(a.z) - m) * r * gg[c0 + 2] + bb[c0 + 2]));
    o.w = to_bf(gelu_exact((to_f(a.w) - m) * r * gg[c0 + 3] + bb[c0 + 3]));
    *(ushort4*)&xio[e] = o;
}

// ---------------- conv2 MFMA implicit GEMM, zero-LDS input, LDS-transposed coalesced epilogue ----------------
__global__ __launch_bounds__(256) void k_conv2m(const u16* __restrict__ f1b,
                                                const u16* __restrict__ wp,   // [9][64][32]
                                                const float* __restrict__ bias,
                                                u16* __restrict__ f2n,
                                                float* __restrict__ sacc) {
    __shared__ u16 st[256][72];       // [pixel][64 ch + pad] = 36.9 KB
    __shared__ float rs[8][4], rq[8][4];
    int b = blockIdx.y;
    int tile = blockIdx.x;
    int y0 = (tile >> 3) << 4;
    int x0 = (tile & 7) << 4;
    int tid = threadIdx.x;
    int w = tid >> 6, lane = tid & 63;
    int l15 = lane & 15, l16 = lane >> 4;

    const u16* base = f1b + ((size_t)b << 19);

    f32x4 acc[4][4];
    f32x4 zf = {0.f, 0.f, 0.f, 0.f};
#pragma unroll
    for (int m = 0; m < 4; m++)
#pragma unroll
        for (int n = 0; n < 4; n++) acc[m][n] = zf;
    bf16x8 zb = {0, 0, 0, 0, 0, 0, 0, 0};

#pragma unroll
    for (int tap = 0; tap < 9; tap++) {
        int dy = tap / 3, dx = tap % 3;
        int gx = x0 + l15 + dx - 1;
        bf16x8 af[4], bk[4];
#pragma unroll
        for (int m = 0; m < 4; m++) {
            int gy = y0 + w * 4 + m + dy - 1;
            bool ok = (gy >= 0) && (gy < 128) && (gx >= 0) && (gx < 128);
            int pix = ok ? (gy * 128 + gx) : 0;
            bf16x8 v = *(const bf16x8*)(base + ((size_t)pix << 5) + l16 * 8);
            af[m] = ok ? v : zb;
        }
#pragma unroll
        for (int n = 0; n < 4; n++)
            bk[n] = *(const bf16x8*)&wp[(tap * 64 + n * 16 + l15) * 32 + l16 * 8];
#pragma unroll
        for (int m = 0; m < 4; m++)
#pragma unroll
            for (int n = 0; n < 4; n++)
                acc[m][n] = __builtin_amdgcn_mfma_f32_16x16x32_bf16(af[m], bk[n], acc[m][n], 0, 0, 0);
    }

    // round + transpose into LDS: pixel-major rows
#pragma unroll
    for (int n = 0; n < 4; n++) {
        int ch = n * 16 + l15;
        float bv = bias[ch];
#pragma unroll
        for (int m = 0; m < 4; m++) {
#pragma unroll
            for (int r = 0; r < 4; r++) {
                int lpix = (w * 4 + m) * 16 + l16 * 4 + r;   // py*16+px within tile
                st[lpix][ch] = to_bf(acc[m][n][r] + bv);
            }
        }
    }
    __syncthreads();

    // coalesced write-out: one pixel per thread, 8 x 16B stores; GN partials from registers
    int py = tid >> 4, pxx = tid & 15;
    u16* dstp = f2n + ((size_t)(b * 16384 + (y0 + py) * 128 + x0 + pxx) << 6);
    float gs[8], gq[8];
#pragma unroll
    for (int g = 0; g < 8; g++) { gs[g] = 0.0f; gq[g] = 0.0f; }
#pragma unroll
    for (int c0 = 0; c0 < 8; c0++) {
        u16x8 v = *(const u16x8*)&st[tid][c0 * 8];
        *(u16x8*)(dstp + c0 * 8) = v;
#pragma unroll
        for (int i = 0; i < 8; i++) {
            float f = to_f((u16)v[i]);
            gs[c0] += f;
            gq[c0] += f * f;
        }
    }
    // reduce over 64 lanes (pixels) per wave, then across 4 waves, then atomics
#pragma unroll
    for (int g = 0; g < 8; g++) {
#pragma unroll
        for (int off = 1; off < 64; off <<= 1) {
            gs[g] += __shfl_xor(gs[g], off);
            gq[g] += __shfl_xor(gq[g], off);
        }
    }
    if (lane == 0)
#pragma unroll
        for (int g = 0; g < 8; g++) { rs[g][w] = gs[g]; rq[g][w] = gq[g]; }
    __syncthreads();
    if (tid < 8) {
        int g = tid;
        float S = rs[g][0] + rs[g][1] + rs[g][2] + rs[g][3];
        float Q = rq[g][0] + rq[g][1] + rq[g][2] + rq[g][3];
        atomicAdd(&sacc[(b * 8 + g) * 2], S);
        atomicAdd(&sacc[(b * 8 + g) * 2 + 1], Q);
    }
}

// ---------------- bf16 MFMA GEMM (128x128) ----------------
// MODE 0: A [M,K]. MODE 1: implicit im2col of f2n NHWC.
// EPI 1: fp32 C = acc+bias. EPI 2: fp32 C += acc+bias. EPI 3: patch scatter + postab.
// EPI 6: interleaved w12 -> bf16 hb = silu(h1)*h2, out stride N/2.
// EPI 7: bf16 C = rope(acc+bias) for cols<1024, else acc+bias.
template <int MODE, int EPI>
__global__ __launch_bounds__(256) void k_bgemm(const u16* __restrict__ A,
                                               const u16* __restrict__ Bt,
                                               const float* __restrict__ bias,
                                               void* __restrict__ Cp,
                                               const float* __restrict__ aux,
                                               int M, int N, int K) {
    __shared__ u16 ldsA[8192];   // [kg 8][row 128][8]
    __shared__ u16 ldsB[8192];   // [col 128][kg^swz 8][8]
    int tid = threadIdx.x;
    int w = tid >> 6, lane = tid & 63;
    int bm = blockIdx.y * 128, bn = blockIdx.x * 128;
    int wr = w >> 1, wc = w & 1;
    int l15 = lane & 15, l16 = lane >> 4;

    f32x4 acc[4][4];
    f32x4 zf = {0.f, 0.f, 0.f, 0.f};
#pragma unroll
    for (int m = 0; m < 4; m++)
#pragma unroll
        for (int n = 0; n < 4; n++) acc[m][n] = zf;

    for (int k0 = 0; k0 < K; k0 += 64) {
#pragma unroll
        for (int i = 0; i < 4; i++) {
            int chunk = (w * 4 + i) * 64 + lane;
            int kg = chunk >> 7, row = chunk & 127;
            const u16* src;
            if (MODE == 0) {
                int grow = bm + row;
                if (grow > M - 1) grow = M - 1;
                src = A + (size_t)grow * K + k0 + kg * 8;
            } else {
                int grow = bm + row;
                int bimg = grow >> 8, p = grow & 255;
                int kga = (k0 >> 3) + kg;
                int tap = kga >> 3, cq = kga & 7;
                int ky = tap >> 3, kx = tap & 7;
                int gy = ((p >> 4) << 3) + ky, gx = ((p & 15) << 3) + kx;
                src = A + (((size_t)(bimg * 16384 + gy * 128 + gx)) << 6) + cq * 8;
            }
            gload_lds16(src, &ldsA[(w * 4 + i) * 512]);
        }
#pragma unroll
        for (int i = 0; i < 4; i++) {
            int chunk = (w * 4 + i) * 64 + lane;
            int col = chunk >> 3, kgs = chunk & 7;
            int kg_src = kgs ^ (col & 7);
            const u16* src = Bt + (size_t)(bn + col) * K + k0 + kg_src * 8;
            gload_lds16(src, &ldsB[(w * 4 + i) * 512]);
        }
        __syncthreads();

        bf16x8 af[4][2], bfr[4][2];
#pragma unroll
        for (int kk = 0; kk < 2; kk++) {
            int kga = kk * 4 + l16;
#pragma unroll
            for (int m = 0; m < 4; m++) {
                int row_l = wr * 64 + m * 16 + l15;
                af[m][kk] = *(const bf16x8*)&ldsA[(kga * 128 + row_l) * 8];
            }
#pragma unroll
            for (int n = 0; n < 4; n++) {
                int col_l = wc * 64 + n * 16 + l15;
                bfr[n][kk] = *(const bf16x8*)&ldsB[(col_l * 8 + (kga ^ (col_l & 7))) * 8];
            }
        }
#pragma unroll
        for (int m = 0; m < 4; m++)
#pragma unroll
            for (int n = 0; n < 4; n++) {
                acc[m][n] = __builtin_amdgcn_mfma_f32_16x16x32_bf16(af[m][0], bfr[n][0], acc[m][n], 0, 0, 0);
                acc[m][n] = __builtin_amdgcn_mfma_f32_16x16x32_bf16(af[m][1], bfr[n][1], acc[m][n], 0, 0, 0);
            }
        __syncthreads();
    }

    if (EPI == 6) {
#pragma unroll
        for (int np = 0; np < 2; np++) {
            int n_a = np * 2, n_b = np * 2 + 1;
            float bva = bias[bn + wc * 64 + n_a * 16 + l15];
            float bvb = bias[bn + wc * 64 + n_b * 16 + l15];
            int ocol = (bn >> 1) + wc * 32 + np * 16 + l15;
#pragma unroll
            for (int m = 0; m < 4; m++) {
#pragma unroll
                for (int r = 0; r < 4; r++) {
                    int grow = bm + wr * 64 + m * 16 + l16 * 4 + r;
                    if (grow < M) {
                        float h1v = to_f(to_bf(acc[m][n_a][r] + bva));
                        float h2v = to_f(to_bf(acc[m][n_b][r] + bvb));
                        float sl = h1v / (1.0f + __expf(-h1v));
                        ((u16*)Cp)[(size_t)grow * (N >> 1) + ocol] = to_bf(sl * h2v);
                    }
                }
            }
        }
    } else {
#pragma unroll
        for (int n = 0; n < 4; n++) {
            int gcol = bn + wc * 64 + n * 16 + l15;
            float bv = bias[gcol];
            float rc = 0.f, rsn = 0.f, rsc = 1.f;
            bool isqk = false, odd = false;
            if (EPI == 7) {
                isqk = gcol < 1024;
                odd = (l15 & 1) != 0;
                const float* rb = &aux[(gcol & 511) * 4];
                if (isqk) {
                    rc = rb[0]; rsn = rb[1];
                    rsc = (gcol < 512) ? rb[2] : rb[3];
                }
            }
#pragma unroll
            for (int m = 0; m < 4; m++) {
#pragma unroll
                for (int r = 0; r < 4; r++) {
                    int grow = bm + wr * 64 + m * 16 + l16 * 4 + r;
                    float v = acc[m][n][r] + bv;
                    if (EPI == 7) {
                        float p = __shfl_xor(v, 1);
                        float vr = isqk ? ((odd ? (v * rc + p * rsn) : (v * rc - p * rsn)) * rsc) : v;
                        if (grow < M) ((u16*)Cp)[(size_t)grow * N + gcol] = to_bf(vr);
                    } else if (EPI == 1) {
                        if (grow < M) ((float*)Cp)[(size_t)grow * N + gcol] = v;
                    } else if (EPI == 2) {
                        if (grow < M) ((float*)Cp)[(size_t)grow * N + gcol] += v;
                    } else {
                        int bimg = grow >> 8, p2 = grow & 255;
                        v += aux[p2 * 512 + gcol];
                        ((float*)Cp)[((size_t)(bimg * 257) + 1 + p2) * 512 + gcol] = v;
                    }
                }
            }
        }
    }
}

// ---------------- bf16 MFMA GEMM, BM=64 x BN=128 (for N=512 GEMMs; EPI2: fp32 +=) ----------------
__global__ __launch_bounds__(256) void k_bgemm64(const u16* __restrict__ A,
                                                 const u16* __restrict__ Bt,
                                                 const float* __restrict__ bias,
                                                 float* __restrict__ C,
                                                 int M, int N, int K) {
    __shared__ u16 ldsA[4096];   // [kg 8][row 64][8]
    __shared__ u16 ldsB[8192];   // [col 128][kg^swz 8][8]
    int tid = threadIdx.x;
    int w = tid >> 6, lane = tid & 63;
    int bm = blockIdx.y * 64, bn = blockIdx.x * 128;
    int l15 = lane & 15, l16 = lane >> 4;

    f32x4 acc[4][2];
    f32x4 zf = {0.f, 0.f, 0.f, 0.f};
#pragma unroll
    for (int m = 0; m < 4; m++)
#pragma unroll
        for (int n = 0; n < 2; n++) acc[m][n] = zf;

    for (int k0 = 0; k0 < K; k0 += 64) {
#pragma unroll
        for (int i = 0; i < 2; i++) {
            int chunk = (w * 2 + i) * 64 + lane;     // 0..511
            int kg = chunk >> 6, row = chunk & 63;
            int grow = bm + row;
            if (grow > M - 1) grow = M - 1;
            const u16* src = A + (size_t)grow * K + k0 + kg * 8;
            gload_lds16(src, &ldsA[(w * 2 + i) * 512]);
        }
#pragma unroll
        for (int i = 0; i < 4; i++) {
            int chunk = (w * 4 + i) * 64 + lane;
            int col = chunk >> 3, kgs = chunk & 7;
            int kg_src = kgs ^ (col & 7);
            const u16* src = Bt + (size_t)(bn + col) * K + k0 + kg_src * 8;
            gload_lds16(src, &ldsB[(w * 4 + i) * 512]);
        }
        __syncthreads();

        bf16x8 af[4][2], bfr[2][2];
#pragma unroll
        for (int kk = 0; kk < 2; kk++) {
            int kga = kk * 4 + l16;
#pragma unroll
            for (int m = 0; m < 4; m++) {
                int row_l = m * 16 + l15;
                af[m][kk] = *(const bf16x8*)&ldsA[(kga * 64 + row_l) * 8];
            }
#pragma unroll
            for (int n = 0; n < 2; n++) {
                int col_l = w * 32 + n * 16 + l15;
                bfr[n][kk] = *(const bf16x8*)&ldsB[(col_l * 8 + (kga ^ (col_l & 7))) * 8];
            }
        }
#pragma unroll
        for (int m = 0; m < 4; m++)
#pragma unroll
            for (int n = 0; n < 2; n++) {
                acc[m][n] = __builtin_amdgcn_mfma_f32_16x16x32_bf16(af[m][0], bfr[n][0], acc[m][n], 0, 0, 0);
                acc[m][n] = __builtin_amdgcn_mfma_f32_16x16x32_bf16(af[m][1], bfr[n][1], acc[m][n], 0, 0, 0);
            }
        __syncthreads();
    }

#pragma unroll
    for (int n = 0; n < 2; n++) {
        int gcol = bn + w * 32 + n * 16 + l15;
        float bv = bias[gcol];
#pragma unroll
        for (int m = 0; m < 4; m++) {
#pragma unroll
            for (int r = 0; r < 4; r++) {
                int grow = bm + m * 16 + l16 * 4 + r;
                if (grow < M) C[(size_t)grow * N + gcol] += acc[m][n][r] + bv;
            }
        }
    }
}

// ---------------- LayerNorm, wave-per-row, bf16 out ----------------
__global__ __launch_bounds__(256) void k_lnb(const float* __restrict__ x,
                                             const float* __restrict__ g,
                                             const float* __restrict__ bta,
                                             u16* __restrict__ o) {
    int row = blockIdx.x * 4 + (threadIdx.x >> 6);
    int lane = threadIdx.x & 63;
    const float4* xr = (const float4*)(x + (size_t)row * 512);
    float4 a = xr[lane * 2], b = xr[lane * 2 + 1];
    float s = a.x + a.y + a.z + a.w + b.x + b.y + b.z + b.w;
#pragma unroll
    for (int off = 1; off < 64; off <<= 1) s += __shfl_xor(s, off);
    float mean = s * (1.0f / 512.0f);
    float d[8] = {a.x - mean, a.y - mean, a.z - mean, a.w - mean,
                  b.x - mean, b.y - mean, b.z - mean, b.w - mean};
    float q = 0.0f;
#pragma unroll
    for (int i = 0; i < 8; i++) q += d[i] * d[i];
#pragma unroll
    for (int off = 1; off < 64; off <<= 1) q += __shfl_xor(q, off);
    float rstd = rsqrtf(q * (1.0f / 512.0f) + EPSV);
    int c0 = lane * 8;
    float4 g0 = *(const float4*)&g[c0], g1 = *(const float4*)&g[c0 + 4];
    float4 b0 = *(const float4*)&bta[c0], b1 = *(const float4*)&bta[c0 + 4];
    u16* orow = o + (size_t)row * 512 + c0;
    *(ushort4*)orow = make_ushort4(to_bf(d[0] * rstd * g0.x + b0.x), to_bf(d[1] * rstd * g0.y + b0.y),
                                   to_bf(d[2] * rstd * g0.z + b0.z), to_bf(d[3] * rstd * g0.w + b0.w));
    *(ushort4*)(orow + 4) = make_ushort4(to_bf(d[4] * rstd * g1.x + b1.x), to_bf(d[5] * rstd * g1.y + b1.y),
                                         to_bf(d[6] * rstd * g1.z + b1.z), to_bf(d[7] * rstd * g1.w + b1.w));
}

// final LN, wave-per-row, output remap (fp32 out)
__global__ __launch_bounds__(256) void k_ln_out(const float* __restrict__ x,
                                                const float* __restrict__ g,
                                                const float* __restrict__ bta,
                                                float* __restrict__ out) {
    int row = blockIdx.x * 4 + (threadIdx.x >> 6);
    int lane = threadIdx.x & 63;
    const float4* xr = (const float4*)(x + (size_t)row * 512);
    float4 a = xr[lane * 2], b = xr[lane * 2 + 1];
    float s = a.x + a.y + a.z + a.w + b.x + b.y + b.z + b.w;
#pragma unroll
    for (int off = 1; off < 64; off <<= 1) s += __shfl_xor(s, off);
    float mean = s * (1.0f / 512.0f);
    float d[8] = {a.x - mean, a.y - mean, a.z - mean, a.w - mean,
                  b.x - mean, b.y - mean, b.z - mean, b.w - mean};
    float q = 0.0f;
#pragma unroll
    for (int i = 0; i < 8; i++) q += d[i] * d[i];
#pragma unroll
    for (int off = 1; off < 64; off <<= 1) q += __shfl_xor(q, off);
    float rstd = rsqrtf(q * (1.0f / 512.0f) + EPSV);
    int bb = row / 257, t = row % 257;
    float* dst = (t == 0) ? out + (size_t)bb * 512
                          : out + 16384 + (size_t)(bb * 256 + (t - 1)) * 512;
    int c0 = lane * 8;
    float4 g0 = *(const float4*)&g[c0], g1 = *(const float4*)&g[c0 + 4];
    float4 b0 = *(const float4*)&bta[c0], b1 = *(const float4*)&bta[c0 + 4];
    *(float4*)(dst + c0) = make_float4(d[0] * rstd * g0.x + b0.x, d[1] * rstd * g0.y + b0.y,
                                       d[2] * rstd * g0.z + b0.z, d[3] * rstd * g0.w + b0.w);
    *(float4*)(dst + c0 + 4) = make_float4(d[4] * rstd * g1.x + b1.x, d[5] * rstd * g1.y + b1.y,
                                           d[6] * rstd * g1.z + b1.z, d[7] * rstd * g1.w + b1.w);
}

// ---------------- MFMA attention: pre-roped qkv, direct-global Q/K, dbuf PV, setprio ----------------
__global__ __launch_bounds__(256) void k_attn_mfma(const u16* __restrict__ qkv,
                                                   u16* __restrict__ y) {
    __shared__ u16 KV[2][64][72];
    __shared__ float sc[32][260];
    __shared__ u16 Pb[32][328];
    __shared__ float red1[32][8];
    __shared__ float red2[32][8];
    __shared__ float invr[32];

    int bid = blockIdx.x;                 // ((b*8+h)*9 + qt)
    int qt = bid % 9, bh = bid / 9;
    int h = bh & 7, b = bh >> 3;
    int q0 = qt * 32;
    int tid = threadIdx.x;
    int w = tid >> 6, lane = tid & 63;
    int l15 = lane & 15, l16 = lane >> 4;

    bf16x8 aq[2][2];
#pragma unroll
    for (int m = 0; m < 2; m++) {
        int grow = q0 + m * 16 + l15; if (grow > 256) grow = 256;
        const u16* qp = qkv + (size_t)(b * 257 + grow) * 1536 + h * 64 + l16 * 8;
        aq[m][0] = *(const bf16x8*)qp;
        aq[m][1] = *(const bf16x8*)(qp + 32);
    }

    for (int t = 0; t < 5; t++) {
        int j0 = t * 64;
        int gk = j0 + w * 16 + l15; if (gk > 256) gk = 256;
        const u16* kp = qkv + (size_t)(b * 257 + gk) * 1536 + 512 + h * 64 + l16 * 8;
        bf16x8 bk0 = *(const bf16x8*)kp;
        bf16x8 bk1 = *(const bf16x8*)(kp + 32);
        f32x4 a2[2];
        f32x4 zf = {0.f, 0.f, 0.f, 0.f};
        __builtin_amdgcn_s_setprio(1);
#pragma unroll
        for (int m = 0; m < 2; m++) {
            a2[m] = zf;
            a2[m] = __builtin_amdgcn_mfma_f32_16x16x32_bf16(aq[m][0], bk0, a2[m], 0, 0, 0);
            a2[m] = __builtin_amdgcn_mfma_f32_16x16x32_bf16(aq[m][1], bk1, a2[m], 0, 0, 0);
        }
        __builtin_amdgcn_s_setprio(0);
        int col = j0 + w * 16 + l15;
        if (col < 257) {
#pragma unroll
            for (int m = 0; m < 2; m++)
#pragma unroll
                for (int r = 0; r < 4; r++)
                    sc[m * 16 + l16 * 4 + r][col] = a2[m][r];
        }
    }
    __syncthreads();

    {
        int r = tid >> 3, sub = tid & 7;
        float mx = -1e30f;
        for (int j = sub; j < 257; j += 8) mx = fmaxf(mx, sc[r][j]);
        red1[r][sub] = mx;
        __syncthreads();
        mx = red1[r][0];
#pragma unroll
        for (int i = 1; i < 8; i++) mx = fmaxf(mx, red1[r][i]);
        float sm = 0.0f;
        for (int j = sub; j < 257; j += 8) {
            float e = __expf(sc[r][j] - mx);
            Pb[r][j] = to_bf(e);
            sm += e;
        }
        for (int j = 257 + sub; j < 320; j += 8) Pb[r][j] = 0;
        red2[r][sub] = sm;
        __syncthreads();
        if (sub == 0) {
            float t = red2[r][0];
#pragma unroll
            for (int i = 1; i < 8; i++) t += red2[r][i];
            invr[r] = 1.0f / t;
        }
        __syncthreads();
    }

    f32x4 oacc[2];
    {
        f32x4 zf = {0.f, 0.f, 0.f, 0.f};
        oacc[0] = zf; oacc[1] = zf;
    }
    for (int t = 0; t < 5; t++) {
        int j0 = t * 64;
        int buf = t & 1;
        {
            int vk = tid & 63, vd0 = (tid >> 6) * 16;
            int gk = j0 + vk;
            u16 o[16];
            if (gk <= 256) {
                const u16* vp = qkv + (size_t)(b * 257 + gk) * 1536 + 1024 + h * 64 + vd0;
                ushort4 a0 = *(const ushort4*)vp, a1 = *(const ushort4*)(vp + 4);
                ushort4 a2v = *(const ushort4*)(vp + 8), a3 = *(const ushort4*)(vp + 12);
                o[0] = a0.x; o[1] = a0.y; o[2] = a0.z; o[3] = a0.w;
                o[4] = a1.x; o[5] = a1.y; o[6] = a1.z; o[7] = a1.w;
                o[8] = a2v.x; o[9] = a2v.y; o[10] = a2v.z; o[11] = a2v.w;
                o[12] = a3.x; o[13] = a3.y; o[14] = a3.z; o[15] = a3.w;
            } else {
#pragma unroll
                for (int i = 0; i < 16; i++) o[i] = 0;
            }
#pragma unroll
            for (int i = 0; i < 16; i++) KV[buf][vd0 + i][vk] = o[i];
        }
        __syncthreads();

        bf16x8 ap[2][2], bv[2];
#pragma unroll
        for (int m = 0; m < 2; m++)
#pragma unroll
            for (int kk = 0; kk < 2; kk++)
                ap[m][kk] = *(const bf16x8*)&Pb[m * 16 + l15][j0 + kk * 32 + l16 * 8];
#pragma unroll
        for (int kk = 0; kk < 2; kk++)
            bv[kk] = *(const bf16x8*)&KV[buf][w * 16 + l15][kk * 32 + l16 * 8];
        __builtin_amdgcn_s_setprio(1);
#pragma unroll
        for (int m = 0; m < 2; m++) {
            oacc[m] = __builtin_amdgcn_mfma_f32_16x16x32_bf16(ap[m][0], bv[0], oacc[m], 0, 0, 0);
            oacc[m] = __builtin_amdgcn_mfma_f32_16x16x32_bf16(ap[m][1], bv[1], oacc[m], 0, 0, 0);
        }
        __builtin_amdgcn_s_setprio(0);
    }

#pragma unroll
    for (int m = 0; m < 2; m++)
#pragma unroll
        for (int r = 0; r < 4; r++) {
            int lr = m * 16 + l16 * 4 + r;
            int grow = q0 + lr;
            if (grow < 257)
                y[(size_t)(b * 257 + grow) * 512 + h * 64 + w * 16 + l15] =
                    to_bf(oacc[m][r] * invr[lr]);
        }
}

// ---------------- host launch ----------------
extern "C" void kernel_launch(void* const* d_in, const int* in_sizes, int n_in,
                              void* d_out, int out_size, void* d_ws, size_t ws_size,
                              hipStream_t stream) {
    const float* x       = (const float*)d_in[0];
    const float* conv1_w = (const float*)d_in[1];
    const float* conv1_b = (const float*)d_in[2];
    const float* gn1_g   = (const float*)d_in[3];
    const float* gn1_b   = (const float*)d_in[4];
    const float* conv2_w = (const float*)d_in[5];
    const float* conv2_b = (const float*)d_in[6];
    const float* gn2_g   = (const float*)d_in[7];
    const float* gn2_b   = (const float*)d_in[8];
    const float* patch_w = (const float*)d_in[9];
    const float* patch_b = (const float*)d_in[10];
    const float* cls_tok = (const float*)d_in[11];
    const float* ln1_g   = (const float*)d_in[12];
    const float* ln1_b   = (const float*)d_in[13];
    const float* qkv_w   = (const float*)d_in[14];
    const float* qkv_b   = (const float*)d_in[15];
    const float* out_w   = (const float*)d_in[16];
    const float* out_b   = (const float*)d_in[17];
    const float* ln2_g   = (const float*)d_in[18];
    const float* ln2_b   = (const float*)d_in[19];
    const float* w1_w    = (const float*)d_in[20];
    const float* w1_b    = (const float*)d_in[21];
    const float* w2_w    = (const float*)d_in[22];
    const float* w2_b    = (const float*)d_in[23];
    const float* w3_w    = (const float*)d_in[24];
    const float* w3_b    = (const float*)d_in[25];
    const float* fn_g    = (const float*)d_in[26];
    const float* fn_b    = (const float*)d_in[27];
    float* out = (float*)d_out;
    char* wsb  = (char*)d_ws;

    const size_t O_R1    = 0;
    const size_t O_W12A  = 0;                 // 33,554,432 (after patchgemm)
    const size_t O_W3A   = 33554432;          // 16,777,216
    const size_t O_HB    = O_R1 + 67371008;   // 33,685,504
    const size_t O_NB    = O_R1 + 101056512;  // 8,421,376
    const size_t O_Y     = O_R1 + 109477888;  // 8,421,376
    const size_t O_R2    = 134217728;         // f1n bf16 | qkvb bf16
    const size_t O_XA    = 201326592;
    const size_t O_PWT   = 218169344;
    const size_t O_QKVT  = 222363648;
    const size_t O_OUTT  = 234946560;
    const size_t O_PT    = 245432320;
    const size_t O_RT    = 245956608;
    const size_t O_CW1   = 245964800;
    const size_t O_CW2   = 245968896;
    const size_t O_SA    = 246046720;
    const size_t O_B12   = 246050816;
    const size_t NEED    = 246181888;
    if (ws_size < NEED) {
        k_wsfail<<<1, 1, 0, stream>>>(out);
        return;
    }
    u16*   f2n    = (u16*)(wsb + O_R1);
    u16*   w12All = (u16*)(wsb + O_W12A);
    u16*   w3All  = (u16*)(wsb + O_W3A);
    u16*   hb     = (u16*)(wsb + O_HB);
    u16*   nb     = (u16*)(wsb + O_NB);
    u16*   yb     = (u16*)(wsb + O_Y);
    u16*   f1n    = (u16*)(wsb + O_R2);
    u16*   qkvb   = (u16*)(wsb + O_R2);
    float* xa     = (float*)(wsb + O_XA);
    u16*   patchT = (u16*)(wsb + O_PWT);
    u16*   qkvT   = (u16*)(wsb + O_QKVT);
    u16*   outT   = (u16*)(wsb + O_OUTT);
    float* postab = (float*)(wsb + O_PT);
    float* ropet  = (float*)(wsb + O_RT);
    float* w1t    = (float*)(wsb + O_CW1);
    u16*   wpack  = (u16*)(wsb + O_CW2);
    float* sacc   = (float*)(wsb + O_SA);
    float* bias12 = (float*)(wsb + O_B12);

    // setup + persistent weight conversions
    k_setup<<<512, 256, 0, stream>>>(sacc, conv1_w, w1t, conv2_w, wpack,
                                     w1_b, w2_b, bias12, postab, ropet, cls_tok, xa);
    k_pperm<<<8192, 256, 0, stream>>>(patch_w, patchT);
    k_wcvtT<<<dim3(48, 16, 8), 256, 0, stream>>>(qkv_w, qkvT, 512, 1536);
    k_wcvtT<<<dim3(16, 16, 8), 256, 0, stream>>>(out_w, outT, 512, 512);

    // conv stem (NHWC bf16, fused GN stats)
    k_conv1<<<dim3(64, 32), 256, 0, stream>>>(x, w1t, conv1_b, f1n, sacc);
    k_gnap<<<16384, 256, 0, stream>>>(f1n, sacc, gn1_g, gn1_b, 31, 19, 4);
    k_conv2m<<<dim3(64, 32), 256, 0, stream>>>(f1n, wpack, conv2_b, f2n, sacc + 256);
    k_gnap<<<32768, 256, 0, stream>>>(f2n, sacc + 256, gn2_g, gn2_b, 63, 20, 8);

    // patch embed (frees region 0 afterwards)
    k_bgemm<1, 3><<<dim3(4, 64), 256, 0, stream>>>(f2n, patchT, patch_b, xa, postab, 8192, 512, 4096);

    // one-time all-layer MLP weight conversion into freed region
    k_wcvtT12L<<<dim3(64, 16, 16), 256, 0, stream>>>(w1_w, w2_w, w12All);
    k_wcvtT<<<dim3(16, 64, 8), 256, 0, stream>>>(w3_w, w3All, 2048, 512);

    // transformer
    for (int l = 0; l < 8; l++) {
        k_lnb<<<2056, 256, 0, stream>>>(xa, ln1_g + l * 512, ln1_b + l * 512, nb);
        k_bgemm<0, 7><<<dim3(12, 65), 256, 0, stream>>>(nb, qkvT + (size_t)l * 786432,
                                                        qkv_b + l * 1536, qkvb, ropet, 8224, 1536, 512);
        k_attn_mfma<<<2304, 256, 0, stream>>>(qkvb, yb);
        k_bgemm64<<<dim3(4, 129), 256, 0, stream>>>(yb, outT + (size_t)l * 262144,
                                                    out_b + l * 512, xa, 8224, 512, 512);
        k_lnb<<<2056, 256, 0, stream>>>(xa, ln2_g + l * 512, ln2_b + l * 512, nb);
        k_bgemm<0, 6><<<dim3(32, 65), 256, 0, stream>>>(nb, w12All + (size_t)l * 2097152,
                                                        bias12 + l * 4096, hb, nullptr, 8224, 4096, 512);
        k_bgemm64<<<dim3(4, 129), 256, 0, stream>>>(hb, w3All + (size_t)l * 1048576,
                                                    w3_b + l * 512, xa, 8224, 512, 2048);
    }
    k_ln_out<<<2056, 256, 0, stream>>>(xa, fn_g, fn_b, out);
}